// Round 8
// baseline (2837.184 us; speedup 1.0000x reference)
//
#include <hip/hip_runtime.h>
#include <math.h>

// Problem constants (from reference)
constexpr int N_NODES = 50000;
constexpr int N_EDGES = 1600000;
constexpr int HDIM    = 64;
constexpr int NLAYER  = 5;
constexpr int NBASIS  = 8;
constexpr int TLUT    = 512;           // radial LUT entries per layer
constexpr float CUT_R = 5.0f;
constexpr float PI_F  = 3.14159265358979f;

__device__ __forceinline__ float bcastf(float v, int l) {
    return __uint_as_float(__builtin_amdgcn_readlane(__float_as_uint(v), l));
}
__device__ __forceinline__ float waveRedSum(float v) {
    for (int off = 32; off > 0; off >>= 1) v += __shfl_xor(v, off, 64);
    return v;
}
__device__ __forceinline__ float siluf(float x) { return x / (1.0f + __expf(-x)); }

// ---------------- setup kernels ----------------

__global__ void k_embed(const int* __restrict__ an, const float* __restrict__ embed,
                        float* __restrict__ feats) {
    int i = blockIdx.x * blockDim.x + threadIdx.x;           // N*H threads
    if (i >= N_NODES * HDIM) return;
    int node = i >> 6, h = i & 63;
    feats[i] = embed[an[node] * HDIM + h];
}

__global__ void k_hist(const int* __restrict__ row, int* __restrict__ counts) {
    int e = blockIdx.x * blockDim.x + threadIdx.x;
    if (e < N_EDGES) atomicAdd(&counts[row[e]], 1);
}

__global__ void k_scan1(const int* __restrict__ counts, int* __restrict__ partial) {
    __shared__ int s[256];
    int i = blockIdx.x * 256 + threadIdx.x;
    int v = (i < N_NODES) ? counts[i] : 0;
    s[threadIdx.x] = v; __syncthreads();
    for (int off = 128; off > 0; off >>= 1) {
        if (threadIdx.x < off) s[threadIdx.x] += s[threadIdx.x + off];
        __syncthreads();
    }
    if (threadIdx.x == 0) partial[blockIdx.x] = s[0];
}

// single-block exclusive scan of block partials (nb <= 256)
__global__ void k_scan2(int* __restrict__ partial, int nb) {
    __shared__ int s[256];
    int v = (threadIdx.x < nb) ? partial[threadIdx.x] : 0;
    s[threadIdx.x] = v; __syncthreads();
    for (int off = 1; off < 256; off <<= 1) {
        int add = (threadIdx.x >= off) ? s[threadIdx.x - off] : 0;
        __syncthreads();
        s[threadIdx.x] += add;
        __syncthreads();
    }
    if (threadIdx.x < nb) partial[threadIdx.x] = s[threadIdx.x] - v;  // exclusive
}

__global__ void k_scan3(const int* __restrict__ counts, const int* __restrict__ partial,
                        int* __restrict__ starts, int* __restrict__ cursor) {
    __shared__ int s[256];
    int i = blockIdx.x * 256 + threadIdx.x;
    int v = (i < N_NODES) ? counts[i] : 0;
    s[threadIdx.x] = v; __syncthreads();
    for (int off = 1; off < 256; off <<= 1) {               // inclusive Hillis-Steele
        int add = (threadIdx.x >= off) ? s[threadIdx.x - off] : 0;
        __syncthreads();
        s[threadIdx.x] += add;
        __syncthreads();
    }
    if (i < N_NODES) {
        int st = partial[blockIdx.x] + s[threadIdx.x] - v;  // exclusive
        starts[i] = st; cursor[i] = st;
    }
    if (i == 0) starts[N_NODES] = N_EDGES;
}

// scatter edges into CSR order; record packed to 4B: (col<<16) | t_fix9.7
__global__ void k_scatter(const int* __restrict__ row, const int* __restrict__ col,
                          const float* __restrict__ pos, int* __restrict__ cursor,
                          unsigned int* __restrict__ erec) {
    int e = blockIdx.x * blockDim.x + threadIdx.x;
    if (e >= N_EDGES) return;
    int r = row[e], c = col[e];
    int p = atomicAdd(&cursor[r], 1);
    float dx = pos[c * 3 + 0] - pos[r * 3 + 0];
    float dy = pos[c * 3 + 1] - pos[r * 3 + 1];
    float dz = pos[c * 3 + 2] - pos[r * 3 + 2];
    float len = sqrtf(dx * dx + dy * dy + dz * dz);
    float t = len * ((float)(TLUT - 1) / CUT_R);
    t = fminf(t, (float)(TLUT - 1));        // exact for len>=cutoff (rbf==0 there)
    unsigned int tfix = (unsigned int)(t * 128.0f);   // 9.7 fixed point, <= 65408
    erec[p] = ((unsigned int)c << 16) | tfix;
}

// W2s[l][k][h] = sum_{m<3} rad_w2[l][k][h*3+m]; Wsp[l][k][h] = (self_w @ proj_top)[k][h]
__global__ void k_prep(const float* __restrict__ rad_w2, const float* __restrict__ self_w,
                       const float* __restrict__ proj_w,
                       float* __restrict__ W2s, float* __restrict__ Wsp) {
    int i = blockIdx.x * blockDim.x + threadIdx.x;          // L*H*H
    if (i >= NLAYER * HDIM * HDIM) return;
    int l = i / (HDIM * HDIM); int rem = i % (HDIM * HDIM);
    int k = rem / HDIM; int h = rem % HDIM;
    const float* w = rad_w2 + ((size_t)l * HDIM + k) * (HDIM * 3) + h * 3;
    W2s[i] = w[0] + w[1] + w[2];
    const float* sw = self_w + ((size_t)l * HDIM + k) * HDIM;
    const float* pw = proj_w + (size_t)l * 2 * HDIM * HDIM;
    float acc = 0.f;
    for (int m = 0; m < HDIM; ++m) acc += sw[m] * pw[m * HDIM + h];
    Wsp[i] = acc;
}

// b2s[l][h] = sum_m rad_b2[l][h*3+m];  bsp[l][h] = self_b@proj_top + proj_b
__global__ void k_bias(const float* __restrict__ rad_b2, const float* __restrict__ self_b,
                       const float* __restrict__ proj_w, const float* __restrict__ proj_b,
                       float* __restrict__ b2s, float* __restrict__ bsp) {
    int i = blockIdx.x * blockDim.x + threadIdx.x;          // L*H
    if (i >= NLAYER * HDIM) return;
    int l = i / HDIM, h = i % HDIM;
    const float* rb2 = rad_b2 + l * HDIM * 3 + h * 3;
    b2s[i] = rb2[0] + rb2[1] + rb2[2];
    float acc = proj_b[l * HDIM + h];
    const float* pw = proj_w + (size_t)l * 2 * HDIM * HDIM;
    const float* sb = self_b + l * HDIM;
    for (int m = 0; m < HDIM; ++m) acc += sb[m] * pw[m * HDIM + h];
    bsp[i] = acc;
}

// radial LUT: lut[l][t][h] = (silu(rbf(len_t)@W1 + b1) @ W2s + b2s)[h]
__global__ void k_lut(const float* __restrict__ widths, const float* __restrict__ rad_w1,
                      const float* __restrict__ rad_b1, const float* __restrict__ W2s,
                      const float* __restrict__ b2s, float* __restrict__ lut) {
    int bid = blockIdx.x;                 // l*TLUT + t
    int l = bid / TLUT, t = bid % TLUT;
    int h = threadIdx.x;                  // 64 threads
    __shared__ float h1s[HDIM];
    float len = (float)t * (CUT_R / (float)(TLUT - 1));
    float cut = 0.0f;
    if (len < CUT_R) cut = 0.5f * (cosf(len * (PI_F / CUT_R)) + 1.0f);
    float acc = rad_b1[l * HDIM + h];
    for (int b = 0; b < NBASIS; ++b) {
        float wb = fmaxf(widths[b], 0.1f);
        float center = (float)b * (CUT_R / (float)(NBASIS - 1));
        float d = (len - center) / wb;
        float rbf = __expf(-0.5f * d * d) * cut;
        acc += rbf * rad_w1[(l * NBASIS + b) * HDIM + h];
    }
    h1s[h] = siluf(acc);
    __syncthreads();
    float o = b2s[l * HDIM + h];
    const float* w2 = W2s + (size_t)l * HDIM * HDIM;
    for (int k = 0; k < HDIM; ++k) o += h1s[k] * w2[k * HDIM + h];
    lut[(size_t)bid * HDIM + h] = o;
}

// lutQ[(l*TLUT+t)*16+j] = pair {row t ch 4j..4j+3, row t+1 ch 4j..4j+3}
__global__ void k_lutq(const float* __restrict__ lut, float4* __restrict__ lutQ) {
    int i = blockIdx.x * blockDim.x + threadIdx.x;          // L*TLUT*16
    if (i >= NLAYER * TLUT * 16) return;
    int j = i & 15;
    int lt = i >> 4;                       // l*TLUT + t
    int l = lt / TLUT, t = lt % TLUT;
    int t1 = (t < TLUT - 1) ? t + 1 : t;
    const float* r0 = lut + (size_t)(l * TLUT + t)  * HDIM + 4 * j;
    const float* r1 = lut + (size_t)(l * TLUT + t1) * HDIM + 4 * j;
    lutQ[(size_t)i * 2 + 0] = make_float4(r0[0], r0[1], r0[2], r0[3]);
    lutQ[(size_t)i * 2 + 1] = make_float4(r1[0], r1[1], r1[2], r1[3]);
}

// ---------------- per-layer kernels ----------------

// one wave per node, 4 edge slots x 16 lanes (4 channels each via float4)
__global__ __launch_bounds__(256) void k_agg(const float4* __restrict__ feats4,
                                             const float4* __restrict__ lutQ_l,
                                             const int* __restrict__ starts,
                                             const unsigned int* __restrict__ erec,
                                             float4* __restrict__ agg4) {
    int wid  = (blockIdx.x * blockDim.x + threadIdx.x) >> 6;
    int lane = threadIdx.x & 63;
    int slot = lane >> 4;
    int j    = lane & 15;
    if (wid >= N_NODES) return;
    int e0 = starts[wid], e1 = starts[wid + 1];
    float ax = 0.f, ay = 0.f, az = 0.f, aw = 0.f;
    #pragma unroll 2
    for (int e = e0 + slot; e < e1; e += 4) {
        unsigned int rec = erec[e];
        int c    = rec >> 16;
        int tfix = rec & 0xffff;
        int i0   = tfix >> 7;
        float f  = (float)(tfix & 127) * (1.0f / 128.0f);
        const float4* q = lutQ_l + ((size_t)(i0 * 16 + j) * 2);
        float4 w0 = q[0];
        float4 w1 = q[1];
        float4 fv = feats4[(size_t)c * 16 + j];
        ax += fv.x * (w0.x + f * (w1.x - w0.x));
        ay += fv.y * (w0.y + f * (w1.y - w0.y));
        az += fv.z * (w0.z + f * (w1.z - w0.z));
        aw += fv.w * (w0.w + f * (w1.w - w0.w));
    }
    // reduce across the 4 slots (lanes j, j+16, j+32, j+48)
    ax += __shfl_xor(ax, 16, 64);  ay += __shfl_xor(ay, 16, 64);
    az += __shfl_xor(az, 16, 64);  aw += __shfl_xor(aw, 16, 64);
    ax += __shfl_xor(ax, 32, 64);  ay += __shfl_xor(ay, 32, 64);
    az += __shfl_xor(az, 32, 64);  aw += __shfl_xor(aw, 32, 64);
    if (slot == 0) agg4[(size_t)wid * 16 + j] = make_float4(ax, ay, az, aw);
}

// One wave per block; lane = node (64 nodes/block). Node vectors live in
// per-lane VGPR arrays with fully-static indexing; weights are wave-uniform
// loads (s_load -> SGPR operand of v_fmac). No LDS, no shuffles except none:
// LayerNorm is per-lane. Phased liveness keeps peak regs ~192: {a,conv} ->
// {x,conv} -> {conv,m1,upd} -> {x(reload),upd}.
__global__ __launch_bounds__(64) void k_node(float* __restrict__ feats,
        const float* __restrict__ agg,
        const float* __restrict__ Wsp_l, const float* __restrict__ bsp_l,
        const float* __restrict__ projw_l,
        const float* __restrict__ mlp_w1_l, const float* __restrict__ mlp_b1_l,
        const float* __restrict__ mlp_w2_l, const float* __restrict__ mlp_b2_l,
        const float* __restrict__ ln_g_l, const float* __restrict__ ln_b_l) {
    const int lane = threadIdx.x;
    const int node = blockIdx.x * 64 + lane;
    const int nds  = (node < N_NODES) ? node : (N_NODES - 1);
    const float* pb = projw_l + HDIM * HDIM;   // bottom half of proj_w

    float reg[64], conv[64], m1[64], upd[64];

    // reg <- a (per-lane contiguous row)
    {
        const float* ar = agg + (size_t)nds * 64;
        #pragma unroll
        for (int q = 0; q < 16; ++q)
            *(float4*)&reg[q * 4] = *(const float4*)&ar[q * 4];
    }
    #pragma unroll
    for (int h = 0; h < 64; ++h) conv[h] = bsp_l[h];
    #pragma unroll
    for (int k = 0; k < 64; ++k) {
        const float ak = reg[k];
        const float* wr = pb + k * 64;
        #pragma unroll
        for (int h = 0; h < 64; ++h) conv[h] = fmaf(ak, wr[h], conv[h]);
    }
    // reg <- x
    {
        const float* xr = feats + (size_t)nds * 64;
        #pragma unroll
        for (int q = 0; q < 16; ++q)
            *(float4*)&reg[q * 4] = *(const float4*)&xr[q * 4];
    }
    #pragma unroll
    for (int k = 0; k < 64; ++k) {
        const float xk = reg[k];
        const float* wr = Wsp_l + k * 64;
        #pragma unroll
        for (int h = 0; h < 64; ++h) conv[h] = fmaf(xk, wr[h], conv[h]);
    }

    // m1a = silu(conv @ W1[:,0:64] + b1a); upd = b2 + m1a @ W2[0:64,:]
    #pragma unroll
    for (int j = 0; j < 64; ++j) m1[j] = mlp_b1_l[j];
    #pragma unroll
    for (int k = 0; k < 64; ++k) {
        const float ck = conv[k];
        const float* wr = mlp_w1_l + k * 128;
        #pragma unroll
        for (int j = 0; j < 64; ++j) m1[j] = fmaf(ck, wr[j], m1[j]);
    }
    #pragma unroll
    for (int j = 0; j < 64; ++j) m1[j] = siluf(m1[j]);
    #pragma unroll
    for (int h = 0; h < 64; ++h) upd[h] = mlp_b2_l[h];
    #pragma unroll
    for (int j = 0; j < 64; ++j) {
        const float mj = m1[j];
        const float* wr = mlp_w2_l + j * 64;
        #pragma unroll
        for (int h = 0; h < 64; ++h) upd[h] = fmaf(mj, wr[h], upd[h]);
    }

    // m1b = silu(conv @ W1[:,64:128] + b1b); upd += m1b @ W2[64:128,:]
    #pragma unroll
    for (int j = 0; j < 64; ++j) m1[j] = mlp_b1_l[64 + j];
    #pragma unroll
    for (int k = 0; k < 64; ++k) {
        const float ck = conv[k];
        const float* wr = mlp_w1_l + k * 128 + 64;
        #pragma unroll
        for (int j = 0; j < 64; ++j) m1[j] = fmaf(ck, wr[j], m1[j]);
    }
    #pragma unroll
    for (int j = 0; j < 64; ++j) m1[j] = siluf(m1[j]);
    #pragma unroll
    for (int j = 0; j < 64; ++j) {
        const float mj = m1[j];
        const float* wr = mlp_w2_l + (64 + j) * 64;
        #pragma unroll
        for (int h = 0; h < 64; ++h) upd[h] = fmaf(mj, wr[h], upd[h]);
    }

    // residual + LayerNorm (reload x; fully per-lane)
    {
        const float* xr = feats + (size_t)nds * 64;
        #pragma unroll
        for (int q = 0; q < 16; ++q)
            *(float4*)&reg[q * 4] = *(const float4*)&xr[q * 4];
    }
    float s1 = 0.f, s2 = 0.f;
    #pragma unroll
    for (int h = 0; h < 64; ++h) {
        float y = reg[h] + upd[h];
        reg[h] = y;
        s1 += y; s2 += y * y;
    }
    float mu  = s1 * (1.0f / 64.0f);
    float var = s2 * (1.0f / 64.0f) - mu * mu;
    float rr  = rsqrtf(var + 1e-5f);
    #pragma unroll
    for (int h = 0; h < 64; ++h)
        reg[h] = (reg[h] - mu) * rr * ln_g_l[h] + ln_b_l[h];
    if (node < N_NODES) {
        float* orow = feats + (size_t)node * 64;
        #pragma unroll
        for (int q = 0; q < 16; ++q)
            *(float4*)&orow[q * 4] = *(const float4*)&reg[q * 4];
    }
}

// ---------------- readout ----------------

__global__ __launch_bounds__(256) void k_readout(const float* __restrict__ feats,
        const int* __restrict__ an,
        const float* __restrict__ ro_w1, const float* __restrict__ ro_b1,
        const float* __restrict__ ro_w2, const float* __restrict__ ro_b2,
        const float* __restrict__ ro_w3, const float* __restrict__ ro_b3,
        const float* __restrict__ atomic_e, float* __restrict__ blockpart) {
    __shared__ float sacc[4];
    int wib  = threadIdx.x >> 6;
    int lane = threadIdx.x & 63;
    int node = blockIdx.x * 4 + wib;
    float e = 0.0f;
    if (node < N_NODES) {
        float x = feats[(size_t)node * HDIM + lane];
        float h1 = ro_b1[lane];
        #pragma unroll 8
        for (int k = 0; k < HDIM; ++k) h1 += bcastf(x, k) * ro_w1[k * HDIM + lane];
        h1 = siluf(h1);
        int j = lane & 31;
        float h2 = ro_b2[j];
        #pragma unroll 8
        for (int k = 0; k < HDIM; ++k) h2 += bcastf(h1, k) * ro_w2[k * 32 + j];
        h2 = siluf(h2);
        float contrib = (lane < 32) ? h2 * ro_w3[j] : 0.0f;
        contrib = waveRedSum(contrib);
        e = contrib + ro_b3[0] + atomic_e[an[node]];
    }
    if (lane == 0) sacc[wib] = e;
    __syncthreads();
    if (threadIdx.x == 0)
        blockpart[blockIdx.x] = sacc[0] + sacc[1] + sacc[2] + sacc[3];
}

__global__ void k_final(const float* __restrict__ blockpart, int nb, float* __restrict__ out) {
    __shared__ float s[256];
    float acc = 0.f;
    for (int i = threadIdx.x; i < nb; i += 256) acc += blockpart[i];
    s[threadIdx.x] = acc; __syncthreads();
    for (int off = 128; off > 0; off >>= 1) {
        if (threadIdx.x < off) s[threadIdx.x] += s[threadIdx.x + off];
        __syncthreads();
    }
    if (threadIdx.x == 0) out[0] = s[0];
}

// ---------------- launch ----------------

extern "C" void kernel_launch(void* const* d_in, const int* in_sizes, int n_in,
                              void* d_out, int out_size, void* d_ws, size_t ws_size,
                              hipStream_t stream) {
    const int*   an       = (const int*)  d_in[0];
    const float* pos      = (const float*)d_in[1];
    const int*   edge     = (const int*)  d_in[2];
    const float* widths   = (const float*)d_in[3];
    const float* embed    = (const float*)d_in[4];
    const float* rad_w1   = (const float*)d_in[5];
    const float* rad_b1   = (const float*)d_in[6];
    const float* rad_w2   = (const float*)d_in[7];
    const float* rad_b2   = (const float*)d_in[8];
    const float* self_w   = (const float*)d_in[9];
    const float* self_b   = (const float*)d_in[10];
    const float* proj_w   = (const float*)d_in[11];
    const float* proj_b   = (const float*)d_in[12];
    const float* mlp_w1   = (const float*)d_in[13];
    const float* mlp_b1   = (const float*)d_in[14];
    const float* mlp_w2   = (const float*)d_in[15];
    const float* mlp_b2   = (const float*)d_in[16];
    const float* ln_g     = (const float*)d_in[17];
    const float* ln_b     = (const float*)d_in[18];
    const float* ro_w1    = (const float*)d_in[19];
    const float* ro_b1    = (const float*)d_in[20];
    const float* ro_w2    = (const float*)d_in[21];
    const float* ro_b2    = (const float*)d_in[22];
    const float* ro_w3    = (const float*)d_in[23];
    const float* ro_b3    = (const float*)d_in[24];
    const float* atomic_e = (const float*)d_in[25];

    char* w = (char*)d_ws;
    auto alloc = [&](size_t bytes) { char* p = w; w += (bytes + 255) & ~(size_t)255; return p; };
    float* feats     = (float*)alloc(sizeof(float) * N_NODES * HDIM);
    float* aggb      = (float*)alloc(sizeof(float) * N_NODES * HDIM);
    float* lut       = (float*)alloc(sizeof(float) * NLAYER * TLUT * HDIM);
    float4* lutQ     = (float4*)alloc(sizeof(float4) * NLAYER * TLUT * 32);
    float* W2s       = (float*)alloc(sizeof(float) * NLAYER * HDIM * HDIM);
    float* b2s       = (float*)alloc(sizeof(float) * NLAYER * HDIM);
    float* Wsp       = (float*)alloc(sizeof(float) * NLAYER * HDIM * HDIM);
    float* bsp       = (float*)alloc(sizeof(float) * NLAYER * HDIM);
    unsigned int* erec = (unsigned int*)alloc(sizeof(unsigned int) * N_EDGES);
    int*   starts    = (int*)  alloc(sizeof(int) * (N_NODES + 1));
    int*   cursor    = (int*)  alloc(sizeof(int) * N_NODES);
    int*   counts    = (int*)  alloc(sizeof(int) * N_NODES);
    int*   partial   = (int*)  alloc(sizeof(int) * 256);
    float* blockpart = (float*)alloc(sizeof(float) * 12500);
    (void)ws_size; (void)in_sizes; (void)n_in; (void)out_size;

    const int* erow = edge;
    const int* ecol = edge + N_EDGES;

    hipMemsetAsync(counts, 0, sizeof(int) * N_NODES, stream);
    k_embed<<<12500, 256, 0, stream>>>(an, embed, feats);
    k_hist<<<6250, 256, 0, stream>>>(erow, counts);
    k_scan1<<<196, 256, 0, stream>>>(counts, partial);
    k_scan2<<<1, 256, 0, stream>>>(partial, 196);
    k_scan3<<<196, 256, 0, stream>>>(counts, partial, starts, cursor);
    k_scatter<<<6250, 256, 0, stream>>>(erow, ecol, pos, cursor, erec);
    k_prep<<<80, 256, 0, stream>>>(rad_w2, self_w, proj_w, W2s, Wsp);
    k_bias<<<5, 64, 0, stream>>>(rad_b2, self_b, proj_w, proj_b, b2s, bsp);
    k_lut<<<NLAYER * TLUT, 64, 0, stream>>>(widths, rad_w1, rad_b1, W2s, b2s, lut);
    k_lutq<<<(NLAYER * TLUT * 16 + 255) / 256, 256, 0, stream>>>(lut, lutQ);

    for (int l = 0; l < NLAYER; ++l) {
        k_agg<<<12500, 256, 0, stream>>>((const float4*)feats,
                                         lutQ + (size_t)l * TLUT * 32,
                                         starts, erec, (float4*)aggb);
        k_node<<<782, 64, 0, stream>>>(feats, aggb,
            Wsp + (size_t)l * HDIM * HDIM, bsp + l * HDIM,
            proj_w + (size_t)l * 2 * HDIM * HDIM,
            mlp_w1 + (size_t)l * HDIM * 2 * HDIM, mlp_b1 + l * 2 * HDIM,
            mlp_w2 + (size_t)l * 2 * HDIM * HDIM, mlp_b2 + l * HDIM,
            ln_g + l * HDIM, ln_b + l * HDIM);
    }

    k_readout<<<12500, 256, 0, stream>>>(feats, an, ro_w1, ro_b1, ro_w2, ro_b2,
                                         ro_w3, ro_b3, atomic_e, blockpart);
    k_final<<<1, 256, 0, stream>>>(blockpart, 12500, (float*)d_out);
}

// Round 9
// 823.303 us; speedup vs baseline: 3.4461x; 3.4461x over previous
//
#include <hip/hip_runtime.h>
#include <math.h>

// Problem constants (from reference)
constexpr int N_NODES = 50000;
constexpr int N_EDGES = 1600000;
constexpr int HDIM    = 64;
constexpr int NLAYER  = 5;
constexpr int NBASIS  = 8;
constexpr int TLUT    = 512;           // radial LUT entries per layer
constexpr float CUT_R = 5.0f;
constexpr float PI_F  = 3.14159265358979f;

__device__ __forceinline__ float bcastf(float v, int l) {
    return __uint_as_float(__builtin_amdgcn_readlane(__float_as_uint(v), l));
}
__device__ __forceinline__ float waveRedSum(float v) {
    for (int off = 32; off > 0; off >>= 1) v += __shfl_xor(v, off, 64);
    return v;
}
__device__ __forceinline__ float siluf(float x) { return x / (1.0f + __expf(-x)); }

// round-to-nearest-even f32 -> bf16 bits
__device__ __forceinline__ unsigned int f2bf(float x) {
    unsigned int b = __float_as_uint(x);
    return (b + 0x7fffu + ((b >> 16) & 1u)) >> 16;
}
__device__ __forceinline__ float bf_lo(unsigned int u) { return __uint_as_float(u << 16); }
__device__ __forceinline__ float bf_hi(unsigned int u) { return __uint_as_float(u & 0xffff0000u); }

// ---------------- setup kernels ----------------

__global__ void k_embed(const int* __restrict__ an, const float* __restrict__ embed,
                        float* __restrict__ feats, unsigned short* __restrict__ featsbf) {
    int i = blockIdx.x * blockDim.x + threadIdx.x;           // N*H threads
    if (i >= N_NODES * HDIM) return;
    int node = i >> 6, h = i & 63;
    float v = embed[an[node] * HDIM + h];
    feats[i] = v;
    featsbf[i] = (unsigned short)f2bf(v);
}

__global__ void k_hist(const int* __restrict__ row, int* __restrict__ counts) {
    int e = blockIdx.x * blockDim.x + threadIdx.x;
    if (e < N_EDGES) atomicAdd(&counts[row[e]], 1);
}

__global__ void k_scan1(const int* __restrict__ counts, int* __restrict__ partial) {
    __shared__ int s[256];
    int i = blockIdx.x * 256 + threadIdx.x;
    int v = (i < N_NODES) ? counts[i] : 0;
    s[threadIdx.x] = v; __syncthreads();
    for (int off = 128; off > 0; off >>= 1) {
        if (threadIdx.x < off) s[threadIdx.x] += s[threadIdx.x + off];
        __syncthreads();
    }
    if (threadIdx.x == 0) partial[blockIdx.x] = s[0];
}

// single-block exclusive scan of block partials (nb <= 256)
__global__ void k_scan2(int* __restrict__ partial, int nb) {
    __shared__ int s[256];
    int v = (threadIdx.x < nb) ? partial[threadIdx.x] : 0;
    s[threadIdx.x] = v; __syncthreads();
    for (int off = 1; off < 256; off <<= 1) {
        int add = (threadIdx.x >= off) ? s[threadIdx.x - off] : 0;
        __syncthreads();
        s[threadIdx.x] += add;
        __syncthreads();
    }
    if (threadIdx.x < nb) partial[threadIdx.x] = s[threadIdx.x] - v;  // exclusive
}

__global__ void k_scan3(const int* __restrict__ counts, const int* __restrict__ partial,
                        int* __restrict__ starts, int* __restrict__ cursor) {
    __shared__ int s[256];
    int i = blockIdx.x * 256 + threadIdx.x;
    int v = (i < N_NODES) ? counts[i] : 0;
    s[threadIdx.x] = v; __syncthreads();
    for (int off = 1; off < 256; off <<= 1) {               // inclusive Hillis-Steele
        int add = (threadIdx.x >= off) ? s[threadIdx.x - off] : 0;
        __syncthreads();
        s[threadIdx.x] += add;
        __syncthreads();
    }
    if (i < N_NODES) {
        int st = partial[blockIdx.x] + s[threadIdx.x] - v;  // exclusive
        starts[i] = st; cursor[i] = st;
    }
    if (i == 0) starts[N_NODES] = N_EDGES;
}

// scatter edges into CSR order; record packed to 4B: (col<<16) | t_fix9.7
__global__ void k_scatter(const int* __restrict__ row, const int* __restrict__ col,
                          const float* __restrict__ pos, int* __restrict__ cursor,
                          unsigned int* __restrict__ erec) {
    int e = blockIdx.x * blockDim.x + threadIdx.x;
    if (e >= N_EDGES) return;
    int r = row[e], c = col[e];
    int p = atomicAdd(&cursor[r], 1);
    float dx = pos[c * 3 + 0] - pos[r * 3 + 0];
    float dy = pos[c * 3 + 1] - pos[r * 3 + 1];
    float dz = pos[c * 3 + 2] - pos[r * 3 + 2];
    float len = sqrtf(dx * dx + dy * dy + dz * dz);
    float t = len * ((float)(TLUT - 1) / CUT_R);
    t = fminf(t, (float)(TLUT - 1));        // exact for len>=cutoff (rbf==0 there)
    unsigned int tfix = (unsigned int)(t * 128.0f);   // 9.7 fixed point, <= 65408
    erec[p] = ((unsigned int)c << 16) | tfix;
}

// W2s[l][k][h] = sum_{m<3} rad_w2[l][k][h*3+m]; Wsp[l][k][h] = (self_w @ proj_top)[k][h]
__global__ void k_prep(const float* __restrict__ rad_w2, const float* __restrict__ self_w,
                       const float* __restrict__ proj_w,
                       float* __restrict__ W2s, float* __restrict__ Wsp) {
    int i = blockIdx.x * blockDim.x + threadIdx.x;          // L*H*H
    if (i >= NLAYER * HDIM * HDIM) return;
    int l = i / (HDIM * HDIM); int rem = i % (HDIM * HDIM);
    int k = rem / HDIM; int h = rem % HDIM;
    const float* w = rad_w2 + ((size_t)l * HDIM + k) * (HDIM * 3) + h * 3;
    W2s[i] = w[0] + w[1] + w[2];
    const float* sw = self_w + ((size_t)l * HDIM + k) * HDIM;
    const float* pw = proj_w + (size_t)l * 2 * HDIM * HDIM;
    float acc = 0.f;
    for (int m = 0; m < HDIM; ++m) acc += sw[m] * pw[m * HDIM + h];
    Wsp[i] = acc;
}

// b2s[l][h] = sum_m rad_b2[l][h*3+m];  bsp[l][h] = self_b@proj_top + proj_b
__global__ void k_bias(const float* __restrict__ rad_b2, const float* __restrict__ self_b,
                       const float* __restrict__ proj_w, const float* __restrict__ proj_b,
                       float* __restrict__ b2s, float* __restrict__ bsp) {
    int i = blockIdx.x * blockDim.x + threadIdx.x;          // L*H
    if (i >= NLAYER * HDIM) return;
    int l = i / HDIM, h = i % HDIM;
    const float* rb2 = rad_b2 + l * HDIM * 3 + h * 3;
    b2s[i] = rb2[0] + rb2[1] + rb2[2];
    float acc = proj_b[l * HDIM + h];
    const float* pw = proj_w + (size_t)l * 2 * HDIM * HDIM;
    const float* sb = self_b + l * HDIM;
    for (int m = 0; m < HDIM; ++m) acc += sb[m] * pw[m * HDIM + h];
    bsp[i] = acc;
}

// radial LUT: lut[l][t][h] = (silu(rbf(len_t)@W1 + b1) @ W2s + b2s)[h]
__global__ void k_lut(const float* __restrict__ widths, const float* __restrict__ rad_w1,
                      const float* __restrict__ rad_b1, const float* __restrict__ W2s,
                      const float* __restrict__ b2s, float* __restrict__ lut) {
    int bid = blockIdx.x;                 // l*TLUT + t
    int l = bid / TLUT, t = bid % TLUT;
    int h = threadIdx.x;                  // 64 threads
    __shared__ float h1s[HDIM];
    float len = (float)t * (CUT_R / (float)(TLUT - 1));
    float cut = 0.0f;
    if (len < CUT_R) cut = 0.5f * (cosf(len * (PI_F / CUT_R)) + 1.0f);
    float acc = rad_b1[l * HDIM + h];
    for (int b = 0; b < NBASIS; ++b) {
        float wb = fmaxf(widths[b], 0.1f);
        float center = (float)b * (CUT_R / (float)(NBASIS - 1));
        float d = (len - center) / wb;
        float rbf = __expf(-0.5f * d * d) * cut;
        acc += rbf * rad_w1[(l * NBASIS + b) * HDIM + h];
    }
    h1s[h] = siluf(acc);
    __syncthreads();
    float o = b2s[l * HDIM + h];
    const float* w2 = W2s + (size_t)l * HDIM * HDIM;
    for (int k = 0; k < HDIM; ++k) o += h1s[k] * w2[k * HDIM + h];
    lut[(size_t)bid * HDIM + h] = o;
}

// lutQb[(l*TLUT+t)*16+j] = uint4; component c (0..3) packs bf16(lut[t][4j+c]) in
// low16 and bf16(lut[t+1][4j+c]) in high16.
__global__ void k_lutq(const float* __restrict__ lut, uint4* __restrict__ lutQb) {
    int i = blockIdx.x * blockDim.x + threadIdx.x;          // L*TLUT*16
    if (i >= NLAYER * TLUT * 16) return;
    int j = i & 15;
    int lt = i >> 4;                       // l*TLUT + t
    int l = lt / TLUT, t = lt % TLUT;
    int t1 = (t < TLUT - 1) ? t + 1 : t;
    const float* r0 = lut + (size_t)(l * TLUT + t)  * HDIM + 4 * j;
    const float* r1 = lut + (size_t)(l * TLUT + t1) * HDIM + 4 * j;
    uint4 o;
    o.x = f2bf(r0[0]) | (f2bf(r1[0]) << 16);
    o.y = f2bf(r0[1]) | (f2bf(r1[1]) << 16);
    o.z = f2bf(r0[2]) | (f2bf(r1[2]) << 16);
    o.w = f2bf(r0[3]) | (f2bf(r1[3]) << 16);
    lutQb[i] = o;
}

// ---------------- per-layer kernels ----------------

// one wave per node, 4 edge slots x 16 lanes (4 channels each).
// Gathered operands are bf16: featsbf row (8B/lane) + packed LUT pair (16B/lane)
// -> 7 cache lines per edge vs 13 for fp32.
__global__ __launch_bounds__(256) void k_agg(const uint2* __restrict__ featsbf2,
                                             const uint4* __restrict__ lutQb_l,
                                             const int* __restrict__ starts,
                                             const unsigned int* __restrict__ erec,
                                             float4* __restrict__ agg4) {
    int wid  = (blockIdx.x * blockDim.x + threadIdx.x) >> 6;
    int lane = threadIdx.x & 63;
    int slot = lane >> 4;
    int j    = lane & 15;
    if (wid >= N_NODES) return;
    int e0 = starts[wid], e1 = starts[wid + 1];
    float ax = 0.f, ay = 0.f, az = 0.f, aw = 0.f;
    #pragma unroll 2
    for (int e = e0 + slot; e < e1; e += 4) {
        unsigned int rec = erec[e];
        int c    = rec >> 16;
        int tfix = rec & 0xffff;
        int i0   = tfix >> 7;
        float f  = (float)(tfix & 127) * (1.0f / 128.0f);
        uint4 qw = lutQb_l[i0 * 16 + j];
        uint2 fb = featsbf2[(size_t)c * 16 + j];
        float w00 = bf_lo(qw.x), w01 = bf_hi(qw.x);
        float w10 = bf_lo(qw.y), w11 = bf_hi(qw.y);
        float w20 = bf_lo(qw.z), w21 = bf_hi(qw.z);
        float w30 = bf_lo(qw.w), w31 = bf_hi(qw.w);
        ax += bf_lo(fb.x) * (w00 + f * (w01 - w00));
        ay += bf_hi(fb.x) * (w10 + f * (w11 - w10));
        az += bf_lo(fb.y) * (w20 + f * (w21 - w20));
        aw += bf_hi(fb.y) * (w30 + f * (w31 - w30));
    }
    // reduce across the 4 slots (lanes j, j+16, j+32, j+48)
    ax += __shfl_xor(ax, 16, 64);  ay += __shfl_xor(ay, 16, 64);
    az += __shfl_xor(az, 16, 64);  aw += __shfl_xor(aw, 16, 64);
    ax += __shfl_xor(ax, 32, 64);  ay += __shfl_xor(ay, 32, 64);
    az += __shfl_xor(az, 32, 64);  aw += __shfl_xor(aw, 32, 64);
    if (slot == 0) agg4[(size_t)wid * 16 + j] = make_float4(ax, ay, az, aw);
}

// 4 waves/block, 16 nodes per wave; lane = output channel. Weights in per-lane
// VGPR arrays (static index); matmul k-operands via wave-uniform ds_read_b128
// broadcasts from a private 8KB LDS region per wave. No __syncthreads needed.
// (round-6 structure: VGPR 120, 80.5us measured; no launch_bounds occupancy arg)
constexpr int NPW = 16;                    // nodes per wave
__global__ __launch_bounds__(256) void k_node(float* __restrict__ feats,
        unsigned short* __restrict__ featsbf,
        const float* __restrict__ agg,
        const float* __restrict__ Wsp_l, const float* __restrict__ bsp_l,
        const float* __restrict__ projw_l,
        const float* __restrict__ mlp_w1_l, const float* __restrict__ mlp_b1_l,
        const float* __restrict__ mlp_w2_l, const float* __restrict__ mlp_b2_l,
        const float* __restrict__ ln_g_l, const float* __restrict__ ln_b_l) {
    __shared__ float Tall[4 * 2 * NPW * 64];   // 32 KB (4 waves x 8 KB)
    const int lane = threadIdx.x & 63;
    const int wib  = threadIdx.x >> 6;
    float* T = Tall + wib * (2 * NPW * 64);
    const int nb0 = blockIdx.x * (4 * NPW) + wib * NPW;
    const float* pb = projw_l + HDIM * HDIM;   // bottom half of proj_w

    // stage x (rows 0..15) and a (rows 16..31); coalesced, 2-way bank (free)
    #pragma unroll 4
    for (int r = 0; r < NPW; ++r) {
        int nd = nb0 + r; nd = (nd < N_NODES) ? nd : (N_NODES - 1);
        T[r * 64 + lane]         = feats[(size_t)nd * 64 + lane];
        T[(NPW + r) * 64 + lane] = agg[(size_t)nd * 64 + lane];
    }

    // conv weights: per-lane columns, static-index register arrays
    float Wa[64], Wb[64];
    #pragma unroll
    for (int k = 0; k < 64; ++k) Wa[k] = Wsp_l[k * 64 + lane];
    #pragma unroll
    for (int k = 0; k < 64; ++k) Wb[k] = pb[k * 64 + lane];
    float bspv = bsp_l[lane];

    asm volatile("s_waitcnt lgkmcnt(0)" ::: "memory");

    // conv = bsp + x@Wsp + a@Pb -> store over a-rows (16..31)
    #pragma unroll 1
    for (int r0 = 0; r0 < NPW; r0 += 4) {
        float c0 = bspv, c1 = bspv, c2 = bspv, c3 = bspv;
        #pragma unroll
        for (int k = 0; k < 64; k += 4) {
            float4 x0 = *(const float4*)&T[(r0 + 0) * 64 + k];
            float4 x1 = *(const float4*)&T[(r0 + 1) * 64 + k];
            float4 x2 = *(const float4*)&T[(r0 + 2) * 64 + k];
            float4 x3 = *(const float4*)&T[(r0 + 3) * 64 + k];
            c0 = fmaf(x0.x, Wa[k], c0); c0 = fmaf(x0.y, Wa[k+1], c0); c0 = fmaf(x0.z, Wa[k+2], c0); c0 = fmaf(x0.w, Wa[k+3], c0);
            c1 = fmaf(x1.x, Wa[k], c1); c1 = fmaf(x1.y, Wa[k+1], c1); c1 = fmaf(x1.z, Wa[k+2], c1); c1 = fmaf(x1.w, Wa[k+3], c1);
            c2 = fmaf(x2.x, Wa[k], c2); c2 = fmaf(x2.y, Wa[k+1], c2); c2 = fmaf(x2.z, Wa[k+2], c2); c2 = fmaf(x2.w, Wa[k+3], c2);
            c3 = fmaf(x3.x, Wa[k], c3); c3 = fmaf(x3.y, Wa[k+1], c3); c3 = fmaf(x3.z, Wa[k+2], c3); c3 = fmaf(x3.w, Wa[k+3], c3);
        }
        #pragma unroll
        for (int k = 0; k < 64; k += 4) {
            float4 a0 = *(const float4*)&T[(NPW + r0 + 0) * 64 + k];
            float4 a1 = *(const float4*)&T[(NPW + r0 + 1) * 64 + k];
            float4 a2 = *(const float4*)&T[(NPW + r0 + 2) * 64 + k];
            float4 a3 = *(const float4*)&T[(NPW + r0 + 3) * 64 + k];
            c0 = fmaf(a0.x, Wb[k], c0); c0 = fmaf(a0.y, Wb[k+1], c0); c0 = fmaf(a0.z, Wb[k+2], c0); c0 = fmaf(a0.w, Wb[k+3], c0);
            c1 = fmaf(a1.x, Wb[k], c1); c1 = fmaf(a1.y, Wb[k+1], c1); c1 = fmaf(a1.z, Wb[k+2], c1); c1 = fmaf(a1.w, Wb[k+3], c1);
            c2 = fmaf(a2.x, Wb[k], c2); c2 = fmaf(a2.y, Wb[k+1], c2); c2 = fmaf(a2.z, Wb[k+2], c2); c2 = fmaf(a2.w, Wb[k+3], c2);
            c3 = fmaf(a3.x, Wb[k], c3); c3 = fmaf(a3.y, Wb[k+1], c3); c3 = fmaf(a3.z, Wb[k+2], c3); c3 = fmaf(a3.w, Wb[k+3], c3);
        }
        T[(NPW + r0 + 0) * 64 + lane] = c0;
        T[(NPW + r0 + 1) * 64 + lane] = c1;
        T[(NPW + r0 + 2) * 64 + lane] = c2;
        T[(NPW + r0 + 3) * 64 + lane] = c3;
    }

    // mlp1 weights (reuse Wa/Wb register budget)
    float W1a[64], W1b[64];
    #pragma unroll
    for (int k = 0; k < 64; ++k) W1a[k] = mlp_w1_l[k * 128 + lane];
    #pragma unroll
    for (int k = 0; k < 64; ++k) W1b[k] = mlp_w1_l[k * 128 + 64 + lane];
    float b1a = mlp_b1_l[lane], b1b = mlp_b1_l[64 + lane];

    asm volatile("s_waitcnt lgkmcnt(0)" ::: "memory");

    // m1 = silu(conv@W1 + b1): node r -> row r (ch 0..63) and row NPW+r (ch 64..127)
    #pragma unroll 1
    for (int r0 = 0; r0 < NPW; r0 += 2) {
        float m00 = b1a, m01 = b1b, m10 = b1a, m11 = b1b;
        #pragma unroll
        for (int k = 0; k < 64; k += 4) {
            float4 x0 = *(const float4*)&T[(NPW + r0 + 0) * 64 + k];
            float4 x1 = *(const float4*)&T[(NPW + r0 + 1) * 64 + k];
            m00 = fmaf(x0.x, W1a[k], m00); m00 = fmaf(x0.y, W1a[k+1], m00); m00 = fmaf(x0.z, W1a[k+2], m00); m00 = fmaf(x0.w, W1a[k+3], m00);
            m01 = fmaf(x0.x, W1b[k], m01); m01 = fmaf(x0.y, W1b[k+1], m01); m01 = fmaf(x0.z, W1b[k+2], m01); m01 = fmaf(x0.w, W1b[k+3], m01);
            m10 = fmaf(x1.x, W1a[k], m10); m10 = fmaf(x1.y, W1a[k+1], m10); m10 = fmaf(x1.z, W1a[k+2], m10); m10 = fmaf(x1.w, W1a[k+3], m10);
            m11 = fmaf(x1.x, W1b[k], m11); m11 = fmaf(x1.y, W1b[k+1], m11); m11 = fmaf(x1.z, W1b[k+2], m11); m11 = fmaf(x1.w, W1b[k+3], m11);
        }
        T[(r0 + 0) * 64 + lane]       = siluf(m00);
        T[(NPW + r0 + 0) * 64 + lane] = siluf(m01);
        T[(r0 + 1) * 64 + lane]       = siluf(m10);
        T[(NPW + r0 + 1) * 64 + lane] = siluf(m11);
    }

    // mlp2 weights
    float W2c[128];
    #pragma unroll
    for (int k = 0; k < 128; ++k) W2c[k] = mlp_w2_l[k * 64 + lane];
    float b2v = mlp_b2_l[lane];
    float gv  = ln_g_l[lane], bv = ln_b_l[lane];

    asm volatile("s_waitcnt lgkmcnt(0)" ::: "memory");

    // upd = m1@W2 + b2; then residual + LayerNorm, write feats (fp32 + bf16)
    #pragma unroll 1
    for (int r0 = 0; r0 < NPW; r0 += 2) {
        float u0 = b2v, u1 = b2v;
        #pragma unroll
        for (int k = 0; k < 64; k += 4) {
            float4 x0 = *(const float4*)&T[(r0 + 0) * 64 + k];
            float4 x1 = *(const float4*)&T[(r0 + 1) * 64 + k];
            u0 = fmaf(x0.x, W2c[k], u0); u0 = fmaf(x0.y, W2c[k+1], u0); u0 = fmaf(x0.z, W2c[k+2], u0); u0 = fmaf(x0.w, W2c[k+3], u0);
            u1 = fmaf(x1.x, W2c[k], u1); u1 = fmaf(x1.y, W2c[k+1], u1); u1 = fmaf(x1.z, W2c[k+2], u1); u1 = fmaf(x1.w, W2c[k+3], u1);
        }
        #pragma unroll
        for (int k = 0; k < 64; k += 4) {
            float4 x0 = *(const float4*)&T[(NPW + r0 + 0) * 64 + k];
            float4 x1 = *(const float4*)&T[(NPW + r0 + 1) * 64 + k];
            u0 = fmaf(x0.x, W2c[64+k], u0); u0 = fmaf(x0.y, W2c[64+k+1], u0); u0 = fmaf(x0.z, W2c[64+k+2], u0); u0 = fmaf(x0.w, W2c[64+k+3], u0);
            u1 = fmaf(x1.x, W2c[64+k], u1); u1 = fmaf(x1.y, W2c[64+k+1], u1); u1 = fmaf(x1.z, W2c[64+k+2], u1); u1 = fmaf(x1.w, W2c[64+k+3], u1);
        }
        int nd0 = nb0 + r0, nd1 = nb0 + r0 + 1;
        int nd0s = (nd0 < N_NODES) ? nd0 : (N_NODES - 1);
        int nd1s = (nd1 < N_NODES) ? nd1 : (N_NODES - 1);
        float y0 = feats[(size_t)nd0s * 64 + lane] + u0;
        float y1 = feats[(size_t)nd1s * 64 + lane] + u1;
        float p0 = y0, q0 = y0 * y0, p1 = y1, q1 = y1 * y1;
        #pragma unroll
        for (int off = 32; off > 0; off >>= 1) {
            p0 += __shfl_xor(p0, off, 64);  q0 += __shfl_xor(q0, off, 64);
            p1 += __shfl_xor(p1, off, 64);  q1 += __shfl_xor(q1, off, 64);
        }
        float mu0 = p0 * (1.0f / 64.0f), var0 = q0 * (1.0f / 64.0f) - mu0 * mu0;
        float mu1 = p1 * (1.0f / 64.0f), var1 = q1 * (1.0f / 64.0f) - mu1 * mu1;
        float rr0 = rsqrtf(var0 + 1e-5f), rr1 = rsqrtf(var1 + 1e-5f);
        float o0 = (y0 - mu0) * rr0 * gv + bv;
        float o1 = (y1 - mu1) * rr1 * gv + bv;
        if (nd0 < N_NODES) {
            feats[(size_t)nd0 * 64 + lane] = o0;
            featsbf[(size_t)nd0 * 64 + lane] = (unsigned short)f2bf(o0);
        }
        if (nd1 < N_NODES) {
            feats[(size_t)nd1 * 64 + lane] = o1;
            featsbf[(size_t)nd1 * 64 + lane] = (unsigned short)f2bf(o1);
        }
    }
}

// ---------------- readout ----------------

__global__ __launch_bounds__(256) void k_readout(const float* __restrict__ feats,
        const int* __restrict__ an,
        const float* __restrict__ ro_w1, const float* __restrict__ ro_b1,
        const float* __restrict__ ro_w2, const float* __restrict__ ro_b2,
        const float* __restrict__ ro_w3, const float* __restrict__ ro_b3,
        const float* __restrict__ atomic_e, float* __restrict__ blockpart) {
    __shared__ float sacc[4];
    int wib  = threadIdx.x >> 6;
    int lane = threadIdx.x & 63;
    int node = blockIdx.x * 4 + wib;
    float e = 0.0f;
    if (node < N_NODES) {
        float x = feats[(size_t)node * HDIM + lane];
        float h1 = ro_b1[lane];
        #pragma unroll 8
        for (int k = 0; k < HDIM; ++k) h1 += bcastf(x, k) * ro_w1[k * HDIM + lane];
        h1 = siluf(h1);
        int j = lane & 31;
        float h2 = ro_b2[j];
        #pragma unroll 8
        for (int k = 0; k < HDIM; ++k) h2 += bcastf(h1, k) * ro_w2[k * 32 + j];
        h2 = siluf(h2);
        float contrib = (lane < 32) ? h2 * ro_w3[j] : 0.0f;
        contrib = waveRedSum(contrib);
        e = contrib + ro_b3[0] + atomic_e[an[node]];
    }
    if (lane == 0) sacc[wib] = e;
    __syncthreads();
    if (threadIdx.x == 0)
        blockpart[blockIdx.x] = sacc[0] + sacc[1] + sacc[2] + sacc[3];
}

__global__ void k_final(const float* __restrict__ blockpart, int nb, float* __restrict__ out) {
    __shared__ float s[256];
    float acc = 0.f;
    for (int i = threadIdx.x; i < nb; i += 256) acc += blockpart[i];
    s[threadIdx.x] = acc; __syncthreads();
    for (int off = 128; off > 0; off >>= 1) {
        if (threadIdx.x < off) s[threadIdx.x] += s[threadIdx.x + off];
        __syncthreads();
    }
    if (threadIdx.x == 0) out[0] = s[0];
}

// ---------------- launch ----------------

extern "C" void kernel_launch(void* const* d_in, const int* in_sizes, int n_in,
                              void* d_out, int out_size, void* d_ws, size_t ws_size,
                              hipStream_t stream) {
    const int*   an       = (const int*)  d_in[0];
    const float* pos      = (const float*)d_in[1];
    const int*   edge     = (const int*)  d_in[2];
    const float* widths   = (const float*)d_in[3];
    const float* embed    = (const float*)d_in[4];
    const float* rad_w1   = (const float*)d_in[5];
    const float* rad_b1   = (const float*)d_in[6];
    const float* rad_w2   = (const float*)d_in[7];
    const float* rad_b2   = (const float*)d_in[8];
    const float* self_w   = (const float*)d_in[9];
    const float* self_b   = (const float*)d_in[10];
    const float* proj_w   = (const float*)d_in[11];
    const float* proj_b   = (const float*)d_in[12];
    const float* mlp_w1   = (const float*)d_in[13];
    const float* mlp_b1   = (const float*)d_in[14];
    const float* mlp_w2   = (const float*)d_in[15];
    const float* mlp_b2   = (const float*)d_in[16];
    const float* ln_g     = (const float*)d_in[17];
    const float* ln_b     = (const float*)d_in[18];
    const float* ro_w1    = (const float*)d_in[19];
    const float* ro_b1    = (const float*)d_in[20];
    const float* ro_w2    = (const float*)d_in[21];
    const float* ro_b2    = (const float*)d_in[22];
    const float* ro_w3    = (const float*)d_in[23];
    const float* ro_b3    = (const float*)d_in[24];
    const float* atomic_e = (const float*)d_in[25];

    char* w = (char*)d_ws;
    auto alloc = [&](size_t bytes) { char* p = w; w += (bytes + 255) & ~(size_t)255; return p; };
    float* feats     = (float*)alloc(sizeof(float) * N_NODES * HDIM);
    float* aggb      = (float*)alloc(sizeof(float) * N_NODES * HDIM);
    unsigned short* featsbf = (unsigned short*)alloc(sizeof(unsigned short) * N_NODES * HDIM);
    float* lut       = (float*)alloc(sizeof(float) * NLAYER * TLUT * HDIM);
    uint4* lutQb     = (uint4*)alloc(sizeof(uint4) * NLAYER * TLUT * 16);
    float* W2s       = (float*)alloc(sizeof(float) * NLAYER * HDIM * HDIM);
    float* b2s       = (float*)alloc(sizeof(float) * NLAYER * HDIM);
    float* Wsp       = (float*)alloc(sizeof(float) * NLAYER * HDIM * HDIM);
    float* bsp       = (float*)alloc(sizeof(float) * NLAYER * HDIM);
    unsigned int* erec = (unsigned int*)alloc(sizeof(unsigned int) * N_EDGES);
    int*   starts    = (int*)  alloc(sizeof(int) * (N_NODES + 1));
    int*   cursor    = (int*)  alloc(sizeof(int) * N_NODES);
    int*   counts    = (int*)  alloc(sizeof(int) * N_NODES);
    int*   partial   = (int*)  alloc(sizeof(int) * 256);
    float* blockpart = (float*)alloc(sizeof(float) * 12500);
    (void)ws_size; (void)in_sizes; (void)n_in; (void)out_size;

    const int* erow = edge;
    const int* ecol = edge + N_EDGES;

    hipMemsetAsync(counts, 0, sizeof(int) * N_NODES, stream);
    k_embed<<<12500, 256, 0, stream>>>(an, embed, feats, featsbf);
    k_hist<<<6250, 256, 0, stream>>>(erow, counts);
    k_scan1<<<196, 256, 0, stream>>>(counts, partial);
    k_scan2<<<1, 256, 0, stream>>>(partial, 196);
    k_scan3<<<196, 256, 0, stream>>>(counts, partial, starts, cursor);
    k_scatter<<<6250, 256, 0, stream>>>(erow, ecol, pos, cursor, erec);
    k_prep<<<80, 256, 0, stream>>>(rad_w2, self_w, proj_w, W2s, Wsp);
    k_bias<<<5, 64, 0, stream>>>(rad_b2, self_b, proj_w, proj_b, b2s, bsp);
    k_lut<<<NLAYER * TLUT, 64, 0, stream>>>(widths, rad_w1, rad_b1, W2s, b2s, lut);
    k_lutq<<<(NLAYER * TLUT * 16 + 255) / 256, 256, 0, stream>>>(lut, lutQb);

    for (int l = 0; l < NLAYER; ++l) {
        k_agg<<<12500, 256, 0, stream>>>((const uint2*)featsbf,
                                         lutQb + (size_t)l * TLUT * 16,
                                         starts, erec, (float4*)aggb);
        k_node<<<782, 256, 0, stream>>>(feats, featsbf, aggb,
            Wsp + (size_t)l * HDIM * HDIM, bsp + l * HDIM,
            proj_w + (size_t)l * 2 * HDIM * HDIM,
            mlp_w1 + (size_t)l * HDIM * 2 * HDIM, mlp_b1 + l * 2 * HDIM,
            mlp_w2 + (size_t)l * 2 * HDIM * HDIM, mlp_b2 + l * HDIM,
            ln_g + l * HDIM, ln_b + l * HDIM);
    }

    k_readout<<<12500, 256, 0, stream>>>(feats, an, ro_w1, ro_b1, ro_w2, ro_b2,
                                         ro_w3, ro_b3, atomic_e, blockpart);
    k_final<<<1, 256, 0, stream>>>(blockpart, 12500, (float*)d_out);
}

// Round 10
// 770.379 us; speedup vs baseline: 3.6828x; 1.0687x over previous
//
#include <hip/hip_runtime.h>
#include <math.h>

// Problem constants (from reference)
constexpr int N_NODES = 50000;
constexpr int N_EDGES = 1600000;
constexpr int HDIM    = 64;
constexpr int NLAYER  = 5;
constexpr int NBASIS  = 8;
constexpr int TLUT    = 512;           // radial LUT entries per layer
constexpr float CUT_R = 5.0f;
constexpr float PI_F  = 3.14159265358979f;

__device__ __forceinline__ float bcastf(float v, int l) {
    return __uint_as_float(__builtin_amdgcn_readlane(__float_as_uint(v), l));
}
__device__ __forceinline__ float waveRedSum(float v) {
    for (int off = 32; off > 0; off >>= 1) v += __shfl_xor(v, off, 64);
    return v;
}
__device__ __forceinline__ float siluf(float x) { return x / (1.0f + __expf(-x)); }

// round-to-nearest-even f32 -> bf16 bits
__device__ __forceinline__ unsigned int f2bf(float x) {
    unsigned int b = __float_as_uint(x);
    return (b + 0x7fffu + ((b >> 16) & 1u)) >> 16;
}
__device__ __forceinline__ float bf_lo(unsigned int u) { return __uint_as_float(u << 16); }
__device__ __forceinline__ float bf_hi(unsigned int u) { return __uint_as_float(u & 0xffff0000u); }

// ---------------- setup kernels ----------------

__global__ void k_embed(const int* __restrict__ an, const float* __restrict__ embed,
                        float* __restrict__ feats, unsigned short* __restrict__ featsbf) {
    int i = blockIdx.x * blockDim.x + threadIdx.x;           // N*H threads
    if (i >= N_NODES * HDIM) return;
    int node = i >> 6, h = i & 63;
    float v = embed[an[node] * HDIM + h];
    feats[i] = v;
    featsbf[i] = (unsigned short)f2bf(v);
}

__global__ void k_hist(const int* __restrict__ row, int* __restrict__ counts) {
    int e = blockIdx.x * blockDim.x + threadIdx.x;
    if (e < N_EDGES) atomicAdd(&counts[row[e]], 1);
}

__global__ void k_scan1(const int* __restrict__ counts, int* __restrict__ partial) {
    __shared__ int s[256];
    int i = blockIdx.x * 256 + threadIdx.x;
    int v = (i < N_NODES) ? counts[i] : 0;
    s[threadIdx.x] = v; __syncthreads();
    for (int off = 128; off > 0; off >>= 1) {
        if (threadIdx.x < off) s[threadIdx.x] += s[threadIdx.x + off];
        __syncthreads();
    }
    if (threadIdx.x == 0) partial[blockIdx.x] = s[0];
}

// single-block exclusive scan of block partials (nb <= 256)
__global__ void k_scan2(int* __restrict__ partial, int nb) {
    __shared__ int s[256];
    int v = (threadIdx.x < nb) ? partial[threadIdx.x] : 0;
    s[threadIdx.x] = v; __syncthreads();
    for (int off = 1; off < 256; off <<= 1) {
        int add = (threadIdx.x >= off) ? s[threadIdx.x - off] : 0;
        __syncthreads();
        s[threadIdx.x] += add;
        __syncthreads();
    }
    if (threadIdx.x < nb) partial[threadIdx.x] = s[threadIdx.x] - v;  // exclusive
}

__global__ void k_scan3(const int* __restrict__ counts, const int* __restrict__ partial,
                        int* __restrict__ starts, int* __restrict__ cursor) {
    __shared__ int s[256];
    int i = blockIdx.x * 256 + threadIdx.x;
    int v = (i < N_NODES) ? counts[i] : 0;
    s[threadIdx.x] = v; __syncthreads();
    for (int off = 1; off < 256; off <<= 1) {               // inclusive Hillis-Steele
        int add = (threadIdx.x >= off) ? s[threadIdx.x - off] : 0;
        __syncthreads();
        s[threadIdx.x] += add;
        __syncthreads();
    }
    if (i < N_NODES) {
        int st = partial[blockIdx.x] + s[threadIdx.x] - v;  // exclusive
        starts[i] = st; cursor[i] = st;
    }
    if (i == 0) starts[N_NODES] = N_EDGES;
}

// scatter edges into CSR order; record packed to 4B: (col<<16) | t_fix9.7
__global__ void k_scatter(const int* __restrict__ row, const int* __restrict__ col,
                          const float* __restrict__ pos, int* __restrict__ cursor,
                          unsigned int* __restrict__ erec) {
    int e = blockIdx.x * blockDim.x + threadIdx.x;
    if (e >= N_EDGES) return;
    int r = row[e], c = col[e];
    int p = atomicAdd(&cursor[r], 1);
    float dx = pos[c * 3 + 0] - pos[r * 3 + 0];
    float dy = pos[c * 3 + 1] - pos[r * 3 + 1];
    float dz = pos[c * 3 + 2] - pos[r * 3 + 2];
    float len = sqrtf(dx * dx + dy * dy + dz * dz);
    float t = len * ((float)(TLUT - 1) / CUT_R);
    t = fminf(t, (float)(TLUT - 1));        // exact for len>=cutoff (rbf==0 there)
    unsigned int tfix = (unsigned int)(t * 128.0f);   // 9.7 fixed point, <= 65408
    erec[p] = ((unsigned int)c << 16) | tfix;
}

// W2s[l][k][h] = sum_{m<3} rad_w2[l][k][h*3+m]; Wsp[l][k][h] = (self_w @ proj_top)[k][h]
__global__ void k_prep(const float* __restrict__ rad_w2, const float* __restrict__ self_w,
                       const float* __restrict__ proj_w,
                       float* __restrict__ W2s, float* __restrict__ Wsp) {
    int i = blockIdx.x * blockDim.x + threadIdx.x;          // L*H*H
    if (i >= NLAYER * HDIM * HDIM) return;
    int l = i / (HDIM * HDIM); int rem = i % (HDIM * HDIM);
    int k = rem / HDIM; int h = rem % HDIM;
    const float* w = rad_w2 + ((size_t)l * HDIM + k) * (HDIM * 3) + h * 3;
    W2s[i] = w[0] + w[1] + w[2];
    const float* sw = self_w + ((size_t)l * HDIM + k) * HDIM;
    const float* pw = proj_w + (size_t)l * 2 * HDIM * HDIM;
    float acc = 0.f;
    for (int m = 0; m < HDIM; ++m) acc += sw[m] * pw[m * HDIM + h];
    Wsp[i] = acc;
}

// b2s[l][h] = sum_m rad_b2[l][h*3+m];  bsp[l][h] = self_b@proj_top + proj_b
__global__ void k_bias(const float* __restrict__ rad_b2, const float* __restrict__ self_b,
                       const float* __restrict__ proj_w, const float* __restrict__ proj_b,
                       float* __restrict__ b2s, float* __restrict__ bsp) {
    int i = blockIdx.x * blockDim.x + threadIdx.x;          // L*H
    if (i >= NLAYER * HDIM) return;
    int l = i / HDIM, h = i % HDIM;
    const float* rb2 = rad_b2 + l * HDIM * 3 + h * 3;
    b2s[i] = rb2[0] + rb2[1] + rb2[2];
    float acc = proj_b[l * HDIM + h];
    const float* pw = proj_w + (size_t)l * 2 * HDIM * HDIM;
    const float* sb = self_b + l * HDIM;
    for (int m = 0; m < HDIM; ++m) acc += sb[m] * pw[m * HDIM + h];
    bsp[i] = acc;
}

// radial LUT: lut[l][t][h] = (silu(rbf(len_t)@W1 + b1) @ W2s + b2s)[h]
__global__ void k_lut(const float* __restrict__ widths, const float* __restrict__ rad_w1,
                      const float* __restrict__ rad_b1, const float* __restrict__ W2s,
                      const float* __restrict__ b2s, float* __restrict__ lut) {
    int bid = blockIdx.x;                 // l*TLUT + t
    int l = bid / TLUT, t = bid % TLUT;
    int h = threadIdx.x;                  // 64 threads
    __shared__ float h1s[HDIM];
    float len = (float)t * (CUT_R / (float)(TLUT - 1));
    float cut = 0.0f;
    if (len < CUT_R) cut = 0.5f * (cosf(len * (PI_F / CUT_R)) + 1.0f);
    float acc = rad_b1[l * HDIM + h];
    for (int b = 0; b < NBASIS; ++b) {
        float wb = fmaxf(widths[b], 0.1f);
        float center = (float)b * (CUT_R / (float)(NBASIS - 1));
        float d = (len - center) / wb;
        float rbf = __expf(-0.5f * d * d) * cut;
        acc += rbf * rad_w1[(l * NBASIS + b) * HDIM + h];
    }
    h1s[h] = siluf(acc);
    __syncthreads();
    float o = b2s[l * HDIM + h];
    const float* w2 = W2s + (size_t)l * HDIM * HDIM;
    for (int k = 0; k < HDIM; ++k) o += h1s[k] * w2[k * HDIM + h];
    lut[(size_t)bid * HDIM + h] = o;
}

// lutQb[(l*TLUT+t)*16+j] = uint4; component c (0..3) packs bf16(lut[t][4j+c]) in
// low16 and bf16(lut[t+1][4j+c]) in high16.
__global__ void k_lutq(const float* __restrict__ lut, uint4* __restrict__ lutQb) {
    int i = blockIdx.x * blockDim.x + threadIdx.x;          // L*TLUT*16
    if (i >= NLAYER * TLUT * 16) return;
    int j = i & 15;
    int lt = i >> 4;                       // l*TLUT + t
    int l = lt / TLUT, t = lt % TLUT;
    int t1 = (t < TLUT - 1) ? t + 1 : t;
    const float* r0 = lut + (size_t)(l * TLUT + t)  * HDIM + 4 * j;
    const float* r1 = lut + (size_t)(l * TLUT + t1) * HDIM + 4 * j;
    uint4 o;
    o.x = f2bf(r0[0]) | (f2bf(r1[0]) << 16);
    o.y = f2bf(r0[1]) | (f2bf(r1[1]) << 16);
    o.z = f2bf(r0[2]) | (f2bf(r1[2]) << 16);
    o.w = f2bf(r0[3]) | (f2bf(r1[3]) << 16);
    lutQb[i] = o;
}

// ---------------- per-layer kernels ----------------

// one wave per node, 4 edge slots x 16 lanes (4 channels each).
// Gathered operands are bf16: featsbf row (8B/lane) + packed LUT pair (16B/lane)
__global__ __launch_bounds__(256) void k_agg(const uint2* __restrict__ featsbf2,
                                             const uint4* __restrict__ lutQb_l,
                                             const int* __restrict__ starts,
                                             const unsigned int* __restrict__ erec,
                                             float4* __restrict__ agg4) {
    int wid  = (blockIdx.x * blockDim.x + threadIdx.x) >> 6;
    int lane = threadIdx.x & 63;
    int slot = lane >> 4;
    int j    = lane & 15;
    if (wid >= N_NODES) return;
    int e0 = starts[wid], e1 = starts[wid + 1];
    float ax = 0.f, ay = 0.f, az = 0.f, aw = 0.f;
    #pragma unroll 2
    for (int e = e0 + slot; e < e1; e += 4) {
        unsigned int rec = erec[e];
        int c    = rec >> 16;
        int tfix = rec & 0xffff;
        int i0   = tfix >> 7;
        float f  = (float)(tfix & 127) * (1.0f / 128.0f);
        uint4 qw = lutQb_l[i0 * 16 + j];
        uint2 fb = featsbf2[(size_t)c * 16 + j];
        float w00 = bf_lo(qw.x), w01 = bf_hi(qw.x);
        float w10 = bf_lo(qw.y), w11 = bf_hi(qw.y);
        float w20 = bf_lo(qw.z), w21 = bf_hi(qw.z);
        float w30 = bf_lo(qw.w), w31 = bf_hi(qw.w);
        ax += bf_lo(fb.x) * (w00 + f * (w01 - w00));
        ay += bf_hi(fb.x) * (w10 + f * (w11 - w10));
        az += bf_lo(fb.y) * (w20 + f * (w21 - w20));
        aw += bf_hi(fb.y) * (w30 + f * (w31 - w30));
    }
    // reduce across the 4 slots (lanes j, j+16, j+32, j+48)
    ax += __shfl_xor(ax, 16, 64);  ay += __shfl_xor(ay, 16, 64);
    az += __shfl_xor(az, 16, 64);  aw += __shfl_xor(aw, 16, 64);
    ax += __shfl_xor(ax, 32, 64);  ay += __shfl_xor(ay, 32, 64);
    az += __shfl_xor(az, 32, 64);  aw += __shfl_xor(aw, 32, 64);
    if (slot == 0) agg4[(size_t)wid * 16 + j] = make_float4(ax, ay, az, aw);
}

// k_node v2: 64 nodes/block, lane = node, wave = 16-channel output slice.
// Node rows in LDS (pitch 65, per-lane b128 reads); weights wave-uniform ->
// s_load into SGPRs (v_fmac v,s,v). LN via cross-wave LDS partials.
constexpr int LP = 65;                      // LDS row pitch (floats)
__global__ __launch_bounds__(256) void k_node(float* __restrict__ feats,
        unsigned short* __restrict__ featsbf,
        const float* __restrict__ agg,
        const float* __restrict__ Wsp_l, const float* __restrict__ bsp_l,
        const float* __restrict__ projw_l,
        const float* __restrict__ mlp_w1_l, const float* __restrict__ mlp_b1_l,
        const float* __restrict__ mlp_w2_l, const float* __restrict__ mlp_b2_l,
        const float* __restrict__ ln_g_l, const float* __restrict__ ln_b_l) {
    __shared__ float X[64 * LP];            // x -> conv -> x(restaged) -> y
    __shared__ float A[64 * LP];            // a -> m1_lo
    __shared__ float B[64 * LP];            // m1_hi
    __shared__ float P1[256], P2[256];      // LN partials [node*4 + wave]
    const int tid  = threadIdx.x;
    const int lane = tid & 63;
    const int wib  = tid >> 6;
    const int h0   = __builtin_amdgcn_readfirstlane(wib) * 16;  // provably uniform
    const int nb0  = blockIdx.x * 64;
    const float* pb = projw_l + HDIM * HDIM;

    // stage x->X, a->A (thread: rows wib, wib+4, ..., col=lane; coalesced)
    #pragma unroll 4
    for (int i = 0; i < 16; ++i) {
        int r  = wib + i * 4;
        int nd = nb0 + r; nd = (nd < N_NODES) ? nd : (N_NODES - 1);
        X[r * LP + lane] = feats[(size_t)nd * 64 + lane];
        A[r * LP + lane] = agg[(size_t)nd * 64 + lane];
    }
    __syncthreads();

    float acc[16];
    // ---- conv channels [h0, h0+16) for node = lane ----
    #pragma unroll
    for (int j = 0; j < 16; ++j) acc[j] = bsp_l[h0 + j];
    #pragma unroll 1
    for (int kc = 0; kc < 4; ++kc) {        // x @ Wsp
        float ch[16];
        float4 t0 = *(const float4*)&X[lane * LP + kc * 16 + 0];
        float4 t1 = *(const float4*)&X[lane * LP + kc * 16 + 4];
        float4 t2 = *(const float4*)&X[lane * LP + kc * 16 + 8];
        float4 t3 = *(const float4*)&X[lane * LP + kc * 16 + 12];
        ch[0]=t0.x; ch[1]=t0.y; ch[2]=t0.z; ch[3]=t0.w;
        ch[4]=t1.x; ch[5]=t1.y; ch[6]=t1.z; ch[7]=t1.w;
        ch[8]=t2.x; ch[9]=t2.y; ch[10]=t2.z; ch[11]=t2.w;
        ch[12]=t3.x; ch[13]=t3.y; ch[14]=t3.z; ch[15]=t3.w;
        const float* wb0 = Wsp_l + (kc * 16) * 64 + h0;
        #pragma unroll
        for (int kk = 0; kk < 16; ++kk) {
            const float* wr = wb0 + kk * 64;
            #pragma unroll
            for (int j = 0; j < 16; ++j) acc[j] = fmaf(ch[kk], wr[j], acc[j]);
        }
    }
    #pragma unroll 1
    for (int kc = 0; kc < 4; ++kc) {        // a @ Pb
        float ch[16];
        float4 t0 = *(const float4*)&A[lane * LP + kc * 16 + 0];
        float4 t1 = *(const float4*)&A[lane * LP + kc * 16 + 4];
        float4 t2 = *(const float4*)&A[lane * LP + kc * 16 + 8];
        float4 t3 = *(const float4*)&A[lane * LP + kc * 16 + 12];
        ch[0]=t0.x; ch[1]=t0.y; ch[2]=t0.z; ch[3]=t0.w;
        ch[4]=t1.x; ch[5]=t1.y; ch[6]=t1.z; ch[7]=t1.w;
        ch[8]=t2.x; ch[9]=t2.y; ch[10]=t2.z; ch[11]=t2.w;
        ch[12]=t3.x; ch[13]=t3.y; ch[14]=t3.z; ch[15]=t3.w;
        const float* wb0 = pb + (kc * 16) * 64 + h0;
        #pragma unroll
        for (int kk = 0; kk < 16; ++kk) {
            const float* wr = wb0 + kk * 64;
            #pragma unroll
            for (int j = 0; j < 16; ++j) acc[j] = fmaf(ch[kk], wr[j], acc[j]);
        }
    }
    __syncthreads();                        // all reads of X done before overwrite
    #pragma unroll
    for (int c = 0; c < 4; ++c)             // conv -> X[lane][h0..h0+16)
        *(float4*)&X[lane * LP + h0 + 4 * c] =
            make_float4(acc[4*c], acc[4*c+1], acc[4*c+2], acc[4*c+3]);
    __syncthreads();

    // ---- m1_lo channels [h0, h0+16) -> A; m1_hi [64+h0, 64+h0+16) -> B ----
    {
        float accL[16], accH[16];
        #pragma unroll
        for (int j = 0; j < 16; ++j) { accL[j] = mlp_b1_l[h0 + j]; accH[j] = mlp_b1_l[64 + h0 + j]; }
        #pragma unroll 1
        for (int kc = 0; kc < 4; ++kc) {
            float ch[16];
            float4 t0 = *(const float4*)&X[lane * LP + kc * 16 + 0];
            float4 t1 = *(const float4*)&X[lane * LP + kc * 16 + 4];
            float4 t2 = *(const float4*)&X[lane * LP + kc * 16 + 8];
            float4 t3 = *(const float4*)&X[lane * LP + kc * 16 + 12];
            ch[0]=t0.x; ch[1]=t0.y; ch[2]=t0.z; ch[3]=t0.w;
            ch[4]=t1.x; ch[5]=t1.y; ch[6]=t1.z; ch[7]=t1.w;
            ch[8]=t2.x; ch[9]=t2.y; ch[10]=t2.z; ch[11]=t2.w;
            ch[12]=t3.x; ch[13]=t3.y; ch[14]=t3.z; ch[15]=t3.w;
            const float* wbL = mlp_w1_l + (kc * 16) * 128 + h0;
            const float* wbH = mlp_w1_l + (kc * 16) * 128 + 64 + h0;
            #pragma unroll
            for (int kk = 0; kk < 16; ++kk) {
                const float* wrL = wbL + kk * 128;
                const float* wrH = wbH + kk * 128;
                #pragma unroll
                for (int j = 0; j < 16; ++j) {
                    accL[j] = fmaf(ch[kk], wrL[j], accL[j]);
                    accH[j] = fmaf(ch[kk], wrH[j], accH[j]);
                }
            }
        }
        __syncthreads();                    // A reads (conv-a) long done; barrier for X-read ordering
        #pragma unroll
        for (int c = 0; c < 4; ++c) {
            *(float4*)&A[lane * LP + h0 + 4 * c] =
                make_float4(siluf(accL[4*c]), siluf(accL[4*c+1]), siluf(accL[4*c+2]), siluf(accL[4*c+3]));
            *(float4*)&B[lane * LP + h0 + 4 * c] =
                make_float4(siluf(accH[4*c]), siluf(accH[4*c+1]), siluf(accH[4*c+2]), siluf(accH[4*c+3]));
        }
    }
    __syncthreads();

    // ---- upd channels [h0, h0+16): m1_lo @ W2[0:64] + m1_hi @ W2[64:128] ----
    #pragma unroll
    for (int j = 0; j < 16; ++j) acc[j] = mlp_b2_l[h0 + j];
    #pragma unroll 1
    for (int kc = 0; kc < 4; ++kc) {
        float ch[16];
        float4 t0 = *(const float4*)&A[lane * LP + kc * 16 + 0];
        float4 t1 = *(const float4*)&A[lane * LP + kc * 16 + 4];
        float4 t2 = *(const float4*)&A[lane * LP + kc * 16 + 8];
        float4 t3 = *(const float4*)&A[lane * LP + kc * 16 + 12];
        ch[0]=t0.x; ch[1]=t0.y; ch[2]=t0.z; ch[3]=t0.w;
        ch[4]=t1.x; ch[5]=t1.y; ch[6]=t1.z; ch[7]=t1.w;
        ch[8]=t2.x; ch[9]=t2.y; ch[10]=t2.z; ch[11]=t2.w;
        ch[12]=t3.x; ch[13]=t3.y; ch[14]=t3.z; ch[15]=t3.w;
        const float* wb0 = mlp_w2_l + (kc * 16) * 64 + h0;
        #pragma unroll
        for (int kk = 0; kk < 16; ++kk) {
            const float* wr = wb0 + kk * 64;
            #pragma unroll
            for (int j = 0; j < 16; ++j) acc[j] = fmaf(ch[kk], wr[j], acc[j]);
        }
    }
    #pragma unroll 1
    for (int kc = 0; kc < 4; ++kc) {
        float ch[16];
        float4 t0 = *(const float4*)&B[lane * LP + kc * 16 + 0];
        float4 t1 = *(const float4*)&B[lane * LP + kc * 16 + 4];
        float4 t2 = *(const float4*)&B[lane * LP + kc * 16 + 8];
        float4 t3 = *(const float4*)&B[lane * LP + kc * 16 + 12];
        ch[0]=t0.x; ch[1]=t0.y; ch[2]=t0.z; ch[3]=t0.w;
        ch[4]=t1.x; ch[5]=t1.y; ch[6]=t1.z; ch[7]=t1.w;
        ch[8]=t2.x; ch[9]=t2.y; ch[10]=t2.z; ch[11]=t2.w;
        ch[12]=t3.x; ch[13]=t3.y; ch[14]=t3.z; ch[15]=t3.w;
        const float* wb0 = mlp_w2_l + (64 + kc * 16) * 64 + h0;
        #pragma unroll
        for (int kk = 0; kk < 16; ++kk) {
            const float* wr = wb0 + kk * 64;
            #pragma unroll
            for (int j = 0; j < 16; ++j) acc[j] = fmaf(ch[kk], wr[j], acc[j]);
        }
    }
    __syncthreads();                        // X (conv) dead: safe to restage x

    // restage x -> X (coalesced)
    #pragma unroll 4
    for (int i = 0; i < 16; ++i) {
        int r  = wib + i * 4;
        int nd = nb0 + r; nd = (nd < N_NODES) ? nd : (N_NODES - 1);
        X[r * LP + lane] = feats[(size_t)nd * 64 + lane];
    }
    __syncthreads();

    // ---- residual + LayerNorm ----
    float y[16];
    {
        float s1 = 0.f, s2 = 0.f;
        #pragma unroll
        for (int c = 0; c < 4; ++c) {
            float4 xv = *(const float4*)&X[lane * LP + h0 + 4 * c];
            y[4*c+0] = xv.x + acc[4*c+0];  y[4*c+1] = xv.y + acc[4*c+1];
            y[4*c+2] = xv.z + acc[4*c+2];  y[4*c+3] = xv.w + acc[4*c+3];
        }
        #pragma unroll
        for (int j = 0; j < 16; ++j) { s1 += y[j]; s2 += y[j] * y[j]; }
        P1[lane * 4 + wib] = s1;
        P2[lane * 4 + wib] = s2;
    }
    __syncthreads();
    {
        float4 p1 = *(const float4*)&P1[lane * 4];
        float4 p2 = *(const float4*)&P2[lane * 4];
        float s1 = p1.x + p1.y + p1.z + p1.w;
        float s2 = p2.x + p2.y + p2.z + p2.w;
        float mu  = s1 * (1.0f / 64.0f);
        float var = s2 * (1.0f / 64.0f) - mu * mu;
        float rr  = rsqrtf(var + 1e-5f);
        #pragma unroll
        for (int c = 0; c < 4; ++c) {
            float4 o;
            o.x = (y[4*c+0] - mu) * rr * ln_g_l[h0 + 4*c + 0] + ln_b_l[h0 + 4*c + 0];
            o.y = (y[4*c+1] - mu) * rr * ln_g_l[h0 + 4*c + 1] + ln_b_l[h0 + 4*c + 1];
            o.z = (y[4*c+2] - mu) * rr * ln_g_l[h0 + 4*c + 2] + ln_b_l[h0 + 4*c + 2];
            o.w = (y[4*c+3] - mu) * rr * ln_g_l[h0 + 4*c + 3] + ln_b_l[h0 + 4*c + 3];
            *(float4*)&X[lane * LP + h0 + 4 * c] = o;   // own column range only
        }
    }
    __syncthreads();

    // coalesced store X -> feats + featsbf
    #pragma unroll 4
    for (int i = 0; i < 16; ++i) {
        int r  = wib + i * 4;
        int nd = nb0 + r;
        if (nd < N_NODES) {
            float v = X[r * LP + lane];
            feats[(size_t)nd * 64 + lane]   = v;
            featsbf[(size_t)nd * 64 + lane] = (unsigned short)f2bf(v);
        }
    }
}

// ---------------- readout ----------------

__global__ __launch_bounds__(256) void k_readout(const float* __restrict__ feats,
        const int* __restrict__ an,
        const float* __restrict__ ro_w1, const float* __restrict__ ro_b1,
        const float* __restrict__ ro_w2, const float* __restrict__ ro_b2,
        const float* __restrict__ ro_w3, const float* __restrict__ ro_b3,
        const float* __restrict__ atomic_e, float* __restrict__ blockpart) {
    __shared__ float sacc[4];
    int wib  = threadIdx.x >> 6;
    int lane = threadIdx.x & 63;
    int node = blockIdx.x * 4 + wib;
    float e = 0.0f;
    if (node < N_NODES) {
        float x = feats[(size_t)node * HDIM + lane];
        float h1 = ro_b1[lane];
        #pragma unroll 8
        for (int k = 0; k < HDIM; ++k) h1 += bcastf(x, k) * ro_w1[k * HDIM + lane];
        h1 = siluf(h1);
        int j = lane & 31;
        float h2 = ro_b2[j];
        #pragma unroll 8
        for (int k = 0; k < HDIM; ++k) h2 += bcastf(h1, k) * ro_w2[k * 32 + j];
        h2 = siluf(h2);
        float contrib = (lane < 32) ? h2 * ro_w3[j] : 0.0f;
        contrib = waveRedSum(contrib);
        e = contrib + ro_b3[0] + atomic_e[an[node]];
    }
    if (lane == 0) sacc[wib] = e;
    __syncthreads();
    if (threadIdx.x == 0)
        blockpart[blockIdx.x] = sacc[0] + sacc[1] + sacc[2] + sacc[3];
}

__global__ void k_final(const float* __restrict__ blockpart, int nb, float* __restrict__ out) {
    __shared__ float s[256];
    float acc = 0.f;
    for (int i = threadIdx.x; i < nb; i += 256) acc += blockpart[i];
    s[threadIdx.x] = acc; __syncthreads();
    for (int off = 128; off > 0; off >>= 1) {
        if (threadIdx.x < off) s[threadIdx.x] += s[threadIdx.x + off];
        __syncthreads();
    }
    if (threadIdx.x == 0) out[0] = s[0];
}

// ---------------- launch ----------------

extern "C" void kernel_launch(void* const* d_in, const int* in_sizes, int n_in,
                              void* d_out, int out_size, void* d_ws, size_t ws_size,
                              hipStream_t stream) {
    const int*   an       = (const int*)  d_in[0];
    const float* pos      = (const float*)d_in[1];
    const int*   edge     = (const int*)  d_in[2];
    const float* widths   = (const float*)d_in[3];
    const float* embed    = (const float*)d_in[4];
    const float* rad_w1   = (const float*)d_in[5];
    const float* rad_b1   = (const float*)d_in[6];
    const float* rad_w2   = (const float*)d_in[7];
    const float* rad_b2   = (const float*)d_in[8];
    const float* self_w   = (const float*)d_in[9];
    const float* self_b   = (const float*)d_in[10];
    const float* proj_w   = (const float*)d_in[11];
    const float* proj_b   = (const float*)d_in[12];
    const float* mlp_w1   = (const float*)d_in[13];
    const float* mlp_b1   = (const float*)d_in[14];
    const float* mlp_w2   = (const float*)d_in[15];
    const float* mlp_b2   = (const float*)d_in[16];
    const float* ln_g     = (const float*)d_in[17];
    const float* ln_b     = (const float*)d_in[18];
    const float* ro_w1    = (const float*)d_in[19];
    const float* ro_b1    = (const float*)d_in[20];
    const float* ro_w2    = (const float*)d_in[21];
    const float* ro_b2    = (const float*)d_in[22];
    const float* ro_w3    = (const float*)d_in[23];
    const float* ro_b3    = (const float*)d_in[24];
    const float* atomic_e = (const float*)d_in[25];

    char* w = (char*)d_ws;
    auto alloc = [&](size_t bytes) { char* p = w; w += (bytes + 255) & ~(size_t)255; return p; };
    float* feats     = (float*)alloc(sizeof(float) * N_NODES * HDIM);
    float* aggb      = (float*)alloc(sizeof(float) * N_NODES * HDIM);
    unsigned short* featsbf = (unsigned short*)alloc(sizeof(unsigned short) * N_NODES * HDIM);
    float* lut       = (float*)alloc(sizeof(float) * NLAYER * TLUT * HDIM);
    uint4* lutQb     = (uint4*)alloc(sizeof(uint4) * NLAYER * TLUT * 16);
    float* W2s       = (float*)alloc(sizeof(float) * NLAYER * HDIM * HDIM);
    float* b2s       = (float*)alloc(sizeof(float) * NLAYER * HDIM);
    float* Wsp       = (float*)alloc(sizeof(float) * NLAYER * HDIM * HDIM);
    float* bsp       = (float*)alloc(sizeof(float) * NLAYER * HDIM);
    unsigned int* erec = (unsigned int*)alloc(sizeof(unsigned int) * N_EDGES);
    int*   starts    = (int*)  alloc(sizeof(int) * (N_NODES + 1));
    int*   cursor    = (int*)  alloc(sizeof(int) * N_NODES);
    int*   counts    = (int*)  alloc(sizeof(int) * N_NODES);
    int*   partial   = (int*)  alloc(sizeof(int) * 256);
    float* blockpart = (float*)alloc(sizeof(float) * 12500);
    (void)ws_size; (void)in_sizes; (void)n_in; (void)out_size;

    const int* erow = edge;
    const int* ecol = edge + N_EDGES;

    hipMemsetAsync(counts, 0, sizeof(int) * N_NODES, stream);
    k_embed<<<12500, 256, 0, stream>>>(an, embed, feats, featsbf);
    k_hist<<<6250, 256, 0, stream>>>(erow, counts);
    k_scan1<<<196, 256, 0, stream>>>(counts, partial);
    k_scan2<<<1, 256, 0, stream>>>(partial, 196);
    k_scan3<<<196, 256, 0, stream>>>(counts, partial, starts, cursor);
    k_scatter<<<6250, 256, 0, stream>>>(erow, ecol, pos, cursor, erec);
    k_prep<<<80, 256, 0, stream>>>(rad_w2, self_w, proj_w, W2s, Wsp);
    k_bias<<<5, 64, 0, stream>>>(rad_b2, self_b, proj_w, proj_b, b2s, bsp);
    k_lut<<<NLAYER * TLUT, 64, 0, stream>>>(widths, rad_w1, rad_b1, W2s, b2s, lut);
    k_lutq<<<(NLAYER * TLUT * 16 + 255) / 256, 256, 0, stream>>>(lut, lutQb);

    for (int l = 0; l < NLAYER; ++l) {
        k_agg<<<12500, 256, 0, stream>>>((const uint2*)featsbf,
                                         lutQb + (size_t)l * TLUT * 16,
                                         starts, erec, (float4*)aggb);
        k_node<<<782, 256, 0, stream>>>(feats, featsbf, aggb,
            Wsp + (size_t)l * HDIM * HDIM, bsp + l * HDIM,
            proj_w + (size_t)l * 2 * HDIM * HDIM,
            mlp_w1 + (size_t)l * HDIM * 2 * HDIM, mlp_b1 + l * 2 * HDIM,
            mlp_w2 + (size_t)l * 2 * HDIM * HDIM, mlp_b2 + l * HDIM,
            ln_g + l * HDIM, ln_b + l * HDIM);
    }

    k_readout<<<12500, 256, 0, stream>>>(feats, an, ro_w1, ro_b1, ro_w2, ro_b2,
                                         ro_w3, ro_b3, atomic_e, blockpart);
    k_final<<<1, 256, 0, stream>>>(blockpart, 12500, (float*)d_out);
}

// Round 11
// 599.550 us; speedup vs baseline: 4.7322x; 1.2849x over previous
//
#include <hip/hip_runtime.h>
#include <math.h>

// Problem constants (from reference)
constexpr int N_NODES = 50000;
constexpr int N_EDGES = 1600000;
constexpr int HDIM    = 64;
constexpr int NLAYER  = 5;
constexpr int NBASIS  = 8;
constexpr int TLUT    = 512;           // radial LUT entries per layer
constexpr float CUT_R = 5.0f;
constexpr float PI_F  = 3.14159265358979f;

typedef __attribute__((ext_vector_type(8))) short short8;   // 8 bf16 (4 VGPRs)
typedef __attribute__((ext_vector_type(4))) float f32x4;    // MFMA acc
#define MFMA16 __builtin_amdgcn_mfma_f32_16x16x32_bf16

__device__ __forceinline__ float bcastf(float v, int l) {
    return __uint_as_float(__builtin_amdgcn_readlane(__float_as_uint(v), l));
}
__device__ __forceinline__ float waveRedSum(float v) {
    for (int off = 32; off > 0; off >>= 1) v += __shfl_xor(v, off, 64);
    return v;
}
__device__ __forceinline__ float siluf(float x) { return x / (1.0f + __expf(-x)); }

// round-to-nearest-even f32 -> bf16 bits
__device__ __forceinline__ unsigned int f2bf(float x) {
    unsigned int b = __float_as_uint(x);
    return (b + 0x7fffu + ((b >> 16) & 1u)) >> 16;
}
__device__ __forceinline__ float bf_lo(unsigned int u) { return __uint_as_float(u << 16); }
__device__ __forceinline__ float bf_hi(unsigned int u) { return __uint_as_float(u & 0xffff0000u); }

// ---------------- setup kernels ----------------

__global__ void k_embed(const int* __restrict__ an, const float* __restrict__ embed,
                        float* __restrict__ feats, unsigned short* __restrict__ featsbf) {
    int i = blockIdx.x * blockDim.x + threadIdx.x;           // N*H threads
    if (i >= N_NODES * HDIM) return;
    int node = i >> 6, h = i & 63;
    float v = embed[an[node] * HDIM + h];
    feats[i] = v;
    featsbf[i] = (unsigned short)f2bf(v);
}

__global__ void k_hist(const int* __restrict__ row, int* __restrict__ counts) {
    int e = blockIdx.x * blockDim.x + threadIdx.x;
    if (e < N_EDGES) atomicAdd(&counts[row[e]], 1);
}

__global__ void k_scan1(const int* __restrict__ counts, int* __restrict__ partial) {
    __shared__ int s[256];
    int i = blockIdx.x * 256 + threadIdx.x;
    int v = (i < N_NODES) ? counts[i] : 0;
    s[threadIdx.x] = v; __syncthreads();
    for (int off = 128; off > 0; off >>= 1) {
        if (threadIdx.x < off) s[threadIdx.x] += s[threadIdx.x + off];
        __syncthreads();
    }
    if (threadIdx.x == 0) partial[blockIdx.x] = s[0];
}

__global__ void k_scan2(int* __restrict__ partial, int nb) {
    __shared__ int s[256];
    int v = (threadIdx.x < nb) ? partial[threadIdx.x] : 0;
    s[threadIdx.x] = v; __syncthreads();
    for (int off = 1; off < 256; off <<= 1) {
        int add = (threadIdx.x >= off) ? s[threadIdx.x - off] : 0;
        __syncthreads();
        s[threadIdx.x] += add;
        __syncthreads();
    }
    if (threadIdx.x < nb) partial[threadIdx.x] = s[threadIdx.x] - v;  // exclusive
}

__global__ void k_scan3(const int* __restrict__ counts, const int* __restrict__ partial,
                        int* __restrict__ starts, int* __restrict__ cursor) {
    __shared__ int s[256];
    int i = blockIdx.x * 256 + threadIdx.x;
    int v = (i < N_NODES) ? counts[i] : 0;
    s[threadIdx.x] = v; __syncthreads();
    for (int off = 1; off < 256; off <<= 1) {
        int add = (threadIdx.x >= off) ? s[threadIdx.x - off] : 0;
        __syncthreads();
        s[threadIdx.x] += add;
        __syncthreads();
    }
    if (i < N_NODES) {
        int st = partial[blockIdx.x] + s[threadIdx.x] - v;  // exclusive
        starts[i] = st; cursor[i] = st;
    }
    if (i == 0) starts[N_NODES] = N_EDGES;
}

// scatter edges into CSR order; record packed to 4B: (col<<16) | t_fix9.7
__global__ void k_scatter(const int* __restrict__ row, const int* __restrict__ col,
                          const float* __restrict__ pos, int* __restrict__ cursor,
                          unsigned int* __restrict__ erec) {
    int e = blockIdx.x * blockDim.x + threadIdx.x;
    if (e >= N_EDGES) return;
    int r = row[e], c = col[e];
    int p = atomicAdd(&cursor[r], 1);
    float dx = pos[c * 3 + 0] - pos[r * 3 + 0];
    float dy = pos[c * 3 + 1] - pos[r * 3 + 1];
    float dz = pos[c * 3 + 2] - pos[r * 3 + 2];
    float len = sqrtf(dx * dx + dy * dy + dz * dz);
    float t = len * ((float)(TLUT - 1) / CUT_R);
    t = fminf(t, (float)(TLUT - 1));
    unsigned int tfix = (unsigned int)(t * 128.0f);   // 9.7 fixed point
    erec[p] = ((unsigned int)c << 16) | tfix;
}

// W2s[l][k][h] = sum_{m<3} rad_w2[l][k][h*3+m]; Wsp[l][k][h] = (self_w @ proj_top)[k][h]
__global__ void k_prep(const float* __restrict__ rad_w2, const float* __restrict__ self_w,
                       const float* __restrict__ proj_w,
                       float* __restrict__ W2s, float* __restrict__ Wsp) {
    int i = blockIdx.x * blockDim.x + threadIdx.x;          // L*H*H
    if (i >= NLAYER * HDIM * HDIM) return;
    int l = i / (HDIM * HDIM); int rem = i % (HDIM * HDIM);
    int k = rem / HDIM; int h = rem % HDIM;
    const float* w = rad_w2 + ((size_t)l * HDIM + k) * (HDIM * 3) + h * 3;
    W2s[i] = w[0] + w[1] + w[2];
    const float* sw = self_w + ((size_t)l * HDIM + k) * HDIM;
    const float* pw = proj_w + (size_t)l * 2 * HDIM * HDIM;
    float acc = 0.f;
    for (int m = 0; m < HDIM; ++m) acc += sw[m] * pw[m * HDIM + h];
    Wsp[i] = acc;
}

// bf16 transposed weights for MFMA B-operands: layout [n][k] contiguous in k
__global__ void k_wtr(const float* __restrict__ Wsp, const float* __restrict__ proj_w,
                      const float* __restrict__ mlp_w1, const float* __restrict__ mlp_w2,
                      unsigned short* __restrict__ WspT, unsigned short* __restrict__ PbT,
                      unsigned short* __restrict__ W1T, unsigned short* __restrict__ W2T) {
    int i = blockIdx.x * blockDim.x + threadIdx.x;          // L * 24576
    if (i >= NLAYER * 24576) return;
    int l = i / 24576, off = i % 24576;
    if (off < 4096) {                       // WspT[n=off>>6][k=off&63]
        int n = off >> 6, k = off & 63;
        WspT[(size_t)l * 4096 + off] = (unsigned short)f2bf(Wsp[(size_t)l * 4096 + k * 64 + n]);
    } else if (off < 8192) {                // PbT (bottom half of proj_w)
        int o = off - 4096; int n = o >> 6, k = o & 63;
        PbT[(size_t)l * 4096 + o] =
            (unsigned short)f2bf(proj_w[(size_t)l * 8192 + (64 + k) * 64 + n]);
    } else if (off < 16384) {               // W1T[n=0..127][k=0..63]
        int o = off - 8192; int n = o >> 6, k = o & 63;
        W1T[(size_t)l * 8192 + o] = (unsigned short)f2bf(mlp_w1[(size_t)l * 8192 + k * 128 + n]);
    } else {                                // W2T[n=0..63][k=0..127]
        int o = off - 16384; int n = o >> 7, k = o & 127;
        W2T[(size_t)l * 8192 + o] = (unsigned short)f2bf(mlp_w2[(size_t)l * 8192 + k * 64 + n]);
    }
}

// b2s[l][h] = sum_m rad_b2[l][h*3+m];  bsp[l][h] = self_b@proj_top + proj_b
__global__ void k_bias(const float* __restrict__ rad_b2, const float* __restrict__ self_b,
                       const float* __restrict__ proj_w, const float* __restrict__ proj_b,
                       float* __restrict__ b2s, float* __restrict__ bsp) {
    int i = blockIdx.x * blockDim.x + threadIdx.x;          // L*H
    if (i >= NLAYER * HDIM) return;
    int l = i / HDIM, h = i % HDIM;
    const float* rb2 = rad_b2 + l * HDIM * 3 + h * 3;
    b2s[i] = rb2[0] + rb2[1] + rb2[2];
    float acc = proj_b[l * HDIM + h];
    const float* pw = proj_w + (size_t)l * 2 * HDIM * HDIM;
    const float* sb = self_b + l * HDIM;
    for (int m = 0; m < HDIM; ++m) acc += sb[m] * pw[m * HDIM + h];
    bsp[i] = acc;
}

// radial LUT
__global__ void k_lut(const float* __restrict__ widths, const float* __restrict__ rad_w1,
                      const float* __restrict__ rad_b1, const float* __restrict__ W2s,
                      const float* __restrict__ b2s, float* __restrict__ lut) {
    int bid = blockIdx.x;                 // l*TLUT + t
    int l = bid / TLUT, t = bid % TLUT;
    int h = threadIdx.x;                  // 64 threads
    __shared__ float h1s[HDIM];
    float len = (float)t * (CUT_R / (float)(TLUT - 1));
    float cut = 0.0f;
    if (len < CUT_R) cut = 0.5f * (cosf(len * (PI_F / CUT_R)) + 1.0f);
    float acc = rad_b1[l * HDIM + h];
    for (int b = 0; b < NBASIS; ++b) {
        float wb = fmaxf(widths[b], 0.1f);
        float center = (float)b * (CUT_R / (float)(NBASIS - 1));
        float d = (len - center) / wb;
        float rbf = __expf(-0.5f * d * d) * cut;
        acc += rbf * rad_w1[(l * NBASIS + b) * HDIM + h];
    }
    h1s[h] = siluf(acc);
    __syncthreads();
    float o = b2s[l * HDIM + h];
    const float* w2 = W2s + (size_t)l * HDIM * HDIM;
    for (int k = 0; k < HDIM; ++k) o += h1s[k] * w2[k * HDIM + h];
    lut[(size_t)bid * HDIM + h] = o;
}

// lutQb[(l*TLUT+t)*16+j] = uint4; comp c packs bf16(lut[t][4j+c]) | bf16(lut[t+1][4j+c])<<16
__global__ void k_lutq(const float* __restrict__ lut, uint4* __restrict__ lutQb) {
    int i = blockIdx.x * blockDim.x + threadIdx.x;          // L*TLUT*16
    if (i >= NLAYER * TLUT * 16) return;
    int j = i & 15;
    int lt = i >> 4;
    int l = lt / TLUT, t = lt % TLUT;
    int t1 = (t < TLUT - 1) ? t + 1 : t;
    const float* r0 = lut + (size_t)(l * TLUT + t)  * HDIM + 4 * j;
    const float* r1 = lut + (size_t)(l * TLUT + t1) * HDIM + 4 * j;
    uint4 o;
    o.x = f2bf(r0[0]) | (f2bf(r1[0]) << 16);
    o.y = f2bf(r0[1]) | (f2bf(r1[1]) << 16);
    o.z = f2bf(r0[2]) | (f2bf(r1[2]) << 16);
    o.w = f2bf(r0[3]) | (f2bf(r1[3]) << 16);
    lutQb[i] = o;
}

// ---------------- per-layer kernels ----------------

// one wave per node, 4 edge slots x 16 lanes (4 channels each). bf16 in, bf16 out.
__global__ __launch_bounds__(256) void k_agg(const uint2* __restrict__ featsbf2,
                                             const uint4* __restrict__ lutQb_l,
                                             const int* __restrict__ starts,
                                             const unsigned int* __restrict__ erec,
                                             unsigned short* __restrict__ aggbf) {
    int wid  = (blockIdx.x * blockDim.x + threadIdx.x) >> 6;
    int lane = threadIdx.x & 63;
    int slot = lane >> 4;
    int j    = lane & 15;
    if (wid >= N_NODES) return;
    int e0 = starts[wid], e1 = starts[wid + 1];
    float ax = 0.f, ay = 0.f, az = 0.f, aw = 0.f;
    #pragma unroll 2
    for (int e = e0 + slot; e < e1; e += 4) {
        unsigned int rec = erec[e];
        int c    = rec >> 16;
        int tfix = rec & 0xffff;
        int i0   = tfix >> 7;
        float f  = (float)(tfix & 127) * (1.0f / 128.0f);
        uint4 qw = lutQb_l[i0 * 16 + j];
        uint2 fb = featsbf2[(size_t)c * 16 + j];
        float w00 = bf_lo(qw.x), w01 = bf_hi(qw.x);
        float w10 = bf_lo(qw.y), w11 = bf_hi(qw.y);
        float w20 = bf_lo(qw.z), w21 = bf_hi(qw.z);
        float w30 = bf_lo(qw.w), w31 = bf_hi(qw.w);
        ax += bf_lo(fb.x) * (w00 + f * (w01 - w00));
        ay += bf_hi(fb.x) * (w10 + f * (w11 - w10));
        az += bf_lo(fb.y) * (w20 + f * (w21 - w20));
        aw += bf_hi(fb.y) * (w30 + f * (w31 - w30));
    }
    ax += __shfl_xor(ax, 16, 64);  ay += __shfl_xor(ay, 16, 64);
    az += __shfl_xor(az, 16, 64);  aw += __shfl_xor(aw, 16, 64);
    ax += __shfl_xor(ax, 32, 64);  ay += __shfl_xor(ay, 32, 64);
    az += __shfl_xor(az, 32, 64);  aw += __shfl_xor(aw, 32, 64);
    if (slot == 0) {
        uint2 o;
        o.x = f2bf(ax) | (f2bf(ay) << 16);
        o.y = f2bf(az) | (f2bf(aw) << 16);
        *(uint2*)&aggbf[(size_t)wid * 64 + 4 * j] = o;
    }
}

// k_node v3 (MFMA): 64 nodes/block, 4 waves; wave w owns node rows [16w,16w+16).
// conv/m1/upd as bf16 MFMA chains; activations in LDS bf16 (pitch 72, 16B-aligned);
// weights pre-transposed [n][k] bf16 in global (L1/L2-cached). LN in registers.
constexpr int BP = 72;                     // bf16 LDS row pitch
__global__ __launch_bounds__(256) void k_node(float* __restrict__ feats,
        unsigned short* __restrict__ featsbf,
        const unsigned short* __restrict__ aggbf,
        const unsigned short* __restrict__ WspT_l, const unsigned short* __restrict__ PbT_l,
        const unsigned short* __restrict__ W1T_l, const unsigned short* __restrict__ W2T_l,
        const float* __restrict__ bsp_l,
        const float* __restrict__ mlp_b1_l, const float* __restrict__ mlp_b2_l,
        const float* __restrict__ ln_g_l, const float* __restrict__ ln_b_l) {
    __shared__ unsigned short P[64 * BP];   // x -> conv
    __shared__ unsigned short Q[64 * BP];   // a -> m1_lo
    __shared__ unsigned short S[64 * BP];   // m1_hi
    const int tid  = threadIdx.x;
    const int lane = tid & 63;
    const int wib  = tid >> 6;
    const int mt   = __builtin_amdgcn_readfirstlane(wib);
    const int nb0  = blockIdx.x * 64;
    const int colL = lane & 15;
    const int kgrp = lane >> 4;

    // stage x->P, a->Q (bf16, coalesced 2B/lane)
    #pragma unroll 4
    for (int i = 0; i < 16; ++i) {
        int r  = wib + i * 4;
        int nd = nb0 + r; nd = (nd < N_NODES) ? nd : (N_NODES - 1);
        P[r * BP + lane] = featsbf[(size_t)nd * 64 + lane];
        Q[r * BP + lane] = aggbf[(size_t)nd * 64 + lane];
    }
    __syncthreads();

    // ---- conv = x@Wsp + a@Pb + bsp ----
    f32x4 acc[4];
    #pragma unroll
    for (int nt = 0; nt < 4; ++nt) {
        float b = bsp_l[nt * 16 + colL];
        acc[nt][0] = b; acc[nt][1] = b; acc[nt][2] = b; acc[nt][3] = b;
    }
    #pragma unroll
    for (int kb = 0; kb < 2; ++kb) {
        short8 ax = *(const short8*)&P[(mt * 16 + colL) * BP + kb * 32 + kgrp * 8];
        short8 aa = *(const short8*)&Q[(mt * 16 + colL) * BP + kb * 32 + kgrp * 8];
        #pragma unroll
        for (int nt = 0; nt < 4; ++nt) {
            short8 bw = *(const short8*)&WspT_l[(nt * 16 + colL) * 64 + kb * 32 + kgrp * 8];
            acc[nt] = MFMA16(ax, bw, acc[nt], 0, 0, 0);
            short8 bp = *(const short8*)&PbT_l[(nt * 16 + colL) * 64 + kb * 32 + kgrp * 8];
            acc[nt] = MFMA16(aa, bp, acc[nt], 0, 0, 0);
        }
    }
    __syncthreads();                        // all conv reads of P done
    #pragma unroll
    for (int nt = 0; nt < 4; ++nt)
        #pragma unroll
        for (int j = 0; j < 4; ++j)
            P[(mt * 16 + kgrp * 4 + j) * BP + nt * 16 + colL] = (unsigned short)f2bf(acc[nt][j]);
    __syncthreads();

    // ---- m1 = silu(conv@W1 + b1), 128 wide ----
    {
        f32x4 m[8];
        #pragma unroll
        for (int nt = 0; nt < 8; ++nt) {
            float b = mlp_b1_l[nt * 16 + colL];
            m[nt][0] = b; m[nt][1] = b; m[nt][2] = b; m[nt][3] = b;
        }
        #pragma unroll
        for (int kb = 0; kb < 2; ++kb) {
            short8 ac = *(const short8*)&P[(mt * 16 + colL) * BP + kb * 32 + kgrp * 8];
            #pragma unroll
            for (int nt = 0; nt < 8; ++nt) {
                short8 bw = *(const short8*)&W1T_l[(nt * 16 + colL) * 64 + kb * 32 + kgrp * 8];
                m[nt] = MFMA16(ac, bw, m[nt], 0, 0, 0);
            }
        }
        // write m1_lo (nt 0..3) -> Q, m1_hi (nt 4..7) -> S (Q's conv reads done 2 barriers ago)
        #pragma unroll
        for (int nt = 0; nt < 4; ++nt)
            #pragma unroll
            for (int j = 0; j < 4; ++j)
                Q[(mt * 16 + kgrp * 4 + j) * BP + nt * 16 + colL] =
                    (unsigned short)f2bf(siluf(m[nt][j]));
        #pragma unroll
        for (int nt = 4; nt < 8; ++nt)
            #pragma unroll
            for (int j = 0; j < 4; ++j)
                S[(mt * 16 + kgrp * 4 + j) * BP + (nt - 4) * 16 + colL] =
                    (unsigned short)f2bf(siluf(m[nt][j]));
    }
    __syncthreads();

    // ---- upd = m1@W2 + b2 ----
    f32x4 u[4];
    #pragma unroll
    for (int nt = 0; nt < 4; ++nt) {
        float b = mlp_b2_l[nt * 16 + colL];
        u[nt][0] = b; u[nt][1] = b; u[nt][2] = b; u[nt][3] = b;
    }
    #pragma unroll
    for (int kb = 0; kb < 4; ++kb) {
        short8 am = (kb < 2)
            ? *(const short8*)&Q[(mt * 16 + colL) * BP + kb * 32 + kgrp * 8]
            : *(const short8*)&S[(mt * 16 + colL) * BP + (kb - 2) * 32 + kgrp * 8];
        #pragma unroll
        for (int nt = 0; nt < 4; ++nt) {
            short8 bw = *(const short8*)&W2T_l[(nt * 16 + colL) * 128 + kb * 32 + kgrp * 8];
            u[nt] = MFMA16(am, bw, u[nt], 0, 0, 0);
        }
    }

    // ---- residual + LayerNorm (in registers; x reloaded from global) ----
    float y[4][4];                           // [nt][j]
    float s1[4] = {0, 0, 0, 0}, s2[4] = {0, 0, 0, 0};
    #pragma unroll
    for (int j = 0; j < 4; ++j) {
        int node = nb0 + mt * 16 + kgrp * 4 + j;
        int nds  = (node < N_NODES) ? node : (N_NODES - 1);
        #pragma unroll
        for (int nt = 0; nt < 4; ++nt) {
            float v = feats[(size_t)nds * 64 + nt * 16 + colL] + u[nt][j];
            y[nt][j] = v;
            s1[j] += v; s2[j] += v * v;
        }
    }
    #pragma unroll
    for (int off = 1; off < 16; off <<= 1) {
        #pragma unroll
        for (int j = 0; j < 4; ++j) {
            s1[j] += __shfl_xor(s1[j], off, 64);
            s2[j] += __shfl_xor(s2[j], off, 64);
        }
    }
    float gv[4], bv[4];
    #pragma unroll
    for (int nt = 0; nt < 4; ++nt) {
        gv[nt] = ln_g_l[nt * 16 + colL];
        bv[nt] = ln_b_l[nt * 16 + colL];
    }
    #pragma unroll
    for (int j = 0; j < 4; ++j) {
        int node = nb0 + mt * 16 + kgrp * 4 + j;
        if (node >= N_NODES) continue;
        float mu  = s1[j] * (1.0f / 64.0f);
        float var = s2[j] * (1.0f / 64.0f) - mu * mu;
        float rr  = rsqrtf(var + 1e-5f);
        #pragma unroll
        for (int nt = 0; nt < 4; ++nt) {
            float o = (y[nt][j] - mu) * rr * gv[nt] + bv[nt];
            feats[(size_t)node * 64 + nt * 16 + colL]   = o;
            featsbf[(size_t)node * 64 + nt * 16 + colL] = (unsigned short)f2bf(o);
        }
    }
}

// ---------------- readout ----------------

__global__ __launch_bounds__(256) void k_readout(const float* __restrict__ feats,
        const int* __restrict__ an,
        const float* __restrict__ ro_w1, const float* __restrict__ ro_b1,
        const float* __restrict__ ro_w2, const float* __restrict__ ro_b2,
        const float* __restrict__ ro_w3, const float* __restrict__ ro_b3,
        const float* __restrict__ atomic_e, float* __restrict__ blockpart) {
    __shared__ float sacc[4];
    int wib  = threadIdx.x >> 6;
    int lane = threadIdx.x & 63;
    int node = blockIdx.x * 4 + wib;
    float e = 0.0f;
    if (node < N_NODES) {
        float x = feats[(size_t)node * HDIM + lane];
        float h1 = ro_b1[lane];
        #pragma unroll 8
        for (int k = 0; k < HDIM; ++k) h1 += bcastf(x, k) * ro_w1[k * HDIM + lane];
        h1 = siluf(h1);
        int j = lane & 31;
        float h2 = ro_b2[j];
        #pragma unroll 8
        for (int k = 0; k < HDIM; ++k) h2 += bcastf(h1, k) * ro_w2[k * 32 + j];
        h2 = siluf(h2);
        float contrib = (lane < 32) ? h2 * ro_w3[j] : 0.0f;
        contrib = waveRedSum(contrib);
        e = contrib + ro_b3[0] + atomic_e[an[node]];
    }
    if (lane == 0) sacc[wib] = e;
    __syncthreads();
    if (threadIdx.x == 0)
        blockpart[blockIdx.x] = sacc[0] + sacc[1] + sacc[2] + sacc[3];
}

__global__ void k_final(const float* __restrict__ blockpart, int nb, float* __restrict__ out) {
    __shared__ float s[256];
    float acc = 0.f;
    for (int i = threadIdx.x; i < nb; i += 256) acc += blockpart[i];
    s[threadIdx.x] = acc; __syncthreads();
    for (int off = 128; off > 0; off >>= 1) {
        if (threadIdx.x < off) s[threadIdx.x] += s[threadIdx.x + off];
        __syncthreads();
    }
    if (threadIdx.x == 0) out[0] = s[0];
}

// ---------------- launch ----------------

extern "C" void kernel_launch(void* const* d_in, const int* in_sizes, int n_in,
                              void* d_out, int out_size, void* d_ws, size_t ws_size,
                              hipStream_t stream) {
    const int*   an       = (const int*)  d_in[0];
    const float* pos      = (const float*)d_in[1];
    const int*   edge     = (const int*)  d_in[2];
    const float* widths   = (const float*)d_in[3];
    const float* embed    = (const float*)d_in[4];
    const float* rad_w1   = (const float*)d_in[5];
    const float* rad_b1   = (const float*)d_in[6];
    const float* rad_w2   = (const float*)d_in[7];
    const float* rad_b2   = (const float*)d_in[8];
    const float* self_w   = (const float*)d_in[9];
    const float* self_b   = (const float*)d_in[10];
    const float* proj_w   = (const float*)d_in[11];
    const float* proj_b   = (const float*)d_in[12];
    const float* mlp_w1   = (const float*)d_in[13];
    const float* mlp_b1   = (const float*)d_in[14];
    const float* mlp_w2   = (const float*)d_in[15];
    const float* mlp_b2   = (const float*)d_in[16];
    const float* ln_g     = (const float*)d_in[17];
    const float* ln_b     = (const float*)d_in[18];
    const float* ro_w1    = (const float*)d_in[19];
    const float* ro_b1    = (const float*)d_in[20];
    const float* ro_w2    = (const float*)d_in[21];
    const float* ro_b2    = (const float*)d_in[22];
    const float* ro_w3    = (const float*)d_in[23];
    const float* ro_b3    = (const float*)d_in[24];
    const float* atomic_e = (const float*)d_in[25];

    char* w = (char*)d_ws;
    auto alloc = [&](size_t bytes) { char* p = w; w += (bytes + 255) & ~(size_t)255; return p; };
    float* feats     = (float*)alloc(sizeof(float) * N_NODES * HDIM);
    unsigned short* featsbf = (unsigned short*)alloc(sizeof(unsigned short) * N_NODES * HDIM);
    unsigned short* aggbf   = (unsigned short*)alloc(sizeof(unsigned short) * N_NODES * HDIM);
    float* lut       = (float*)alloc(sizeof(float) * NLAYER * TLUT * HDIM);
    uint4* lutQb     = (uint4*)alloc(sizeof(uint4) * NLAYER * TLUT * 16);
    float* W2s       = (float*)alloc(sizeof(float) * NLAYER * HDIM * HDIM);
    float* b2s       = (float*)alloc(sizeof(float) * NLAYER * HDIM);
    float* Wsp       = (float*)alloc(sizeof(float) * NLAYER * HDIM * HDIM);
    float* bsp       = (float*)alloc(sizeof(float) * NLAYER * HDIM);
    unsigned short* WspT = (unsigned short*)alloc(sizeof(unsigned short) * NLAYER * 4096);
    unsigned short* PbT  = (unsigned short*)alloc(sizeof(unsigned short) * NLAYER * 4096);
    unsigned short* W1T  = (unsigned short*)alloc(sizeof(unsigned short) * NLAYER * 8192);
    unsigned short* W2T  = (unsigned short*)alloc(sizeof(unsigned short) * NLAYER * 8192);
    unsigned int* erec = (unsigned int*)alloc(sizeof(unsigned int) * N_EDGES);
    int*   starts    = (int*)  alloc(sizeof(int) * (N_NODES + 1));
    int*   cursor    = (int*)  alloc(sizeof(int) * N_NODES);
    int*   counts    = (int*)  alloc(sizeof(int) * N_NODES);
    int*   partial   = (int*)  alloc(sizeof(int) * 256);
    float* blockpart = (float*)alloc(sizeof(float) * 12500);
    (void)ws_size; (void)in_sizes; (void)n_in; (void)out_size;

    const int* erow = edge;
    const int* ecol = edge + N_EDGES;

    hipMemsetAsync(counts, 0, sizeof(int) * N_NODES, stream);
    k_embed<<<12500, 256, 0, stream>>>(an, embed, feats, featsbf);
    k_hist<<<6250, 256, 0, stream>>>(erow, counts);
    k_scan1<<<196, 256, 0, stream>>>(counts, partial);
    k_scan2<<<1, 256, 0, stream>>>(partial, 196);
    k_scan3<<<196, 256, 0, stream>>>(counts, partial, starts, cursor);
    k_scatter<<<6250, 256, 0, stream>>>(erow, ecol, pos, cursor, erec);
    k_prep<<<80, 256, 0, stream>>>(rad_w2, self_w, proj_w, W2s, Wsp);
    k_wtr<<<(NLAYER * 24576 + 255) / 256, 256, 0, stream>>>(Wsp, proj_w, mlp_w1, mlp_w2,
                                                            WspT, PbT, W1T, W2T);
    k_bias<<<5, 64, 0, stream>>>(rad_b2, self_b, proj_w, proj_b, b2s, bsp);
    k_lut<<<NLAYER * TLUT, 64, 0, stream>>>(widths, rad_w1, rad_b1, W2s, b2s, lut);
    k_lutq<<<(NLAYER * TLUT * 16 + 255) / 256, 256, 0, stream>>>(lut, lutQb);

    for (int l = 0; l < NLAYER; ++l) {
        k_agg<<<12500, 256, 0, stream>>>((const uint2*)featsbf,
                                         lutQb + (size_t)l * TLUT * 16,
                                         starts, erec, aggbf);
        k_node<<<782, 256, 0, stream>>>(feats, featsbf, aggbf,
            WspT + (size_t)l * 4096, PbT + (size_t)l * 4096,
            W1T + (size_t)l * 8192, W2T + (size_t)l * 8192,
            bsp + l * HDIM, mlp_b1 + l * 2 * HDIM, mlp_b2 + l * HDIM,
            ln_g + l * HDIM, ln_b + l * HDIM);
    }

    k_readout<<<12500, 256, 0, stream>>>(feats, an, ro_w1, ro_b1, ro_w2, ro_b2,
                                         ro_w3, ro_b3, atomic_e, blockpart);
    k_final<<<1, 256, 0, stream>>>(blockpart, 12500, (float*)d_out);
}

// Round 12
// 589.038 us; speedup vs baseline: 4.8166x; 1.0178x over previous
//
#include <hip/hip_runtime.h>
#include <math.h>

// Problem constants (from reference)
constexpr int N_NODES = 50000;
constexpr int N_EDGES = 1600000;
constexpr int HDIM    = 64;
constexpr int NLAYER  = 5;
constexpr int NBASIS  = 8;
constexpr int TLUT    = 512;           // radial LUT entries per layer
constexpr float CUT_R = 5.0f;
constexpr float PI_F  = 3.14159265358979f;

// binned scatter
constexpr int NBKT = 49;               // buckets of 1024 nodes (r >> 10)
constexpr int BCAP = 34816;            // mean 32768 + ~11 sigma
constexpr int TILE = 2048;

typedef __attribute__((ext_vector_type(8))) short short8;   // 8 bf16 (4 VGPRs)
typedef __attribute__((ext_vector_type(4))) float f32x4;    // MFMA acc
#define MFMA16 __builtin_amdgcn_mfma_f32_16x16x32_bf16

__device__ __forceinline__ float bcastf(float v, int l) {
    return __uint_as_float(__builtin_amdgcn_readlane(__float_as_uint(v), l));
}
__device__ __forceinline__ float waveRedSum(float v) {
    for (int off = 32; off > 0; off >>= 1) v += __shfl_xor(v, off, 64);
    return v;
}
__device__ __forceinline__ float siluf(float x) { return x / (1.0f + __expf(-x)); }

// round-to-nearest-even f32 -> bf16 bits
__device__ __forceinline__ unsigned int f2bf(float x) {
    unsigned int b = __float_as_uint(x);
    return (b + 0x7fffu + ((b >> 16) & 1u)) >> 16;
}
__device__ __forceinline__ float bf_lo(unsigned int u) { return __uint_as_float(u << 16); }
__device__ __forceinline__ float bf_hi(unsigned int u) { return __uint_as_float(u & 0xffff0000u); }
__device__ __forceinline__ float lrp(unsigned int u, float f) {
    float lo = bf_lo(u), hi = bf_hi(u);
    return lo + f * (hi - lo);
}

// ---------------- setup kernels ----------------

__global__ void k_embed(const int* __restrict__ an, const float* __restrict__ embed,
                        float* __restrict__ feats, unsigned short* __restrict__ featsbf) {
    int i = blockIdx.x * blockDim.x + threadIdx.x;           // N*H threads
    if (i >= N_NODES * HDIM) return;
    int node = i >> 6, h = i & 63;
    float v = embed[an[node] * HDIM + h];
    feats[i] = v;
    featsbf[i] = (unsigned short)f2bf(v);
}

__global__ void k_hist(const int* __restrict__ row, int* __restrict__ counts) {
    int e = blockIdx.x * blockDim.x + threadIdx.x;
    if (e < N_EDGES) atomicAdd(&counts[row[e]], 1);
}

__global__ void k_scan1(const int* __restrict__ counts, int* __restrict__ partial) {
    __shared__ int s[256];
    int i = blockIdx.x * 256 + threadIdx.x;
    int v = (i < N_NODES) ? counts[i] : 0;
    s[threadIdx.x] = v; __syncthreads();
    for (int off = 128; off > 0; off >>= 1) {
        if (threadIdx.x < off) s[threadIdx.x] += s[threadIdx.x + off];
        __syncthreads();
    }
    if (threadIdx.x == 0) partial[blockIdx.x] = s[0];
}

__global__ void k_scan2(int* __restrict__ partial, int nb) {
    __shared__ int s[256];
    int v = (threadIdx.x < nb) ? partial[threadIdx.x] : 0;
    s[threadIdx.x] = v; __syncthreads();
    for (int off = 1; off < 256; off <<= 1) {
        int add = (threadIdx.x >= off) ? s[threadIdx.x - off] : 0;
        __syncthreads();
        s[threadIdx.x] += add;
        __syncthreads();
    }
    if (threadIdx.x < nb) partial[threadIdx.x] = s[threadIdx.x] - v;  // exclusive
}

__global__ void k_scan3(const int* __restrict__ counts, const int* __restrict__ partial,
                        int* __restrict__ starts) {
    __shared__ int s[256];
    int i = blockIdx.x * 256 + threadIdx.x;
    int v = (i < N_NODES) ? counts[i] : 0;
    s[threadIdx.x] = v; __syncthreads();
    for (int off = 1; off < 256; off <<= 1) {
        int add = (threadIdx.x >= off) ? s[threadIdx.x - off] : 0;
        __syncthreads();
        s[threadIdx.x] += add;
        __syncthreads();
    }
    if (i < N_NODES) starts[i] = partial[blockIdx.x] + s[threadIdx.x] - v;  // exclusive
    if (i == 0) starts[N_NODES] = N_EDGES;
}

// pass A: block-sort 2048-edge tiles by node bucket (r>>10), append runs to binned[]
__global__ __launch_bounds__(256) void k_binA(const int* __restrict__ row,
                                              const int* __restrict__ col,
                                              const float* __restrict__ pos,
                                              int* __restrict__ btail,
                                              uint2* __restrict__ binned) {
    __shared__ uint2 ent[TILE];          // 16 KB: payload {rec, row}
    __shared__ short bb[TILE];           // 4 KB: bucket id
    __shared__ uint2 sorted[TILE];       // 16 KB
    __shared__ int cnt[64], cnt2[64], base[64], gbase[64];
    const int tid = threadIdx.x;
    const int t0  = blockIdx.x * TILE;
    const int nv  = min(TILE, N_EDGES - t0);

    if (tid < 64) cnt[tid] = 0;
    __syncthreads();

    #pragma unroll
    for (int i = 0; i < TILE / 256; ++i) {
        int idx = i * 256 + tid;
        if (idx < nv) {
            int e = t0 + idx;
            int r = row[e], c = col[e];
            float dx = pos[c * 3 + 0] - pos[r * 3 + 0];
            float dy = pos[c * 3 + 1] - pos[r * 3 + 1];
            float dz = pos[c * 3 + 2] - pos[r * 3 + 2];
            float len = sqrtf(dx * dx + dy * dy + dz * dz);
            float t = len * ((float)(TLUT - 1) / CUT_R);
            t = fminf(t, (float)(TLUT - 1));
            unsigned int tfix = (unsigned int)(t * 128.0f);
            uint2 p;
            p.x = ((unsigned int)c << 16) | tfix;
            p.y = (unsigned int)r;
            ent[idx] = p;
            int b = r >> 10;
            bb[idx] = (short)b;
            atomicAdd(&cnt[b], 1);
        }
    }
    __syncthreads();
    if (tid == 0) {                       // exclusive scan over 49 buckets
        int run = 0;
        for (int b = 0; b < NBKT; ++b) { base[b] = run; run += cnt[b]; }
    }
    __syncthreads();
    if (tid < NBKT) {
        gbase[tid] = atomicAdd(&btail[tid], cnt[tid]);
        cnt2[tid] = base[tid];
    }
    __syncthreads();
    #pragma unroll
    for (int i = 0; i < TILE / 256; ++i) {
        int idx = i * 256 + tid;
        if (idx < nv) {
            int b = bb[idx];
            int p = atomicAdd(&cnt2[b], 1);
            sorted[p] = ent[idx];
        }
    }
    __syncthreads();
    for (int s = tid; s < nv; s += 256) {
        uint2 p = sorted[s];
        int b = (int)(p.y >> 10);
        binned[(size_t)b * BCAP + gbase[b] + (s - base[b])] = p;
    }
}

// pass B: one block per bucket; LDS cursors; erec writes land in a 128KB slice
__global__ __launch_bounds__(256) void k_binB(const uint2* __restrict__ binned,
                                              const int* __restrict__ btail,
                                              const int* __restrict__ starts,
                                              unsigned int* __restrict__ erec) {
    __shared__ int lcur[1024];
    const int b = blockIdx.x;
    const int node0 = b << 10;
    for (int i = threadIdx.x; i < 1024; i += 256) {
        int n = node0 + i;
        lcur[i] = (n < N_NODES) ? starts[n] : 0;
    }
    __syncthreads();
    const int cnt = btail[b];
    const uint2* src = binned + (size_t)b * BCAP;
    for (int s = threadIdx.x; s < cnt; s += 256) {
        uint2 p = src[s];
        int pp = atomicAdd(&lcur[p.y & 1023], 1);
        erec[pp] = p.x;
    }
}

// W2s[l][k][h] = sum_{m<3} rad_w2[l][k][h*3+m]; Wsp[l][k][h] = (self_w @ proj_top)[k][h]
__global__ void k_prep(const float* __restrict__ rad_w2, const float* __restrict__ self_w,
                       const float* __restrict__ proj_w,
                       float* __restrict__ W2s, float* __restrict__ Wsp) {
    int i = blockIdx.x * blockDim.x + threadIdx.x;          // L*H*H
    if (i >= NLAYER * HDIM * HDIM) return;
    int l = i / (HDIM * HDIM); int rem = i % (HDIM * HDIM);
    int k = rem / HDIM; int h = rem % HDIM;
    const float* w = rad_w2 + ((size_t)l * HDIM + k) * (HDIM * 3) + h * 3;
    W2s[i] = w[0] + w[1] + w[2];
    const float* sw = self_w + ((size_t)l * HDIM + k) * HDIM;
    const float* pw = proj_w + (size_t)l * 2 * HDIM * HDIM;
    float acc = 0.f;
    for (int m = 0; m < HDIM; ++m) acc += sw[m] * pw[m * HDIM + h];
    Wsp[i] = acc;
}

// bf16 transposed weights for MFMA B-operands: layout [n][k] contiguous in k
__global__ void k_wtr(const float* __restrict__ Wsp, const float* __restrict__ proj_w,
                      const float* __restrict__ mlp_w1, const float* __restrict__ mlp_w2,
                      unsigned short* __restrict__ WspT, unsigned short* __restrict__ PbT,
                      unsigned short* __restrict__ W1T, unsigned short* __restrict__ W2T) {
    int i = blockIdx.x * blockDim.x + threadIdx.x;          // L * 24576
    if (i >= NLAYER * 24576) return;
    int l = i / 24576, off = i % 24576;
    if (off < 4096) {
        int n = off >> 6, k = off & 63;
        WspT[(size_t)l * 4096 + off] = (unsigned short)f2bf(Wsp[(size_t)l * 4096 + k * 64 + n]);
    } else if (off < 8192) {
        int o = off - 4096; int n = o >> 6, k = o & 63;
        PbT[(size_t)l * 4096 + o] =
            (unsigned short)f2bf(proj_w[(size_t)l * 8192 + (64 + k) * 64 + n]);
    } else if (off < 16384) {
        int o = off - 8192; int n = o >> 6, k = o & 63;
        W1T[(size_t)l * 8192 + o] = (unsigned short)f2bf(mlp_w1[(size_t)l * 8192 + k * 128 + n]);
    } else {
        int o = off - 16384; int n = o >> 7, k = o & 127;
        W2T[(size_t)l * 8192 + o] = (unsigned short)f2bf(mlp_w2[(size_t)l * 8192 + k * 64 + n]);
    }
}

// b2s[l][h] = sum_m rad_b2[l][h*3+m];  bsp[l][h] = self_b@proj_top + proj_b
__global__ void k_bias(const float* __restrict__ rad_b2, const float* __restrict__ self_b,
                       const float* __restrict__ proj_w, const float* __restrict__ proj_b,
                       float* __restrict__ b2s, float* __restrict__ bsp) {
    int i = blockIdx.x * blockDim.x + threadIdx.x;          // L*H
    if (i >= NLAYER * HDIM) return;
    int l = i / HDIM, h = i % HDIM;
    const float* rb2 = rad_b2 + l * HDIM * 3 + h * 3;
    b2s[i] = rb2[0] + rb2[1] + rb2[2];
    float acc = proj_b[l * HDIM + h];
    const float* pw = proj_w + (size_t)l * 2 * HDIM * HDIM;
    const float* sb = self_b + l * HDIM;
    for (int m = 0; m < HDIM; ++m) acc += sb[m] * pw[m * HDIM + h];
    bsp[i] = acc;
}

// radial LUT
__global__ void k_lut(const float* __restrict__ widths, const float* __restrict__ rad_w1,
                      const float* __restrict__ rad_b1, const float* __restrict__ W2s,
                      const float* __restrict__ b2s, float* __restrict__ lut) {
    int bid = blockIdx.x;                 // l*TLUT + t
    int l = bid / TLUT, t = bid % TLUT;
    int h = threadIdx.x;                  // 64 threads
    __shared__ float h1s[HDIM];
    float len = (float)t * (CUT_R / (float)(TLUT - 1));
    float cut = 0.0f;
    if (len < CUT_R) cut = 0.5f * (cosf(len * (PI_F / CUT_R)) + 1.0f);
    float acc = rad_b1[l * HDIM + h];
    for (int b = 0; b < NBASIS; ++b) {
        float wb = fmaxf(widths[b], 0.1f);
        float center = (float)b * (CUT_R / (float)(NBASIS - 1));
        float d = (len - center) / wb;
        float rbf = __expf(-0.5f * d * d) * cut;
        acc += rbf * rad_w1[(l * NBASIS + b) * HDIM + h];
    }
    h1s[h] = siluf(acc);
    __syncthreads();
    float o = b2s[l * HDIM + h];
    const float* w2 = W2s + (size_t)l * HDIM * HDIM;
    for (int k = 0; k < HDIM; ++k) o += h1s[k] * w2[k * HDIM + h];
    lut[(size_t)bid * HDIM + h] = o;
}

// lutQb[(l*TLUT+t)*16+j] = uint4; comp c packs bf16(lut[t][4j+c]) | bf16(lut[t+1][4j+c])<<16
__global__ void k_lutq(const float* __restrict__ lut, uint4* __restrict__ lutQb) {
    int i = blockIdx.x * blockDim.x + threadIdx.x;          // L*TLUT*16
    if (i >= NLAYER * TLUT * 16) return;
    int j = i & 15;
    int lt = i >> 4;
    int l = lt / TLUT, t = lt % TLUT;
    int t1 = (t < TLUT - 1) ? t + 1 : t;
    const float* r0 = lut + (size_t)(l * TLUT + t)  * HDIM + 4 * j;
    const float* r1 = lut + (size_t)(l * TLUT + t1) * HDIM + 4 * j;
    uint4 o;
    o.x = f2bf(r0[0]) | (f2bf(r1[0]) << 16);
    o.y = f2bf(r0[1]) | (f2bf(r1[1]) << 16);
    o.z = f2bf(r0[2]) | (f2bf(r1[2]) << 16);
    o.w = f2bf(r0[3]) | (f2bf(r1[3]) << 16);
    lutQb[i] = o;
}

// ---------------- per-layer kernels ----------------

// one wave per node, 8 edge slots x 8 lanes (8 channels each via uint4 loads).
__global__ __launch_bounds__(256) void k_agg(const uint4* __restrict__ featsbf4,
                                             const uint4* __restrict__ lutQb_l,
                                             const int* __restrict__ starts,
                                             const unsigned int* __restrict__ erec,
                                             uint4* __restrict__ aggbf4) {
    int wid  = (blockIdx.x * blockDim.x + threadIdx.x) >> 6;
    int lane = threadIdx.x & 63;
    int slot = lane >> 3;     // 0..7
    int j    = lane & 7;      // channel octet
    if (wid >= N_NODES) return;
    int e0 = starts[wid], e1 = starts[wid + 1];
    float a0 = 0, a1 = 0, a2 = 0, a3 = 0, a4 = 0, a5 = 0, a6 = 0, a7 = 0;
    #pragma unroll 2
    for (int e = e0 + slot; e < e1; e += 8) {
        unsigned int rec = erec[e];
        int c    = rec >> 16;
        int tfix = rec & 0xffff;
        int i0   = tfix >> 7;
        float f  = (float)(tfix & 127) * (1.0f / 128.0f);
        uint4 q0 = lutQb_l[i0 * 16 + 2 * j];
        uint4 q1 = lutQb_l[i0 * 16 + 2 * j + 1];
        uint4 fb = featsbf4[(size_t)c * 8 + j];
        a0 += bf_lo(fb.x) * lrp(q0.x, f);
        a1 += bf_hi(fb.x) * lrp(q0.y, f);
        a2 += bf_lo(fb.y) * lrp(q0.z, f);
        a3 += bf_hi(fb.y) * lrp(q0.w, f);
        a4 += bf_lo(fb.z) * lrp(q1.x, f);
        a5 += bf_hi(fb.z) * lrp(q1.y, f);
        a6 += bf_lo(fb.w) * lrp(q1.z, f);
        a7 += bf_hi(fb.w) * lrp(q1.w, f);
    }
    #pragma unroll
    for (int off = 8; off < 64; off <<= 1) {
        a0 += __shfl_xor(a0, off, 64);  a1 += __shfl_xor(a1, off, 64);
        a2 += __shfl_xor(a2, off, 64);  a3 += __shfl_xor(a3, off, 64);
        a4 += __shfl_xor(a4, off, 64);  a5 += __shfl_xor(a5, off, 64);
        a6 += __shfl_xor(a6, off, 64);  a7 += __shfl_xor(a7, off, 64);
    }
    if (slot == 0) {
        uint4 o;
        o.x = f2bf(a0) | (f2bf(a1) << 16);
        o.y = f2bf(a2) | (f2bf(a3) << 16);
        o.z = f2bf(a4) | (f2bf(a5) << 16);
        o.w = f2bf(a6) | (f2bf(a7) << 16);
        aggbf4[(size_t)wid * 8 + j] = o;
    }
}

// k_node v3 (MFMA): 64 nodes/block, 4 waves; wave w owns node rows [16w,16w+16).
constexpr int BP = 72;                     // bf16 LDS row pitch
__global__ __launch_bounds__(256) void k_node(float* __restrict__ feats,
        unsigned short* __restrict__ featsbf,
        const unsigned short* __restrict__ aggbf,
        const unsigned short* __restrict__ WspT_l, const unsigned short* __restrict__ PbT_l,
        const unsigned short* __restrict__ W1T_l, const unsigned short* __restrict__ W2T_l,
        const float* __restrict__ bsp_l,
        const float* __restrict__ mlp_b1_l, const float* __restrict__ mlp_b2_l,
        const float* __restrict__ ln_g_l, const float* __restrict__ ln_b_l) {
    __shared__ unsigned short P[64 * BP];   // x -> conv
    __shared__ unsigned short Q[64 * BP];   // a -> m1_lo
    __shared__ unsigned short S[64 * BP];   // m1_hi
    const int tid  = threadIdx.x;
    const int lane = tid & 63;
    const int wib  = tid >> 6;
    const int mt   = __builtin_amdgcn_readfirstlane(wib);
    const int nb0  = blockIdx.x * 64;
    const int colL = lane & 15;
    const int kgrp = lane >> 4;

    #pragma unroll 4
    for (int i = 0; i < 16; ++i) {
        int r  = wib + i * 4;
        int nd = nb0 + r; nd = (nd < N_NODES) ? nd : (N_NODES - 1);
        P[r * BP + lane] = featsbf[(size_t)nd * 64 + lane];
        Q[r * BP + lane] = aggbf[(size_t)nd * 64 + lane];
    }
    __syncthreads();

    // ---- conv = x@Wsp + a@Pb + bsp ----
    f32x4 acc[4];
    #pragma unroll
    for (int nt = 0; nt < 4; ++nt) {
        float b = bsp_l[nt * 16 + colL];
        acc[nt][0] = b; acc[nt][1] = b; acc[nt][2] = b; acc[nt][3] = b;
    }
    #pragma unroll
    for (int kb = 0; kb < 2; ++kb) {
        short8 ax = *(const short8*)&P[(mt * 16 + colL) * BP + kb * 32 + kgrp * 8];
        short8 aa = *(const short8*)&Q[(mt * 16 + colL) * BP + kb * 32 + kgrp * 8];
        #pragma unroll
        for (int nt = 0; nt < 4; ++nt) {
            short8 bw = *(const short8*)&WspT_l[(nt * 16 + colL) * 64 + kb * 32 + kgrp * 8];
            acc[nt] = MFMA16(ax, bw, acc[nt], 0, 0, 0);
            short8 bp = *(const short8*)&PbT_l[(nt * 16 + colL) * 64 + kb * 32 + kgrp * 8];
            acc[nt] = MFMA16(aa, bp, acc[nt], 0, 0, 0);
        }
    }
    __syncthreads();
    #pragma unroll
    for (int nt = 0; nt < 4; ++nt)
        #pragma unroll
        for (int j = 0; j < 4; ++j)
            P[(mt * 16 + kgrp * 4 + j) * BP + nt * 16 + colL] = (unsigned short)f2bf(acc[nt][j]);
    __syncthreads();

    // ---- m1 = silu(conv@W1 + b1), 128 wide ----
    {
        f32x4 m[8];
        #pragma unroll
        for (int nt = 0; nt < 8; ++nt) {
            float b = mlp_b1_l[nt * 16 + colL];
            m[nt][0] = b; m[nt][1] = b; m[nt][2] = b; m[nt][3] = b;
        }
        #pragma unroll
        for (int kb = 0; kb < 2; ++kb) {
            short8 ac = *(const short8*)&P[(mt * 16 + colL) * BP + kb * 32 + kgrp * 8];
            #pragma unroll
            for (int nt = 0; nt < 8; ++nt) {
                short8 bw = *(const short8*)&W1T_l[(nt * 16 + colL) * 64 + kb * 32 + kgrp * 8];
                m[nt] = MFMA16(ac, bw, m[nt], 0, 0, 0);
            }
        }
        __syncthreads();
        #pragma unroll
        for (int nt = 0; nt < 4; ++nt)
            #pragma unroll
            for (int j = 0; j < 4; ++j)
                Q[(mt * 16 + kgrp * 4 + j) * BP + nt * 16 + colL] =
                    (unsigned short)f2bf(siluf(m[nt][j]));
        #pragma unroll
        for (int nt = 4; nt < 8; ++nt)
            #pragma unroll
            for (int j = 0; j < 4; ++j)
                S[(mt * 16 + kgrp * 4 + j) * BP + (nt - 4) * 16 + colL] =
                    (unsigned short)f2bf(siluf(m[nt][j]));
    }
    __syncthreads();

    // ---- upd = m1@W2 + b2 ----
    f32x4 u[4];
    #pragma unroll
    for (int nt = 0; nt < 4; ++nt) {
        float b = mlp_b2_l[nt * 16 + colL];
        u[nt][0] = b; u[nt][1] = b; u[nt][2] = b; u[nt][3] = b;
    }
    #pragma unroll
    for (int kb = 0; kb < 4; ++kb) {
        short8 am = (kb < 2)
            ? *(const short8*)&Q[(mt * 16 + colL) * BP + kb * 32 + kgrp * 8]
            : *(const short8*)&S[(mt * 16 + colL) * BP + (kb - 2) * 32 + kgrp * 8];
        #pragma unroll
        for (int nt = 0; nt < 4; ++nt) {
            short8 bw = *(const short8*)&W2T_l[(nt * 16 + colL) * 128 + kb * 32 + kgrp * 8];
            u[nt] = MFMA16(am, bw, u[nt], 0, 0, 0);
        }
    }

    // ---- residual + LayerNorm ----
    float y[4][4];
    float s1[4] = {0, 0, 0, 0}, s2[4] = {0, 0, 0, 0};
    #pragma unroll
    for (int j = 0; j < 4; ++j) {
        int node = nb0 + mt * 16 + kgrp * 4 + j;
        int nds  = (node < N_NODES) ? node : (N_NODES - 1);
        #pragma unroll
        for (int nt = 0; nt < 4; ++nt) {
            float v = feats[(size_t)nds * 64 + nt * 16 + colL] + u[nt][j];
            y[nt][j] = v;
            s1[j] += v; s2[j] += v * v;
        }
    }
    #pragma unroll
    for (int off = 1; off < 16; off <<= 1) {
        #pragma unroll
        for (int j = 0; j < 4; ++j) {
            s1[j] += __shfl_xor(s1[j], off, 64);
            s2[j] += __shfl_xor(s2[j], off, 64);
        }
    }
    float gv[4], bv[4];
    #pragma unroll
    for (int nt = 0; nt < 4; ++nt) {
        gv[nt] = ln_g_l[nt * 16 + colL];
        bv[nt] = ln_b_l[nt * 16 + colL];
    }
    #pragma unroll
    for (int j = 0; j < 4; ++j) {
        int node = nb0 + mt * 16 + kgrp * 4 + j;
        if (node >= N_NODES) continue;
        float mu  = s1[j] * (1.0f / 64.0f);
        float var = s2[j] * (1.0f / 64.0f) - mu * mu;
        float rr  = rsqrtf(var + 1e-5f);
        #pragma unroll
        for (int nt = 0; nt < 4; ++nt) {
            float o = (y[nt][j] - mu) * rr * gv[nt] + bv[nt];
            feats[(size_t)node * 64 + nt * 16 + colL]   = o;
            featsbf[(size_t)node * 64 + nt * 16 + colL] = (unsigned short)f2bf(o);
        }
    }
}

// ---------------- readout ----------------

__global__ __launch_bounds__(256) void k_readout(const float* __restrict__ feats,
        const int* __restrict__ an,
        const float* __restrict__ ro_w1, const float* __restrict__ ro_b1,
        const float* __restrict__ ro_w2, const float* __restrict__ ro_b2,
        const float* __restrict__ ro_w3, const float* __restrict__ ro_b3,
        const float* __restrict__ atomic_e, float* __restrict__ blockpart) {
    __shared__ float sacc[4];
    int wib  = threadIdx.x >> 6;
    int lane = threadIdx.x & 63;
    int node = blockIdx.x * 4 + wib;
    float e = 0.0f;
    if (node < N_NODES) {
        float x = feats[(size_t)node * HDIM + lane];
        float h1 = ro_b1[lane];
        #pragma unroll 8
        for (int k = 0; k < HDIM; ++k) h1 += bcastf(x, k) * ro_w1[k * HDIM + lane];
        h1 = siluf(h1);
        int j = lane & 31;
        float h2 = ro_b2[j];
        #pragma unroll 8
        for (int k = 0; k < HDIM; ++k) h2 += bcastf(h1, k) * ro_w2[k * 32 + j];
        h2 = siluf(h2);
        float contrib = (lane < 32) ? h2 * ro_w3[j] : 0.0f;
        contrib = waveRedSum(contrib);
        e = contrib + ro_b3[0] + atomic_e[an[node]];
    }
    if (lane == 0) sacc[wib] = e;
    __syncthreads();
    if (threadIdx.x == 0)
        blockpart[blockIdx.x] = sacc[0] + sacc[1] + sacc[2] + sacc[3];
}

__global__ void k_final(const float* __restrict__ blockpart, int nb, float* __restrict__ out) {
    __shared__ float s[256];
    float acc = 0.f;
    for (int i = threadIdx.x; i < nb; i += 256) acc += blockpart[i];
    s[threadIdx.x] = acc; __syncthreads();
    for (int off = 128; off > 0; off >>= 1) {
        if (threadIdx.x < off) s[threadIdx.x] += s[threadIdx.x + off];
        __syncthreads();
    }
    if (threadIdx.x == 0) out[0] = s[0];
}

// ---------------- launch ----------------

extern "C" void kernel_launch(void* const* d_in, const int* in_sizes, int n_in,
                              void* d_out, int out_size, void* d_ws, size_t ws_size,
                              hipStream_t stream) {
    const int*   an       = (const int*)  d_in[0];
    const float* pos      = (const float*)d_in[1];
    const int*   edge     = (const int*)  d_in[2];
    const float* widths   = (const float*)d_in[3];
    const float* embed    = (const float*)d_in[4];
    const float* rad_w1   = (const float*)d_in[5];
    const float* rad_b1   = (const float*)d_in[6];
    const float* rad_w2   = (const float*)d_in[7];
    const float* rad_b2   = (const float*)d_in[8];
    const float* self_w   = (const float*)d_in[9];
    const float* self_b   = (const float*)d_in[10];
    const float* proj_w   = (const float*)d_in[11];
    const float* proj_b   = (const float*)d_in[12];
    const float* mlp_w1   = (const float*)d_in[13];
    const float* mlp_b1   = (const float*)d_in[14];
    const float* mlp_w2   = (const float*)d_in[15];
    const float* mlp_b2   = (const float*)d_in[16];
    const float* ln_g     = (const float*)d_in[17];
    const float* ln_b     = (const float*)d_in[18];
    const float* ro_w1    = (const float*)d_in[19];
    const float* ro_b1    = (const float*)d_in[20];
    const float* ro_w2    = (const float*)d_in[21];
    const float* ro_b2    = (const float*)d_in[22];
    const float* ro_w3    = (const float*)d_in[23];
    const float* ro_b3    = (const float*)d_in[24];
    const float* atomic_e = (const float*)d_in[25];

    char* w = (char*)d_ws;
    auto alloc = [&](size_t bytes) { char* p = w; w += (bytes + 255) & ~(size_t)255; return p; };
    float* feats     = (float*)alloc(sizeof(float) * N_NODES * HDIM);
    unsigned short* featsbf = (unsigned short*)alloc(sizeof(unsigned short) * N_NODES * HDIM);
    unsigned short* aggbf   = (unsigned short*)alloc(sizeof(unsigned short) * N_NODES * HDIM);
    float* lut       = (float*)alloc(sizeof(float) * NLAYER * TLUT * HDIM);
    uint4* lutQb     = (uint4*)alloc(sizeof(uint4) * NLAYER * TLUT * 16);
    float* W2s       = (float*)alloc(sizeof(float) * NLAYER * HDIM * HDIM);
    float* b2s       = (float*)alloc(sizeof(float) * NLAYER * HDIM);
    float* Wsp       = (float*)alloc(sizeof(float) * NLAYER * HDIM * HDIM);
    float* bsp       = (float*)alloc(sizeof(float) * NLAYER * HDIM);
    unsigned short* WspT = (unsigned short*)alloc(sizeof(unsigned short) * NLAYER * 4096);
    unsigned short* PbT  = (unsigned short*)alloc(sizeof(unsigned short) * NLAYER * 4096);
    unsigned short* W1T  = (unsigned short*)alloc(sizeof(unsigned short) * NLAYER * 8192);
    unsigned short* W2T  = (unsigned short*)alloc(sizeof(unsigned short) * NLAYER * 8192);
    unsigned int* erec = (unsigned int*)alloc(sizeof(unsigned int) * N_EDGES);
    uint2* binned    = (uint2*)alloc(sizeof(uint2) * (size_t)NBKT * BCAP);
    int*   btail     = (int*)  alloc(sizeof(int) * 64);
    int*   starts    = (int*)  alloc(sizeof(int) * (N_NODES + 1));
    int*   counts    = (int*)  alloc(sizeof(int) * N_NODES);
    int*   partial   = (int*)  alloc(sizeof(int) * 256);
    float* blockpart = (float*)alloc(sizeof(float) * 12500);
    (void)ws_size; (void)in_sizes; (void)n_in; (void)out_size;

    const int* erow = edge;
    const int* ecol = edge + N_EDGES;

    hipMemsetAsync(counts, 0, sizeof(int) * N_NODES, stream);
    hipMemsetAsync(btail, 0, sizeof(int) * 64, stream);
    k_embed<<<12500, 256, 0, stream>>>(an, embed, feats, featsbf);
    k_hist<<<6250, 256, 0, stream>>>(erow, counts);
    k_scan1<<<196, 256, 0, stream>>>(counts, partial);
    k_scan2<<<1, 256, 0, stream>>>(partial, 196);
    k_scan3<<<196, 256, 0, stream>>>(counts, partial, starts);
    k_binA<<<(N_EDGES + TILE - 1) / TILE, 256, 0, stream>>>(erow, ecol, pos, btail, binned);
    k_binB<<<NBKT, 256, 0, stream>>>(binned, btail, starts, erec);
    k_prep<<<80, 256, 0, stream>>>(rad_w2, self_w, proj_w, W2s, Wsp);
    k_wtr<<<(NLAYER * 24576 + 255) / 256, 256, 0, stream>>>(Wsp, proj_w, mlp_w1, mlp_w2,
                                                            WspT, PbT, W1T, W2T);
    k_bias<<<5, 64, 0, stream>>>(rad_b2, self_b, proj_w, proj_b, b2s, bsp);
    k_lut<<<NLAYER * TLUT, 64, 0, stream>>>(widths, rad_w1, rad_b1, W2s, b2s, lut);
    k_lutq<<<(NLAYER * TLUT * 16 + 255) / 256, 256, 0, stream>>>(lut, lutQb);

    for (int l = 0; l < NLAYER; ++l) {
        k_agg<<<12500, 256, 0, stream>>>((const uint4*)featsbf,
                                         lutQb + (size_t)l * TLUT * 16,
                                         starts, erec, (uint4*)aggbf);
        k_node<<<782, 256, 0, stream>>>(feats, featsbf, aggbf,
            WspT + (size_t)l * 4096, PbT + (size_t)l * 4096,
            W1T + (size_t)l * 8192, W2T + (size_t)l * 8192,
            bsp + l * HDIM, mlp_b1 + l * 2 * HDIM, mlp_b2 + l * HDIM,
            ln_g + l * HDIM, ln_b + l * HDIM);
    }

    k_readout<<<12500, 256, 0, stream>>>(feats, an, ro_w1, ro_b1, ro_w2, ro_b2,
                                         ro_w3, ro_b3, atomic_e, blockpart);
    k_final<<<1, 256, 0, stream>>>(blockpart, 12500, (float*)d_out);
}

// Round 13
// 536.068 us; speedup vs baseline: 5.2926x; 1.0988x over previous
//
#include <hip/hip_runtime.h>
#include <math.h>

// Problem constants (from reference)
constexpr int N_NODES = 50000;
constexpr int N_EDGES = 1600000;
constexpr int HDIM    = 64;
constexpr int NLAYER  = 5;
constexpr int NBASIS  = 8;
constexpr int TLUT    = 512;           // radial LUT entries per layer
constexpr float CUT_R = 5.0f;
constexpr float PI_F  = 3.14159265358979f;

// binned scatter
constexpr int NBKT = 49;               // buckets of 1024 nodes (r >> 10)
constexpr int BCAP = 34816;            // mean 32768 + ~11 sigma
constexpr int TILE = 2048;

typedef __attribute__((ext_vector_type(8))) short short8;   // 8 bf16 (4 VGPRs)
typedef __attribute__((ext_vector_type(4))) float f32x4;    // MFMA acc
#define MFMA16 __builtin_amdgcn_mfma_f32_16x16x32_bf16

__device__ __forceinline__ float bcastf(float v, int l) {
    return __uint_as_float(__builtin_amdgcn_readlane(__float_as_uint(v), l));
}
__device__ __forceinline__ float waveRedSum(float v) {
    for (int off = 32; off > 0; off >>= 1) v += __shfl_xor(v, off, 64);
    return v;
}
__device__ __forceinline__ float siluf(float x) { return x / (1.0f + __expf(-x)); }

// round-to-nearest-even f32 -> bf16 bits
__device__ __forceinline__ unsigned int f2bf(float x) {
    unsigned int b = __float_as_uint(x);
    return (b + 0x7fffu + ((b >> 16) & 1u)) >> 16;
}
__device__ __forceinline__ float bf_lo(unsigned int u) { return __uint_as_float(u << 16); }
__device__ __forceinline__ float bf_hi(unsigned int u) { return __uint_as_float(u & 0xffff0000u); }
__device__ __forceinline__ float lrp(unsigned int u, float f) {
    float lo = bf_lo(u), hi = bf_hi(u);
    return lo + f * (hi - lo);
}

// ---------------- setup kernels ----------------

__global__ void k_embed(const int* __restrict__ an, const float* __restrict__ embed,
                        float* __restrict__ feats, unsigned short* __restrict__ featsbf) {
    int i = blockIdx.x * blockDim.x + threadIdx.x;           // N*H threads
    if (i >= N_NODES * HDIM) return;
    int node = i >> 6, h = i & 63;
    float v = embed[an[node] * HDIM + h];
    feats[i] = v;
    featsbf[i] = (unsigned short)f2bf(v);
}

// pass A: block-sort 2048-edge tiles by node bucket (r>>10), append runs to binned[]
__global__ __launch_bounds__(256) void k_binA(const int* __restrict__ row,
                                              const int* __restrict__ col,
                                              const float* __restrict__ pos,
                                              int* __restrict__ btail,
                                              uint2* __restrict__ binned) {
    __shared__ uint2 ent[TILE];          // 16 KB: payload {rec, row}
    __shared__ short bb[TILE];           // 4 KB: bucket id
    __shared__ uint2 sorted[TILE];       // 16 KB
    __shared__ int cnt[64], cnt2[64], base[64], gbase[64];
    const int tid = threadIdx.x;
    const int t0  = blockIdx.x * TILE;
    const int nv  = min(TILE, N_EDGES - t0);

    if (tid < 64) cnt[tid] = 0;
    __syncthreads();

    #pragma unroll
    for (int i = 0; i < TILE / 256; ++i) {
        int idx = i * 256 + tid;
        if (idx < nv) {
            int e = t0 + idx;
            int r = row[e], c = col[e];
            float dx = pos[c * 3 + 0] - pos[r * 3 + 0];
            float dy = pos[c * 3 + 1] - pos[r * 3 + 1];
            float dz = pos[c * 3 + 2] - pos[r * 3 + 2];
            float len = sqrtf(dx * dx + dy * dy + dz * dz);
            float t = len * ((float)(TLUT - 1) / CUT_R);
            t = fminf(t, (float)(TLUT - 1));
            unsigned int tfix = (unsigned int)(t * 128.0f);
            uint2 p;
            p.x = ((unsigned int)c << 16) | tfix;
            p.y = (unsigned int)r;
            ent[idx] = p;
            int b = r >> 10;
            bb[idx] = (short)b;
            atomicAdd(&cnt[b], 1);
        }
    }
    __syncthreads();
    if (tid == 0) {                       // exclusive scan over 49 buckets
        int run = 0;
        for (int b = 0; b < NBKT; ++b) { base[b] = run; run += cnt[b]; }
    }
    __syncthreads();
    if (tid < NBKT) {
        gbase[tid] = atomicAdd(&btail[tid], cnt[tid]);
        cnt2[tid] = base[tid];
    }
    __syncthreads();
    #pragma unroll
    for (int i = 0; i < TILE / 256; ++i) {
        int idx = i * 256 + tid;
        if (idx < nv) {
            int b = bb[idx];
            int p = atomicAdd(&cnt2[b], 1);
            sorted[p] = ent[idx];
        }
    }
    __syncthreads();
    for (int s = tid; s < nv; s += 256) {
        uint2 p = sorted[s];
        int b = (int)(p.y >> 10);
        binned[(size_t)b * BCAP + gbase[b] + (s - base[b])] = p;
    }
}

// exclusive scan of 49 bucket totals (1 block)
__global__ void k_scanB(const int* __restrict__ btail, int* __restrict__ bbase) {
    __shared__ int s[64];
    int t = threadIdx.x;
    int v = (t < NBKT) ? btail[t] : 0;
    s[t] = v; __syncthreads();
    for (int off = 1; off < 64; off <<= 1) {
        int add = (t >= off) ? s[t - off] : 0;
        __syncthreads();
        s[t] += add;
        __syncthreads();
    }
    if (t < NBKT) bbase[t] = s[t] - v;
}

// pass B v2: one block per bucket. LDS histogram of node counts -> LDS scan ->
// starts (coalesced) -> scatter erec via LDS cursors. No global atomics.
__global__ __launch_bounds__(256) void k_binB(const uint2* __restrict__ binned,
                                              const int* __restrict__ btail,
                                              const int* __restrict__ bbase,
                                              int* __restrict__ starts,
                                              unsigned int* __restrict__ erec) {
    __shared__ int hist[1024];
    __shared__ int wsum[256];
    const int b = blockIdx.x;
    const int node0 = b << 10;
    const int t = threadIdx.x;
    for (int i = t; i < 1024; i += 256) hist[i] = 0;
    __syncthreads();
    const int cnt = btail[b];
    const uint2* src = binned + (size_t)b * BCAP;
    for (int s = t; s < cnt; s += 256)
        atomicAdd(&hist[src[s].y & 1023], 1);
    __syncthreads();
    // exclusive scan of hist[1024]; thread t owns entries [4t, 4t+4)
    int h0 = hist[4 * t], h1 = hist[4 * t + 1], h2 = hist[4 * t + 2], h3 = hist[4 * t + 3];
    int sum = h0 + h1 + h2 + h3;
    wsum[t] = sum;
    __syncthreads();
    for (int off = 1; off < 256; off <<= 1) {
        int add = (t >= off) ? wsum[t - off] : 0;
        __syncthreads();
        wsum[t] += add;
        __syncthreads();
    }
    int e0 = bbase[b] + wsum[t] - sum;     // exclusive position of node 4t
    int c0 = e0, c1 = e0 + h0, c2 = c1 + h1, c3 = c2 + h2;
    hist[4 * t] = c0; hist[4 * t + 1] = c1; hist[4 * t + 2] = c2; hist[4 * t + 3] = c3;
    int n = node0 + 4 * t;
    if (n     < N_NODES) starts[n]     = c0;
    if (n + 1 < N_NODES) starts[n + 1] = c1;
    if (n + 2 < N_NODES) starts[n + 2] = c2;
    if (n + 3 < N_NODES) starts[n + 3] = c3;
    if (b == 0 && t == 0) starts[N_NODES] = N_EDGES;
    __syncthreads();
    for (int s = t; s < cnt; s += 256) {
        uint2 p = src[s];
        int pp = atomicAdd(&hist[p.y & 1023], 1);
        erec[pp] = p.x;
    }
}

// W2s[l][k][h] = sum_{m<3} rad_w2[l][k][h*3+m]; Wsp[l][k][h] = (self_w @ proj_top)[k][h]
__global__ void k_prep(const float* __restrict__ rad_w2, const float* __restrict__ self_w,
                       const float* __restrict__ proj_w,
                       float* __restrict__ W2s, float* __restrict__ Wsp) {
    int i = blockIdx.x * blockDim.x + threadIdx.x;          // L*H*H
    if (i >= NLAYER * HDIM * HDIM) return;
    int l = i / (HDIM * HDIM); int rem = i % (HDIM * HDIM);
    int k = rem / HDIM; int h = rem % HDIM;
    const float* w = rad_w2 + ((size_t)l * HDIM + k) * (HDIM * 3) + h * 3;
    W2s[i] = w[0] + w[1] + w[2];
    const float* sw = self_w + ((size_t)l * HDIM + k) * HDIM;
    const float* pw = proj_w + (size_t)l * 2 * HDIM * HDIM;
    float acc = 0.f;
    for (int m = 0; m < HDIM; ++m) acc += sw[m] * pw[m * HDIM + h];
    Wsp[i] = acc;
}

// bf16 transposed weights for MFMA B-operands: layout [n][k] contiguous in k
__global__ void k_wtr(const float* __restrict__ Wsp, const float* __restrict__ proj_w,
                      const float* __restrict__ mlp_w1, const float* __restrict__ mlp_w2,
                      unsigned short* __restrict__ WspT, unsigned short* __restrict__ PbT,
                      unsigned short* __restrict__ W1T, unsigned short* __restrict__ W2T) {
    int i = blockIdx.x * blockDim.x + threadIdx.x;          // L * 24576
    if (i >= NLAYER * 24576) return;
    int l = i / 24576, off = i % 24576;
    if (off < 4096) {
        int n = off >> 6, k = off & 63;
        WspT[(size_t)l * 4096 + off] = (unsigned short)f2bf(Wsp[(size_t)l * 4096 + k * 64 + n]);
    } else if (off < 8192) {
        int o = off - 4096; int n = o >> 6, k = o & 63;
        PbT[(size_t)l * 4096 + o] =
            (unsigned short)f2bf(proj_w[(size_t)l * 8192 + (64 + k) * 64 + n]);
    } else if (off < 16384) {
        int o = off - 8192; int n = o >> 6, k = o & 63;
        W1T[(size_t)l * 8192 + o] = (unsigned short)f2bf(mlp_w1[(size_t)l * 8192 + k * 128 + n]);
    } else {
        int o = off - 16384; int n = o >> 7, k = o & 127;
        W2T[(size_t)l * 8192 + o] = (unsigned short)f2bf(mlp_w2[(size_t)l * 8192 + k * 64 + n]);
    }
}

// b2s[l][h] = sum_m rad_b2[l][h*3+m];  bsp[l][h] = self_b@proj_top + proj_b
__global__ void k_bias(const float* __restrict__ rad_b2, const float* __restrict__ self_b,
                       const float* __restrict__ proj_w, const float* __restrict__ proj_b,
                       float* __restrict__ b2s, float* __restrict__ bsp) {
    int i = blockIdx.x * blockDim.x + threadIdx.x;          // L*H
    if (i >= NLAYER * HDIM) return;
    int l = i / HDIM, h = i % HDIM;
    const float* rb2 = rad_b2 + l * HDIM * 3 + h * 3;
    b2s[i] = rb2[0] + rb2[1] + rb2[2];
    float acc = proj_b[l * HDIM + h];
    const float* pw = proj_w + (size_t)l * 2 * HDIM * HDIM;
    const float* sb = self_b + l * HDIM;
    for (int m = 0; m < HDIM; ++m) acc += sb[m] * pw[m * HDIM + h];
    bsp[i] = acc;
}

// radial LUT
__global__ void k_lut(const float* __restrict__ widths, const float* __restrict__ rad_w1,
                      const float* __restrict__ rad_b1, const float* __restrict__ W2s,
                      const float* __restrict__ b2s, float* __restrict__ lut) {
    int bid = blockIdx.x;                 // l*TLUT + t
    int l = bid / TLUT, t = bid % TLUT;
    int h = threadIdx.x;                  // 64 threads
    __shared__ float h1s[HDIM];
    float len = (float)t * (CUT_R / (float)(TLUT - 1));
    float cut = 0.0f;
    if (len < CUT_R) cut = 0.5f * (cosf(len * (PI_F / CUT_R)) + 1.0f);
    float acc = rad_b1[l * HDIM + h];
    for (int b = 0; b < NBASIS; ++b) {
        float wb = fmaxf(widths[b], 0.1f);
        float center = (float)b * (CUT_R / (float)(NBASIS - 1));
        float d = (len - center) / wb;
        float rbf = __expf(-0.5f * d * d) * cut;
        acc += rbf * rad_w1[(l * NBASIS + b) * HDIM + h];
    }
    h1s[h] = siluf(acc);
    __syncthreads();
    float o = b2s[l * HDIM + h];
    const float* w2 = W2s + (size_t)l * HDIM * HDIM;
    for (int k = 0; k < HDIM; ++k) o += h1s[k] * w2[k * HDIM + h];
    lut[(size_t)bid * HDIM + h] = o;
}

// lutQb[(l*TLUT+t)*16+j] = uint4; comp c packs bf16(lut[t][4j+c]) | bf16(lut[t+1][4j+c])<<16
__global__ void k_lutq(const float* __restrict__ lut, uint4* __restrict__ lutQb) {
    int i = blockIdx.x * blockDim.x + threadIdx.x;          // L*TLUT*16
    if (i >= NLAYER * TLUT * 16) return;
    int j = i & 15;
    int lt = i >> 4;
    int l = lt / TLUT, t = lt % TLUT;
    int t1 = (t < TLUT - 1) ? t + 1 : t;
    const float* r0 = lut + (size_t)(l * TLUT + t)  * HDIM + 4 * j;
    const float* r1 = lut + (size_t)(l * TLUT + t1) * HDIM + 4 * j;
    uint4 o;
    o.x = f2bf(r0[0]) | (f2bf(r1[0]) << 16);
    o.y = f2bf(r0[1]) | (f2bf(r1[1]) << 16);
    o.z = f2bf(r0[2]) | (f2bf(r1[2]) << 16);
    o.w = f2bf(r0[3]) | (f2bf(r1[3]) << 16);
    lutQb[i] = o;
}

// ---------------- per-layer kernels ----------------

// one wave per node, 8 edge slots x 8 lanes (8 channels each via uint4 loads).
__global__ __launch_bounds__(256) void k_agg(const uint4* __restrict__ featsbf4,
                                             const uint4* __restrict__ lutQb_l,
                                             const int* __restrict__ starts,
                                             const unsigned int* __restrict__ erec,
                                             uint4* __restrict__ aggbf4) {
    int wid  = (blockIdx.x * blockDim.x + threadIdx.x) >> 6;
    int lane = threadIdx.x & 63;
    int slot = lane >> 3;     // 0..7
    int j    = lane & 7;      // channel octet
    if (wid >= N_NODES) return;
    int e0 = starts[wid], e1 = starts[wid + 1];
    float a0 = 0, a1 = 0, a2 = 0, a3 = 0, a4 = 0, a5 = 0, a6 = 0, a7 = 0;
    #pragma unroll 2
    for (int e = e0 + slot; e < e1; e += 8) {
        unsigned int rec = erec[e];
        int c    = rec >> 16;
        int tfix = rec & 0xffff;
        int i0   = tfix >> 7;
        float f  = (float)(tfix & 127) * (1.0f / 128.0f);
        uint4 q0 = lutQb_l[i0 * 16 + 2 * j];
        uint4 q1 = lutQb_l[i0 * 16 + 2 * j + 1];
        uint4 fb = featsbf4[(size_t)c * 8 + j];
        a0 += bf_lo(fb.x) * lrp(q0.x, f);
        a1 += bf_hi(fb.x) * lrp(q0.y, f);
        a2 += bf_lo(fb.y) * lrp(q0.z, f);
        a3 += bf_hi(fb.y) * lrp(q0.w, f);
        a4 += bf_lo(fb.z) * lrp(q1.x, f);
        a5 += bf_hi(fb.z) * lrp(q1.y, f);
        a6 += bf_lo(fb.w) * lrp(q1.z, f);
        a7 += bf_hi(fb.w) * lrp(q1.w, f);
    }
    #pragma unroll
    for (int off = 8; off < 64; off <<= 1) {
        a0 += __shfl_xor(a0, off, 64);  a1 += __shfl_xor(a1, off, 64);
        a2 += __shfl_xor(a2, off, 64);  a3 += __shfl_xor(a3, off, 64);
        a4 += __shfl_xor(a4, off, 64);  a5 += __shfl_xor(a5, off, 64);
        a6 += __shfl_xor(a6, off, 64);  a7 += __shfl_xor(a7, off, 64);
    }
    if (slot == 0) {
        uint4 o;
        o.x = f2bf(a0) | (f2bf(a1) << 16);
        o.y = f2bf(a2) | (f2bf(a3) << 16);
        o.z = f2bf(a4) | (f2bf(a5) << 16);
        o.w = f2bf(a6) | (f2bf(a7) << 16);
        aggbf4[(size_t)wid * 8 + j] = o;
    }
}

// k_node v3 (MFMA): 64 nodes/block, 4 waves; wave w owns node rows [16w,16w+16).
constexpr int BP = 72;                     // bf16 LDS row pitch
__global__ __launch_bounds__(256) void k_node(float* __restrict__ feats,
        unsigned short* __restrict__ featsbf,
        const unsigned short* __restrict__ aggbf,
        const unsigned short* __restrict__ WspT_l, const unsigned short* __restrict__ PbT_l,
        const unsigned short* __restrict__ W1T_l, const unsigned short* __restrict__ W2T_l,
        const float* __restrict__ bsp_l,
        const float* __restrict__ mlp_b1_l, const float* __restrict__ mlp_b2_l,
        const float* __restrict__ ln_g_l, const float* __restrict__ ln_b_l) {
    __shared__ unsigned short P[64 * BP];   // x -> conv
    __shared__ unsigned short Q[64 * BP];   // a -> m1_lo
    __shared__ unsigned short S[64 * BP];   // m1_hi
    const int tid  = threadIdx.x;
    const int lane = tid & 63;
    const int wib  = tid >> 6;
    const int mt   = __builtin_amdgcn_readfirstlane(wib);
    const int nb0  = blockIdx.x * 64;
    const int colL = lane & 15;
    const int kgrp = lane >> 4;

    #pragma unroll 4
    for (int i = 0; i < 16; ++i) {
        int r  = wib + i * 4;
        int nd = nb0 + r; nd = (nd < N_NODES) ? nd : (N_NODES - 1);
        P[r * BP + lane] = featsbf[(size_t)nd * 64 + lane];
        Q[r * BP + lane] = aggbf[(size_t)nd * 64 + lane];
    }
    __syncthreads();

    // ---- conv = x@Wsp + a@Pb + bsp ----
    f32x4 acc[4];
    #pragma unroll
    for (int nt = 0; nt < 4; ++nt) {
        float b = bsp_l[nt * 16 + colL];
        acc[nt][0] = b; acc[nt][1] = b; acc[nt][2] = b; acc[nt][3] = b;
    }
    #pragma unroll
    for (int kb = 0; kb < 2; ++kb) {
        short8 ax = *(const short8*)&P[(mt * 16 + colL) * BP + kb * 32 + kgrp * 8];
        short8 aa = *(const short8*)&Q[(mt * 16 + colL) * BP + kb * 32 + kgrp * 8];
        #pragma unroll
        for (int nt = 0; nt < 4; ++nt) {
            short8 bw = *(const short8*)&WspT_l[(nt * 16 + colL) * 64 + kb * 32 + kgrp * 8];
            acc[nt] = MFMA16(ax, bw, acc[nt], 0, 0, 0);
            short8 bp = *(const short8*)&PbT_l[(nt * 16 + colL) * 64 + kb * 32 + kgrp * 8];
            acc[nt] = MFMA16(aa, bp, acc[nt], 0, 0, 0);
        }
    }
    __syncthreads();
    #pragma unroll
    for (int nt = 0; nt < 4; ++nt)
        #pragma unroll
        for (int j = 0; j < 4; ++j)
            P[(mt * 16 + kgrp * 4 + j) * BP + nt * 16 + colL] = (unsigned short)f2bf(acc[nt][j]);
    __syncthreads();

    // ---- m1 = silu(conv@W1 + b1), 128 wide ----
    {
        f32x4 m[8];
        #pragma unroll
        for (int nt = 0; nt < 8; ++nt) {
            float b = mlp_b1_l[nt * 16 + colL];
            m[nt][0] = b; m[nt][1] = b; m[nt][2] = b; m[nt][3] = b;
        }
        #pragma unroll
        for (int kb = 0; kb < 2; ++kb) {
            short8 ac = *(const short8*)&P[(mt * 16 + colL) * BP + kb * 32 + kgrp * 8];
            #pragma unroll
            for (int nt = 0; nt < 8; ++nt) {
                short8 bw = *(const short8*)&W1T_l[(nt * 16 + colL) * 64 + kb * 32 + kgrp * 8];
                m[nt] = MFMA16(ac, bw, m[nt], 0, 0, 0);
            }
        }
        __syncthreads();
        #pragma unroll
        for (int nt = 0; nt < 4; ++nt)
            #pragma unroll
            for (int j = 0; j < 4; ++j)
                Q[(mt * 16 + kgrp * 4 + j) * BP + nt * 16 + colL] =
                    (unsigned short)f2bf(siluf(m[nt][j]));
        #pragma unroll
        for (int nt = 4; nt < 8; ++nt)
            #pragma unroll
            for (int j = 0; j < 4; ++j)
                S[(mt * 16 + kgrp * 4 + j) * BP + (nt - 4) * 16 + colL] =
                    (unsigned short)f2bf(siluf(m[nt][j]));
    }
    __syncthreads();

    // ---- upd = m1@W2 + b2 ----
    f32x4 u[4];
    #pragma unroll
    for (int nt = 0; nt < 4; ++nt) {
        float b = mlp_b2_l[nt * 16 + colL];
        u[nt][0] = b; u[nt][1] = b; u[nt][2] = b; u[nt][3] = b;
    }
    #pragma unroll
    for (int kb = 0; kb < 4; ++kb) {
        short8 am = (kb < 2)
            ? *(const short8*)&Q[(mt * 16 + colL) * BP + kb * 32 + kgrp * 8]
            : *(const short8*)&S[(mt * 16 + colL) * BP + (kb - 2) * 32 + kgrp * 8];
        #pragma unroll
        for (int nt = 0; nt < 4; ++nt) {
            short8 bw = *(const short8*)&W2T_l[(nt * 16 + colL) * 128 + kb * 32 + kgrp * 8];
            u[nt] = MFMA16(am, bw, u[nt], 0, 0, 0);
        }
    }

    // ---- residual + LayerNorm ----
    float y[4][4];
    float s1[4] = {0, 0, 0, 0}, s2[4] = {0, 0, 0, 0};
    #pragma unroll
    for (int j = 0; j < 4; ++j) {
        int node = nb0 + mt * 16 + kgrp * 4 + j;
        int nds  = (node < N_NODES) ? node : (N_NODES - 1);
        #pragma unroll
        for (int nt = 0; nt < 4; ++nt) {
            float v = feats[(size_t)nds * 64 + nt * 16 + colL] + u[nt][j];
            y[nt][j] = v;
            s1[j] += v; s2[j] += v * v;
        }
    }
    #pragma unroll
    for (int off = 1; off < 16; off <<= 1) {
        #pragma unroll
        for (int j = 0; j < 4; ++j) {
            s1[j] += __shfl_xor(s1[j], off, 64);
            s2[j] += __shfl_xor(s2[j], off, 64);
        }
    }
    float gv[4], bv[4];
    #pragma unroll
    for (int nt = 0; nt < 4; ++nt) {
        gv[nt] = ln_g_l[nt * 16 + colL];
        bv[nt] = ln_b_l[nt * 16 + colL];
    }
    #pragma unroll
    for (int j = 0; j < 4; ++j) {
        int node = nb0 + mt * 16 + kgrp * 4 + j;
        if (node >= N_NODES) continue;
        float mu  = s1[j] * (1.0f / 64.0f);
        float var = s2[j] * (1.0f / 64.0f) - mu * mu;
        float rr  = rsqrtf(var + 1e-5f);
        #pragma unroll
        for (int nt = 0; nt < 4; ++nt) {
            float o = (y[nt][j] - mu) * rr * gv[nt] + bv[nt];
            feats[(size_t)node * 64 + nt * 16 + colL]   = o;
            featsbf[(size_t)node * 64 + nt * 16 + colL] = (unsigned short)f2bf(o);
        }
    }
}

// ---------------- readout ----------------

__global__ __launch_bounds__(256) void k_readout(const float* __restrict__ feats,
        const int* __restrict__ an,
        const float* __restrict__ ro_w1, const float* __restrict__ ro_b1,
        const float* __restrict__ ro_w2, const float* __restrict__ ro_b2,
        const float* __restrict__ ro_w3, const float* __restrict__ ro_b3,
        const float* __restrict__ atomic_e, float* __restrict__ blockpart) {
    __shared__ float sacc[4];
    int wib  = threadIdx.x >> 6;
    int lane = threadIdx.x & 63;
    int node = blockIdx.x * 4 + wib;
    float e = 0.0f;
    if (node < N_NODES) {
        float x = feats[(size_t)node * HDIM + lane];
        float h1 = ro_b1[lane];
        #pragma unroll 8
        for (int k = 0; k < HDIM; ++k) h1 += bcastf(x, k) * ro_w1[k * HDIM + lane];
        h1 = siluf(h1);
        int j = lane & 31;
        float h2 = ro_b2[j];
        #pragma unroll 8
        for (int k = 0; k < HDIM; ++k) h2 += bcastf(h1, k) * ro_w2[k * 32 + j];
        h2 = siluf(h2);
        float contrib = (lane < 32) ? h2 * ro_w3[j] : 0.0f;
        contrib = waveRedSum(contrib);
        e = contrib + ro_b3[0] + atomic_e[an[node]];
    }
    if (lane == 0) sacc[wib] = e;
    __syncthreads();
    if (threadIdx.x == 0)
        blockpart[blockIdx.x] = sacc[0] + sacc[1] + sacc[2] + sacc[3];
}

__global__ void k_final(const float* __restrict__ blockpart, int nb, float* __restrict__ out) {
    __shared__ float s[256];
    float acc = 0.f;
    for (int i = threadIdx.x; i < nb; i += 256) acc += blockpart[i];
    s[threadIdx.x] = acc; __syncthreads();
    for (int off = 128; off > 0; off >>= 1) {
        if (threadIdx.x < off) s[threadIdx.x] += s[threadIdx.x + off];
        __syncthreads();
    }
    if (threadIdx.x == 0) out[0] = s[0];
}

// ---------------- launch ----------------

extern "C" void kernel_launch(void* const* d_in, const int* in_sizes, int n_in,
                              void* d_out, int out_size, void* d_ws, size_t ws_size,
                              hipStream_t stream) {
    const int*   an       = (const int*)  d_in[0];
    const float* pos      = (const float*)d_in[1];
    const int*   edge     = (const int*)  d_in[2];
    const float* widths   = (const float*)d_in[3];
    const float* embed    = (const float*)d_in[4];
    const float* rad_w1   = (const float*)d_in[5];
    const float* rad_b1   = (const float*)d_in[6];
    const float* rad_w2   = (const float*)d_in[7];
    const float* rad_b2   = (const float*)d_in[8];
    const float* self_w   = (const float*)d_in[9];
    const float* self_b   = (const float*)d_in[10];
    const float* proj_w   = (const float*)d_in[11];
    const float* proj_b   = (const float*)d_in[12];
    const float* mlp_w1   = (const float*)d_in[13];
    const float* mlp_b1   = (const float*)d_in[14];
    const float* mlp_w2   = (const float*)d_in[15];
    const float* mlp_b2   = (const float*)d_in[16];
    const float* ln_g     = (const float*)d_in[17];
    const float* ln_b     = (const float*)d_in[18];
    const float* ro_w1    = (const float*)d_in[19];
    const float* ro_b1    = (const float*)d_in[20];
    const float* ro_w2    = (const float*)d_in[21];
    const float* ro_b2    = (const float*)d_in[22];
    const float* ro_w3    = (const float*)d_in[23];
    const float* ro_b3    = (const float*)d_in[24];
    const float* atomic_e = (const float*)d_in[25];

    char* w = (char*)d_ws;
    auto alloc = [&](size_t bytes) { char* p = w; w += (bytes + 255) & ~(size_t)255; return p; };
    float* feats     = (float*)alloc(sizeof(float) * N_NODES * HDIM);
    unsigned short* featsbf = (unsigned short*)alloc(sizeof(unsigned short) * N_NODES * HDIM);
    unsigned short* aggbf   = (unsigned short*)alloc(sizeof(unsigned short) * N_NODES * HDIM);
    float* lut       = (float*)alloc(sizeof(float) * NLAYER * TLUT * HDIM);
    uint4* lutQb     = (uint4*)alloc(sizeof(uint4) * NLAYER * TLUT * 16);
    float* W2s       = (float*)alloc(sizeof(float) * NLAYER * HDIM * HDIM);
    float* b2s       = (float*)alloc(sizeof(float) * NLAYER * HDIM);
    float* Wsp       = (float*)alloc(sizeof(float) * NLAYER * HDIM * HDIM);
    float* bsp       = (float*)alloc(sizeof(float) * NLAYER * HDIM);
    unsigned short* WspT = (unsigned short*)alloc(sizeof(unsigned short) * NLAYER * 4096);
    unsigned short* PbT  = (unsigned short*)alloc(sizeof(unsigned short) * NLAYER * 4096);
    unsigned short* W1T  = (unsigned short*)alloc(sizeof(unsigned short) * NLAYER * 8192);
    unsigned short* W2T  = (unsigned short*)alloc(sizeof(unsigned short) * NLAYER * 8192);
    unsigned int* erec = (unsigned int*)alloc(sizeof(unsigned int) * N_EDGES);
    uint2* binned    = (uint2*)alloc(sizeof(uint2) * (size_t)NBKT * BCAP);
    int*   btail     = (int*)  alloc(sizeof(int) * 64);
    int*   bbase     = (int*)  alloc(sizeof(int) * 64);
    int*   starts    = (int*)  alloc(sizeof(int) * (N_NODES + 1));
    float* blockpart = (float*)alloc(sizeof(float) * 12500);
    (void)ws_size; (void)in_sizes; (void)n_in; (void)out_size;

    const int* erow = edge;
    const int* ecol = edge + N_EDGES;

    hipMemsetAsync(btail, 0, sizeof(int) * 64, stream);
    k_embed<<<12500, 256, 0, stream>>>(an, embed, feats, featsbf);
    k_binA<<<(N_EDGES + TILE - 1) / TILE, 256, 0, stream>>>(erow, ecol, pos, btail, binned);
    k_scanB<<<1, 64, 0, stream>>>(btail, bbase);
    k_binB<<<NBKT, 256, 0, stream>>>(binned, btail, bbase, starts, erec);
    k_prep<<<80, 256, 0, stream>>>(rad_w2, self_w, proj_w, W2s, Wsp);
    k_wtr<<<(NLAYER * 24576 + 255) / 256, 256, 0, stream>>>(Wsp, proj_w, mlp_w1, mlp_w2,
                                                            WspT, PbT, W1T, W2T);
    k_bias<<<5, 64, 0, stream>>>(rad_b2, self_b, proj_w, proj_b, b2s, bsp);
    k_lut<<<NLAYER * TLUT, 64, 0, stream>>>(widths, rad_w1, rad_b1, W2s, b2s, lut);
    k_lutq<<<(NLAYER * TLUT * 16 + 255) / 256, 256, 0, stream>>>(lut, lutQb);

    for (int l = 0; l < NLAYER; ++l) {
        k_agg<<<12500, 256, 0, stream>>>((const uint4*)featsbf,
                                         lutQb + (size_t)l * TLUT * 16,
                                         starts, erec, (uint4*)aggbf);
        k_node<<<782, 256, 0, stream>>>(feats, featsbf, aggbf,
            WspT + (size_t)l * 4096, PbT + (size_t)l * 4096,
            W1T + (size_t)l * 8192, W2T + (size_t)l * 8192,
            bsp + l * HDIM, mlp_b1 + l * 2 * HDIM, mlp_b2 + l * HDIM,
            ln_g + l * HDIM, ln_b + l * HDIM);
    }

    k_readout<<<12500, 256, 0, stream>>>(feats, an, ro_w1, ro_b1, ro_w2, ro_b2,
                                         ro_w3, ro_b3, atomic_e, blockpart);
    k_final<<<1, 256, 0, stream>>>(blockpart, 12500, (float*)d_out);
}

// Round 14
// 490.057 us; speedup vs baseline: 5.7895x; 1.0939x over previous
//
#include <hip/hip_runtime.h>
#include <math.h>

// Problem constants (from reference)
constexpr int N_NODES = 50000;
constexpr int N_EDGES = 1600000;
constexpr int HDIM    = 64;
constexpr int NLAYER  = 5;
constexpr int NBASIS  = 8;
constexpr int TLUT    = 512;           // radial LUT entries per layer
constexpr float CUT_R = 5.0f;
constexpr float PI_F  = 3.14159265358979f;

// binned scatter: buckets of 256 nodes (r >> 8)
constexpr int NBKT = 196;
constexpr int BCAP = 9216;             // mean 8192 + ~11 sigma
constexpr int TILE = 2048;

typedef __attribute__((ext_vector_type(8))) short short8;   // 8 bf16 (4 VGPRs)
typedef __attribute__((ext_vector_type(4))) float f32x4;    // MFMA acc
#define MFMA16 __builtin_amdgcn_mfma_f32_16x16x32_bf16

__device__ __forceinline__ float bcastf(float v, int l) {
    return __uint_as_float(__builtin_amdgcn_readlane(__float_as_uint(v), l));
}
__device__ __forceinline__ float waveRedSum(float v) {
    for (int off = 32; off > 0; off >>= 1) v += __shfl_xor(v, off, 64);
    return v;
}
__device__ __forceinline__ float siluf(float x) { return x / (1.0f + __expf(-x)); }

// round-to-nearest-even f32 -> bf16 bits
__device__ __forceinline__ unsigned int f2bf(float x) {
    unsigned int b = __float_as_uint(x);
    return (b + 0x7fffu + ((b >> 16) & 1u)) >> 16;
}
__device__ __forceinline__ float bf_lo(unsigned int u) { return __uint_as_float(u << 16); }
__device__ __forceinline__ float bf_hi(unsigned int u) { return __uint_as_float(u & 0xffff0000u); }
__device__ __forceinline__ float lrp(unsigned int u, float f) {
    float lo = bf_lo(u), hi = bf_hi(u);
    return lo + f * (hi - lo);
}

// ---------------- setup kernels ----------------

__global__ void k_embed(const int* __restrict__ an, const float* __restrict__ embed,
                        float* __restrict__ feats, unsigned short* __restrict__ featsbf) {
    int i = blockIdx.x * blockDim.x + threadIdx.x;           // N*H threads
    if (i >= N_NODES * HDIM) return;
    int node = i >> 6, h = i & 63;
    float v = embed[an[node] * HDIM + h];
    feats[i] = v;
    featsbf[i] = (unsigned short)f2bf(v);
}

// pass A: block-sort 2048-edge tiles by node bucket (r>>8), append runs to binned[]
__global__ __launch_bounds__(256) void k_binA(const int* __restrict__ row,
                                              const int* __restrict__ col,
                                              const float* __restrict__ pos,
                                              int* __restrict__ btail,
                                              uint2* __restrict__ binned) {
    __shared__ uint2 ent[TILE];          // 16 KB: payload {rec, row}
    __shared__ short bb[TILE];           // 4 KB: bucket id
    __shared__ uint2 sorted[TILE];       // 16 KB
    __shared__ int cnt[256], cnt2[256], base[256], gbase[256], scn[256];
    const int tid = threadIdx.x;
    const int t0  = blockIdx.x * TILE;
    const int nv  = min(TILE, N_EDGES - t0);

    cnt[tid] = 0;
    __syncthreads();

    #pragma unroll
    for (int i = 0; i < TILE / 256; ++i) {
        int idx = i * 256 + tid;
        if (idx < nv) {
            int e = t0 + idx;
            int r = row[e], c = col[e];
            float dx = pos[c * 3 + 0] - pos[r * 3 + 0];
            float dy = pos[c * 3 + 1] - pos[r * 3 + 1];
            float dz = pos[c * 3 + 2] - pos[r * 3 + 2];
            float len = sqrtf(dx * dx + dy * dy + dz * dz);
            float t = len * ((float)(TLUT - 1) / CUT_R);
            t = fminf(t, (float)(TLUT - 1));
            unsigned int tfix = (unsigned int)(t * 128.0f);
            uint2 p;
            p.x = ((unsigned int)c << 16) | tfix;
            p.y = (unsigned int)r;
            ent[idx] = p;
            int b = r >> 8;
            bb[idx] = (short)b;
            atomicAdd(&cnt[b], 1);
        }
    }
    __syncthreads();
    // parallel exclusive scan of cnt[0..255]
    int cv = cnt[tid];
    scn[tid] = cv;
    __syncthreads();
    for (int off = 1; off < 256; off <<= 1) {
        int add = (tid >= off) ? scn[tid - off] : 0;
        __syncthreads();
        scn[tid] += add;
        __syncthreads();
    }
    base[tid] = scn[tid] - cv;
    if (tid < NBKT && cv > 0) gbase[tid] = atomicAdd(&btail[tid], cv);
    cnt2[tid] = base[tid];
    __syncthreads();
    #pragma unroll
    for (int i = 0; i < TILE / 256; ++i) {
        int idx = i * 256 + tid;
        if (idx < nv) {
            int b = bb[idx];
            int p = atomicAdd(&cnt2[b], 1);
            sorted[p] = ent[idx];
        }
    }
    __syncthreads();
    for (int s = tid; s < nv; s += 256) {
        uint2 p = sorted[s];
        int b = (int)(p.y >> 8);
        binned[(size_t)b * BCAP + gbase[b] + (s - base[b])] = p;
    }
}

// exclusive scan of 196 bucket totals (1 block, 256 threads)
__global__ void k_scanB(const int* __restrict__ btail, int* __restrict__ bbase) {
    __shared__ int s[256];
    int t = threadIdx.x;
    int v = (t < NBKT) ? btail[t] : 0;
    s[t] = v; __syncthreads();
    for (int off = 1; off < 256; off <<= 1) {
        int add = (t >= off) ? s[t - off] : 0;
        __syncthreads();
        s[t] += add;
        __syncthreads();
    }
    if (t < NBKT) bbase[t] = s[t] - v;
}

// pass B v3: one block per 256-node bucket. LDS histogram -> scan -> starts ->
// scatter erec via LDS cursors. No global atomics.
__global__ __launch_bounds__(256) void k_binB(const uint2* __restrict__ binned,
                                              const int* __restrict__ btail,
                                              const int* __restrict__ bbase,
                                              int* __restrict__ starts,
                                              unsigned int* __restrict__ erec) {
    __shared__ int hist[256];
    __shared__ int scn[256];
    __shared__ int cur[256];
    const int b = blockIdx.x;
    const int node0 = b << 8;
    const int t = threadIdx.x;
    hist[t] = 0;
    __syncthreads();
    const int cnt = btail[b];
    const uint2* src = binned + (size_t)b * BCAP;
    for (int s = t; s < cnt; s += 256)
        atomicAdd(&hist[src[s].y & 255], 1);
    __syncthreads();
    int h = hist[t];
    scn[t] = h;
    __syncthreads();
    for (int off = 1; off < 256; off <<= 1) {
        int add = (t >= off) ? scn[t - off] : 0;
        __syncthreads();
        scn[t] += add;
        __syncthreads();
    }
    int excl = bbase[b] + scn[t] - h;
    int n = node0 + t;
    if (n < N_NODES) starts[n] = excl;
    if (b == 0 && t == 0) starts[N_NODES] = N_EDGES;
    cur[t] = excl;
    __syncthreads();
    for (int s = t; s < cnt; s += 256) {
        uint2 p = src[s];
        int pp = atomicAdd(&cur[p.y & 255], 1);
        erec[pp] = p.x;
    }
}

// W2s[l][k][h] = sum_{m<3} rad_w2[l][k][h*3+m]; Wsp[l][k][h] = (self_w @ proj_top)[k][h]
__global__ void k_prep(const float* __restrict__ rad_w2, const float* __restrict__ self_w,
                       const float* __restrict__ proj_w,
                       float* __restrict__ W2s, float* __restrict__ Wsp) {
    int i = blockIdx.x * blockDim.x + threadIdx.x;          // L*H*H
    if (i >= NLAYER * HDIM * HDIM) return;
    int l = i / (HDIM * HDIM); int rem = i % (HDIM * HDIM);
    int k = rem / HDIM; int h = rem % HDIM;
    const float* w = rad_w2 + ((size_t)l * HDIM + k) * (HDIM * 3) + h * 3;
    W2s[i] = w[0] + w[1] + w[2];
    const float* sw = self_w + ((size_t)l * HDIM + k) * HDIM;
    const float* pw = proj_w + (size_t)l * 2 * HDIM * HDIM;
    float acc = 0.f;
    for (int m = 0; m < HDIM; ++m) acc += sw[m] * pw[m * HDIM + h];
    Wsp[i] = acc;
}

// bf16 transposed weights for MFMA B-operands: layout [n][k] contiguous in k
__global__ void k_wtr(const float* __restrict__ Wsp, const float* __restrict__ proj_w,
                      const float* __restrict__ mlp_w1, const float* __restrict__ mlp_w2,
                      unsigned short* __restrict__ WspT, unsigned short* __restrict__ PbT,
                      unsigned short* __restrict__ W1T, unsigned short* __restrict__ W2T) {
    int i = blockIdx.x * blockDim.x + threadIdx.x;          // L * 24576
    if (i >= NLAYER * 24576) return;
    int l = i / 24576, off = i % 24576;
    if (off < 4096) {
        int n = off >> 6, k = off & 63;
        WspT[(size_t)l * 4096 + off] = (unsigned short)f2bf(Wsp[(size_t)l * 4096 + k * 64 + n]);
    } else if (off < 8192) {
        int o = off - 4096; int n = o >> 6, k = o & 63;
        PbT[(size_t)l * 4096 + o] =
            (unsigned short)f2bf(proj_w[(size_t)l * 8192 + (64 + k) * 64 + n]);
    } else if (off < 16384) {
        int o = off - 8192; int n = o >> 6, k = o & 63;
        W1T[(size_t)l * 8192 + o] = (unsigned short)f2bf(mlp_w1[(size_t)l * 8192 + k * 128 + n]);
    } else {
        int o = off - 16384; int n = o >> 7, k = o & 127;
        W2T[(size_t)l * 8192 + o] = (unsigned short)f2bf(mlp_w2[(size_t)l * 8192 + k * 64 + n]);
    }
}

// b2s[l][h] = sum_m rad_b2[l][h*3+m];  bsp[l][h] = self_b@proj_top + proj_b
__global__ void k_bias(const float* __restrict__ rad_b2, const float* __restrict__ self_b,
                       const float* __restrict__ proj_w, const float* __restrict__ proj_b,
                       float* __restrict__ b2s, float* __restrict__ bsp) {
    int i = blockIdx.x * blockDim.x + threadIdx.x;          // L*H
    if (i >= NLAYER * HDIM) return;
    int l = i / HDIM, h = i % HDIM;
    const float* rb2 = rad_b2 + l * HDIM * 3 + h * 3;
    b2s[i] = rb2[0] + rb2[1] + rb2[2];
    float acc = proj_b[l * HDIM + h];
    const float* pw = proj_w + (size_t)l * 2 * HDIM * HDIM;
    const float* sb = self_b + l * HDIM;
    for (int m = 0; m < HDIM; ++m) acc += sb[m] * pw[m * HDIM + h];
    bsp[i] = acc;
}

// radial LUT
__global__ void k_lut(const float* __restrict__ widths, const float* __restrict__ rad_w1,
                      const float* __restrict__ rad_b1, const float* __restrict__ W2s,
                      const float* __restrict__ b2s, float* __restrict__ lut) {
    int bid = blockIdx.x;                 // l*TLUT + t
    int l = bid / TLUT, t = bid % TLUT;
    int h = threadIdx.x;                  // 64 threads
    __shared__ float h1s[HDIM];
    float len = (float)t * (CUT_R / (float)(TLUT - 1));
    float cut = 0.0f;
    if (len < CUT_R) cut = 0.5f * (cosf(len * (PI_F / CUT_R)) + 1.0f);
    float acc = rad_b1[l * HDIM + h];
    for (int b = 0; b < NBASIS; ++b) {
        float wb = fmaxf(widths[b], 0.1f);
        float center = (float)b * (CUT_R / (float)(NBASIS - 1));
        float d = (len - center) / wb;
        float rbf = __expf(-0.5f * d * d) * cut;
        acc += rbf * rad_w1[(l * NBASIS + b) * HDIM + h];
    }
    h1s[h] = siluf(acc);
    __syncthreads();
    float o = b2s[l * HDIM + h];
    const float* w2 = W2s + (size_t)l * HDIM * HDIM;
    for (int k = 0; k < HDIM; ++k) o += h1s[k] * w2[k * HDIM + h];
    lut[(size_t)bid * HDIM + h] = o;
}

// lutQb[(l*TLUT+t)*16+j] = uint4; comp c packs bf16(lut[t][4j+c]) | bf16(lut[t+1][4j+c])<<16
__global__ void k_lutq(const float* __restrict__ lut, uint4* __restrict__ lutQb) {
    int i = blockIdx.x * blockDim.x + threadIdx.x;          // L*TLUT*16
    if (i >= NLAYER * TLUT * 16) return;
    int j = i & 15;
    int lt = i >> 4;
    int l = lt / TLUT, t = lt % TLUT;
    int t1 = (t < TLUT - 1) ? t + 1 : t;
    const float* r0 = lut + (size_t)(l * TLUT + t)  * HDIM + 4 * j;
    const float* r1 = lut + (size_t)(l * TLUT + t1) * HDIM + 4 * j;
    uint4 o;
    o.x = f2bf(r0[0]) | (f2bf(r1[0]) << 16);
    o.y = f2bf(r0[1]) | (f2bf(r1[1]) << 16);
    o.z = f2bf(r0[2]) | (f2bf(r1[2]) << 16);
    o.w = f2bf(r0[3]) | (f2bf(r1[3]) << 16);
    lutQb[i] = o;
}

// ---------------- per-layer kernels ----------------

// one wave per node, 8 edge slots x 8 lanes (8 channels each via uint4 loads).
__global__ __launch_bounds__(256) void k_agg(const uint4* __restrict__ featsbf4,
                                             const uint4* __restrict__ lutQb_l,
                                             const int* __restrict__ starts,
                                             const unsigned int* __restrict__ erec,
                                             uint4* __restrict__ aggbf4) {
    int wid  = (blockIdx.x * blockDim.x + threadIdx.x) >> 6;
    int lane = threadIdx.x & 63;
    int slot = lane >> 3;     // 0..7
    int j    = lane & 7;      // channel octet
    if (wid >= N_NODES) return;
    int e0 = starts[wid], e1 = starts[wid + 1];
    float a0 = 0, a1 = 0, a2 = 0, a3 = 0, a4 = 0, a5 = 0, a6 = 0, a7 = 0;
    #pragma unroll 2
    for (int e = e0 + slot; e < e1; e += 8) {
        unsigned int rec = erec[e];
        int c    = rec >> 16;
        int tfix = rec & 0xffff;
        int i0   = tfix >> 7;
        float f  = (float)(tfix & 127) * (1.0f / 128.0f);
        uint4 q0 = lutQb_l[i0 * 16 + 2 * j];
        uint4 q1 = lutQb_l[i0 * 16 + 2 * j + 1];
        uint4 fb = featsbf4[(size_t)c * 8 + j];
        a0 += bf_lo(fb.x) * lrp(q0.x, f);
        a1 += bf_hi(fb.x) * lrp(q0.y, f);
        a2 += bf_lo(fb.y) * lrp(q0.z, f);
        a3 += bf_hi(fb.y) * lrp(q0.w, f);
        a4 += bf_lo(fb.z) * lrp(q1.x, f);
        a5 += bf_hi(fb.z) * lrp(q1.y, f);
        a6 += bf_lo(fb.w) * lrp(q1.z, f);
        a7 += bf_hi(fb.w) * lrp(q1.w, f);
    }
    #pragma unroll
    for (int off = 8; off < 64; off <<= 1) {
        a0 += __shfl_xor(a0, off, 64);  a1 += __shfl_xor(a1, off, 64);
        a2 += __shfl_xor(a2, off, 64);  a3 += __shfl_xor(a3, off, 64);
        a4 += __shfl_xor(a4, off, 64);  a5 += __shfl_xor(a5, off, 64);
        a6 += __shfl_xor(a6, off, 64);  a7 += __shfl_xor(a7, off, 64);
    }
    if (slot == 0) {
        uint4 o;
        o.x = f2bf(a0) | (f2bf(a1) << 16);
        o.y = f2bf(a2) | (f2bf(a3) << 16);
        o.z = f2bf(a4) | (f2bf(a5) << 16);
        o.w = f2bf(a6) | (f2bf(a7) << 16);
        aggbf4[(size_t)wid * 8 + j] = o;
    }
}

// k_node v3 (MFMA): 64 nodes/block, 4 waves; wave w owns node rows [16w,16w+16).
constexpr int BP = 72;                     // bf16 LDS row pitch
__global__ __launch_bounds__(256) void k_node(float* __restrict__ feats,
        unsigned short* __restrict__ featsbf,
        const unsigned short* __restrict__ aggbf,
        const unsigned short* __restrict__ WspT_l, const unsigned short* __restrict__ PbT_l,
        const unsigned short* __restrict__ W1T_l, const unsigned short* __restrict__ W2T_l,
        const float* __restrict__ bsp_l,
        const float* __restrict__ mlp_b1_l, const float* __restrict__ mlp_b2_l,
        const float* __restrict__ ln_g_l, const float* __restrict__ ln_b_l) {
    __shared__ unsigned short P[64 * BP];   // x -> conv
    __shared__ unsigned short Q[64 * BP];   // a -> m1_lo
    __shared__ unsigned short S[64 * BP];   // m1_hi
    const int tid  = threadIdx.x;
    const int lane = tid & 63;
    const int wib  = tid >> 6;
    const int mt   = __builtin_amdgcn_readfirstlane(wib);
    const int nb0  = blockIdx.x * 64;
    const int colL = lane & 15;
    const int kgrp = lane >> 4;

    #pragma unroll 4
    for (int i = 0; i < 16; ++i) {
        int r  = wib + i * 4;
        int nd = nb0 + r; nd = (nd < N_NODES) ? nd : (N_NODES - 1);
        P[r * BP + lane] = featsbf[(size_t)nd * 64 + lane];
        Q[r * BP + lane] = aggbf[(size_t)nd * 64 + lane];
    }
    __syncthreads();

    // ---- conv = x@Wsp + a@Pb + bsp ----
    f32x4 acc[4];
    #pragma unroll
    for (int nt = 0; nt < 4; ++nt) {
        float b = bsp_l[nt * 16 + colL];
        acc[nt][0] = b; acc[nt][1] = b; acc[nt][2] = b; acc[nt][3] = b;
    }
    #pragma unroll
    for (int kb = 0; kb < 2; ++kb) {
        short8 ax = *(const short8*)&P[(mt * 16 + colL) * BP + kb * 32 + kgrp * 8];
        short8 aa = *(const short8*)&Q[(mt * 16 + colL) * BP + kb * 32 + kgrp * 8];
        #pragma unroll
        for (int nt = 0; nt < 4; ++nt) {
            short8 bw = *(const short8*)&WspT_l[(nt * 16 + colL) * 64 + kb * 32 + kgrp * 8];
            acc[nt] = MFMA16(ax, bw, acc[nt], 0, 0, 0);
            short8 bp = *(const short8*)&PbT_l[(nt * 16 + colL) * 64 + kb * 32 + kgrp * 8];
            acc[nt] = MFMA16(aa, bp, acc[nt], 0, 0, 0);
        }
    }
    __syncthreads();
    #pragma unroll
    for (int nt = 0; nt < 4; ++nt)
        #pragma unroll
        for (int j = 0; j < 4; ++j)
            P[(mt * 16 + kgrp * 4 + j) * BP + nt * 16 + colL] = (unsigned short)f2bf(acc[nt][j]);
    __syncthreads();

    // ---- m1 = silu(conv@W1 + b1), 128 wide ----
    {
        f32x4 m[8];
        #pragma unroll
        for (int nt = 0; nt < 8; ++nt) {
            float b = mlp_b1_l[nt * 16 + colL];
            m[nt][0] = b; m[nt][1] = b; m[nt][2] = b; m[nt][3] = b;
        }
        #pragma unroll
        for (int kb = 0; kb < 2; ++kb) {
            short8 ac = *(const short8*)&P[(mt * 16 + colL) * BP + kb * 32 + kgrp * 8];
            #pragma unroll
            for (int nt = 0; nt < 8; ++nt) {
                short8 bw = *(const short8*)&W1T_l[(nt * 16 + colL) * 64 + kb * 32 + kgrp * 8];
                m[nt] = MFMA16(ac, bw, m[nt], 0, 0, 0);
            }
        }
        __syncthreads();
        #pragma unroll
        for (int nt = 0; nt < 4; ++nt)
            #pragma unroll
            for (int j = 0; j < 4; ++j)
                Q[(mt * 16 + kgrp * 4 + j) * BP + nt * 16 + colL] =
                    (unsigned short)f2bf(siluf(m[nt][j]));
        #pragma unroll
        for (int nt = 4; nt < 8; ++nt)
            #pragma unroll
            for (int j = 0; j < 4; ++j)
                S[(mt * 16 + kgrp * 4 + j) * BP + (nt - 4) * 16 + colL] =
                    (unsigned short)f2bf(siluf(m[nt][j]));
    }
    __syncthreads();

    // ---- upd = m1@W2 + b2 ----
    f32x4 u[4];
    #pragma unroll
    for (int nt = 0; nt < 4; ++nt) {
        float b = mlp_b2_l[nt * 16 + colL];
        u[nt][0] = b; u[nt][1] = b; u[nt][2] = b; u[nt][3] = b;
    }
    #pragma unroll
    for (int kb = 0; kb < 4; ++kb) {
        short8 am = (kb < 2)
            ? *(const short8*)&Q[(mt * 16 + colL) * BP + kb * 32 + kgrp * 8]
            : *(const short8*)&S[(mt * 16 + colL) * BP + (kb - 2) * 32 + kgrp * 8];
        #pragma unroll
        for (int nt = 0; nt < 4; ++nt) {
            short8 bw = *(const short8*)&W2T_l[(nt * 16 + colL) * 128 + kb * 32 + kgrp * 8];
            u[nt] = MFMA16(am, bw, u[nt], 0, 0, 0);
        }
    }

    // ---- residual + LayerNorm ----
    float y[4][4];
    float s1[4] = {0, 0, 0, 0}, s2[4] = {0, 0, 0, 0};
    #pragma unroll
    for (int j = 0; j < 4; ++j) {
        int node = nb0 + mt * 16 + kgrp * 4 + j;
        int nds  = (node < N_NODES) ? node : (N_NODES - 1);
        #pragma unroll
        for (int nt = 0; nt < 4; ++nt) {
            float v = feats[(size_t)nds * 64 + nt * 16 + colL] + u[nt][j];
            y[nt][j] = v;
            s1[j] += v; s2[j] += v * v;
        }
    }
    #pragma unroll
    for (int off = 1; off < 16; off <<= 1) {
        #pragma unroll
        for (int j = 0; j < 4; ++j) {
            s1[j] += __shfl_xor(s1[j], off, 64);
            s2[j] += __shfl_xor(s2[j], off, 64);
        }
    }
    float gv[4], bv[4];
    #pragma unroll
    for (int nt = 0; nt < 4; ++nt) {
        gv[nt] = ln_g_l[nt * 16 + colL];
        bv[nt] = ln_b_l[nt * 16 + colL];
    }
    #pragma unroll
    for (int j = 0; j < 4; ++j) {
        int node = nb0 + mt * 16 + kgrp * 4 + j;
        if (node >= N_NODES) continue;
        float mu  = s1[j] * (1.0f / 64.0f);
        float var = s2[j] * (1.0f / 64.0f) - mu * mu;
        float rr  = rsqrtf(var + 1e-5f);
        #pragma unroll
        for (int nt = 0; nt < 4; ++nt) {
            float o = (y[nt][j] - mu) * rr * gv[nt] + bv[nt];
            feats[(size_t)node * 64 + nt * 16 + colL]   = o;
            featsbf[(size_t)node * 64 + nt * 16 + colL] = (unsigned short)f2bf(o);
        }
    }
}

// ---------------- readout ----------------

__global__ __launch_bounds__(256) void k_readout(const float* __restrict__ feats,
        const int* __restrict__ an,
        const float* __restrict__ ro_w1, const float* __restrict__ ro_b1,
        const float* __restrict__ ro_w2, const float* __restrict__ ro_b2,
        const float* __restrict__ ro_w3, const float* __restrict__ ro_b3,
        const float* __restrict__ atomic_e, float* __restrict__ blockpart) {
    __shared__ float sacc[4];
    int wib  = threadIdx.x >> 6;
    int lane = threadIdx.x & 63;
    int node = blockIdx.x * 4 + wib;
    float e = 0.0f;
    if (node < N_NODES) {
        float x = feats[(size_t)node * HDIM + lane];
        float h1 = ro_b1[lane];
        #pragma unroll 8
        for (int k = 0; k < HDIM; ++k) h1 += bcastf(x, k) * ro_w1[k * HDIM + lane];
        h1 = siluf(h1);
        int j = lane & 31;
        float h2 = ro_b2[j];
        #pragma unroll 8
        for (int k = 0; k < HDIM; ++k) h2 += bcastf(h1, k) * ro_w2[k * 32 + j];
        h2 = siluf(h2);
        float contrib = (lane < 32) ? h2 * ro_w3[j] : 0.0f;
        contrib = waveRedSum(contrib);
        e = contrib + ro_b3[0] + atomic_e[an[node]];
    }
    if (lane == 0) sacc[wib] = e;
    __syncthreads();
    if (threadIdx.x == 0)
        blockpart[blockIdx.x] = sacc[0] + sacc[1] + sacc[2] + sacc[3];
}

__global__ void k_final(const float* __restrict__ blockpart, int nb, float* __restrict__ out) {
    __shared__ float s[256];
    float acc = 0.f;
    for (int i = threadIdx.x; i < nb; i += 256) acc += blockpart[i];
    s[threadIdx.x] = acc; __syncthreads();
    for (int off = 128; off > 0; off >>= 1) {
        if (threadIdx.x < off) s[threadIdx.x] += s[threadIdx.x + off];
        __syncthreads();
    }
    if (threadIdx.x == 0) out[0] = s[0];
}

// ---------------- launch ----------------

extern "C" void kernel_launch(void* const* d_in, const int* in_sizes, int n_in,
                              void* d_out, int out_size, void* d_ws, size_t ws_size,
                              hipStream_t stream) {
    const int*   an       = (const int*)  d_in[0];
    const float* pos      = (const float*)d_in[1];
    const int*   edge     = (const int*)  d_in[2];
    const float* widths   = (const float*)d_in[3];
    const float* embed    = (const float*)d_in[4];
    const float* rad_w1   = (const float*)d_in[5];
    const float* rad_b1   = (const float*)d_in[6];
    const float* rad_w2   = (const float*)d_in[7];
    const float* rad_b2   = (const float*)d_in[8];
    const float* self_w   = (const float*)d_in[9];
    const float* self_b   = (const float*)d_in[10];
    const float* proj_w   = (const float*)d_in[11];
    const float* proj_b   = (const float*)d_in[12];
    const float* mlp_w1   = (const float*)d_in[13];
    const float* mlp_b1   = (const float*)d_in[14];
    const float* mlp_w2   = (const float*)d_in[15];
    const float* mlp_b2   = (const float*)d_in[16];
    const float* ln_g     = (const float*)d_in[17];
    const float* ln_b     = (const float*)d_in[18];
    const float* ro_w1    = (const float*)d_in[19];
    const float* ro_b1    = (const float*)d_in[20];
    const float* ro_w2    = (const float*)d_in[21];
    const float* ro_b2    = (const float*)d_in[22];
    const float* ro_w3    = (const float*)d_in[23];
    const float* ro_b3    = (const float*)d_in[24];
    const float* atomic_e = (const float*)d_in[25];

    char* w = (char*)d_ws;
    auto alloc = [&](size_t bytes) { char* p = w; w += (bytes + 255) & ~(size_t)255; return p; };
    float* feats     = (float*)alloc(sizeof(float) * N_NODES * HDIM);
    unsigned short* featsbf = (unsigned short*)alloc(sizeof(unsigned short) * N_NODES * HDIM);
    unsigned short* aggbf   = (unsigned short*)alloc(sizeof(unsigned short) * N_NODES * HDIM);
    float* lut       = (float*)alloc(sizeof(float) * NLAYER * TLUT * HDIM);
    uint4* lutQb     = (uint4*)alloc(sizeof(uint4) * NLAYER * TLUT * 16);
    float* W2s       = (float*)alloc(sizeof(float) * NLAYER * HDIM * HDIM);
    float* b2s       = (float*)alloc(sizeof(float) * NLAYER * HDIM);
    float* Wsp       = (float*)alloc(sizeof(float) * NLAYER * HDIM * HDIM);
    float* bsp       = (float*)alloc(sizeof(float) * NLAYER * HDIM);
    unsigned short* WspT = (unsigned short*)alloc(sizeof(unsigned short) * NLAYER * 4096);
    unsigned short* PbT  = (unsigned short*)alloc(sizeof(unsigned short) * NLAYER * 4096);
    unsigned short* W1T  = (unsigned short*)alloc(sizeof(unsigned short) * NLAYER * 8192);
    unsigned short* W2T  = (unsigned short*)alloc(sizeof(unsigned short) * NLAYER * 8192);
    unsigned int* erec = (unsigned int*)alloc(sizeof(unsigned int) * N_EDGES);
    uint2* binned    = (uint2*)alloc(sizeof(uint2) * (size_t)NBKT * BCAP);
    int*   btail     = (int*)  alloc(sizeof(int) * 256);
    int*   bbase     = (int*)  alloc(sizeof(int) * 256);
    int*   starts    = (int*)  alloc(sizeof(int) * (N_NODES + 1));
    float* blockpart = (float*)alloc(sizeof(float) * 12500);
    (void)ws_size; (void)in_sizes; (void)n_in; (void)out_size;

    const int* erow = edge;
    const int* ecol = edge + N_EDGES;

    hipMemsetAsync(btail, 0, sizeof(int) * 256, stream);
    k_embed<<<12500, 256, 0, stream>>>(an, embed, feats, featsbf);
    k_binA<<<(N_EDGES + TILE - 1) / TILE, 256, 0, stream>>>(erow, ecol, pos, btail, binned);
    k_scanB<<<1, 256, 0, stream>>>(btail, bbase);
    k_binB<<<NBKT, 256, 0, stream>>>(binned, btail, bbase, starts, erec);
    k_prep<<<80, 256, 0, stream>>>(rad_w2, self_w, proj_w, W2s, Wsp);
    k_wtr<<<(NLAYER * 24576 + 255) / 256, 256, 0, stream>>>(Wsp, proj_w, mlp_w1, mlp_w2,
                                                            WspT, PbT, W1T, W2T);
    k_bias<<<5, 64, 0, stream>>>(rad_b2, self_b, proj_w, proj_b, b2s, bsp);
    k_lut<<<NLAYER * TLUT, 64, 0, stream>>>(widths, rad_w1, rad_b1, W2s, b2s, lut);
    k_lutq<<<(NLAYER * TLUT * 16 + 255) / 256, 256, 0, stream>>>(lut, lutQb);

    for (int l = 0; l < NLAYER; ++l) {
        k_agg<<<12500, 256, 0, stream>>>((const uint4*)featsbf,
                                         lutQb + (size_t)l * TLUT * 16,
                                         starts, erec, (uint4*)aggbf);
        k_node<<<782, 256, 0, stream>>>(feats, featsbf, aggbf,
            WspT + (size_t)l * 4096, PbT + (size_t)l * 4096,
            W1T + (size_t)l * 8192, W2T + (size_t)l * 8192,
            bsp + l * HDIM, mlp_b1 + l * 2 * HDIM, mlp_b2 + l * HDIM,
            ln_g + l * HDIM, ln_b + l * HDIM);
    }

    k_readout<<<12500, 256, 0, stream>>>(feats, an, ro_w1, ro_b1, ro_w2, ro_b2,
                                         ro_w3, ro_b3, atomic_e, blockpart);
    k_final<<<1, 256, 0, stream>>>(blockpart, 12500, (float*)d_out);
}

// Round 15
// 443.402 us; speedup vs baseline: 6.3987x; 1.1052x over previous
//
#include <hip/hip_runtime.h>
#include <math.h>

// Problem constants (from reference)
constexpr int N_NODES = 50000;
constexpr int N_EDGES = 1600000;
constexpr int HDIM    = 64;
constexpr int NLAYER  = 5;
constexpr int NBASIS  = 8;
constexpr int TLUT    = 512;           // radial LUT entries per layer
constexpr float CUT_R = 5.0f;
constexpr float PI_F  = 3.14159265358979f;

// binned scatter: buckets of 256 nodes (r >> 8)
constexpr int NBKT = 196;
constexpr int BCAP = 9216;             // mean 8192 + ~11 sigma
constexpr int TILE = 2048;

typedef __attribute__((ext_vector_type(8))) short short8;   // 8 bf16 (4 VGPRs)
typedef __attribute__((ext_vector_type(4))) float f32x4;    // MFMA acc
#define MFMA16 __builtin_amdgcn_mfma_f32_16x16x32_bf16

__device__ __forceinline__ float waveRedSum(float v) {
    for (int off = 32; off > 0; off >>= 1) v += __shfl_xor(v, off, 64);
    return v;
}
__device__ __forceinline__ float siluf(float x) { return x / (1.0f + __expf(-x)); }

// round-to-nearest-even f32 -> bf16 bits
__device__ __forceinline__ unsigned int f2bf(float x) {
    unsigned int b = __float_as_uint(x);
    return (b + 0x7fffu + ((b >> 16) & 1u)) >> 16;
}
__device__ __forceinline__ float bf_lo(unsigned int u) { return __uint_as_float(u << 16); }
__device__ __forceinline__ float bf_hi(unsigned int u) { return __uint_as_float(u & 0xffff0000u); }
__device__ __forceinline__ float lrp(unsigned int u, float f) {
    float lo = bf_lo(u), hi = bf_hi(u);
    return lo + f * (hi - lo);
}

// ---------------- setup kernels ----------------

__global__ void k_embed(const int* __restrict__ an, const float* __restrict__ embed,
                        float* __restrict__ feats, unsigned short* __restrict__ featsbf) {
    int i = blockIdx.x * blockDim.x + threadIdx.x;           // N*H threads
    if (i >= N_NODES * HDIM) return;
    int node = i >> 6, h = i & 63;
    float v = embed[an[node] * HDIM + h];
    feats[i] = v;
    featsbf[i] = (unsigned short)f2bf(v);
}

// pass A: block-sort 2048-edge tiles by node bucket (r>>8), append runs to binned[]
__global__ __launch_bounds__(256) void k_binA(const int* __restrict__ row,
                                              const int* __restrict__ col,
                                              const float* __restrict__ pos,
                                              int* __restrict__ btail,
                                              uint2* __restrict__ binned) {
    __shared__ uint2 ent[TILE];          // 16 KB: payload {rec, row}
    __shared__ short bb[TILE];           // 4 KB: bucket id
    __shared__ uint2 sorted[TILE];       // 16 KB
    __shared__ int cnt[256], cnt2[256], base[256], gbase[256], scn[256];
    const int tid = threadIdx.x;
    const int t0  = blockIdx.x * TILE;
    const int nv  = min(TILE, N_EDGES - t0);

    cnt[tid] = 0;
    __syncthreads();

    #pragma unroll
    for (int i = 0; i < TILE / 256; ++i) {
        int idx = i * 256 + tid;
        if (idx < nv) {
            int e = t0 + idx;
            int r = row[e], c = col[e];
            float dx = pos[c * 3 + 0] - pos[r * 3 + 0];
            float dy = pos[c * 3 + 1] - pos[r * 3 + 1];
            float dz = pos[c * 3 + 2] - pos[r * 3 + 2];
            float len = sqrtf(dx * dx + dy * dy + dz * dz);
            float t = len * ((float)(TLUT - 1) / CUT_R);
            t = fminf(t, (float)(TLUT - 1));
            unsigned int tfix = (unsigned int)(t * 128.0f);
            uint2 p;
            p.x = ((unsigned int)c << 16) | tfix;
            p.y = (unsigned int)r;
            ent[idx] = p;
            int b = r >> 8;
            bb[idx] = (short)b;
            atomicAdd(&cnt[b], 1);
        }
    }
    __syncthreads();
    int cv = cnt[tid];
    scn[tid] = cv;
    __syncthreads();
    for (int off = 1; off < 256; off <<= 1) {
        int add = (tid >= off) ? scn[tid - off] : 0;
        __syncthreads();
        scn[tid] += add;
        __syncthreads();
    }
    base[tid] = scn[tid] - cv;
    if (tid < NBKT && cv > 0) gbase[tid] = atomicAdd(&btail[tid], cv);
    cnt2[tid] = base[tid];
    __syncthreads();
    #pragma unroll
    for (int i = 0; i < TILE / 256; ++i) {
        int idx = i * 256 + tid;
        if (idx < nv) {
            int b = bb[idx];
            int p = atomicAdd(&cnt2[b], 1);
            sorted[p] = ent[idx];
        }
    }
    __syncthreads();
    for (int s = tid; s < nv; s += 256) {
        uint2 p = sorted[s];
        int b = (int)(p.y >> 8);
        binned[(size_t)b * BCAP + gbase[b] + (s - base[b])] = p;
    }
}

// exclusive scan of 196 bucket totals (1 block, 256 threads)
__global__ void k_scanB(const int* __restrict__ btail, int* __restrict__ bbase) {
    __shared__ int s[256];
    int t = threadIdx.x;
    int v = (t < NBKT) ? btail[t] : 0;
    s[t] = v; __syncthreads();
    for (int off = 1; off < 256; off <<= 1) {
        int add = (t >= off) ? s[t - off] : 0;
        __syncthreads();
        s[t] += add;
        __syncthreads();
    }
    if (t < NBKT) bbase[t] = s[t] - v;
}

// pass B v3: one block per 256-node bucket. LDS histogram -> scan -> starts ->
// scatter erec via LDS cursors. No global atomics.
__global__ __launch_bounds__(256) void k_binB(const uint2* __restrict__ binned,
                                              const int* __restrict__ btail,
                                              const int* __restrict__ bbase,
                                              int* __restrict__ starts,
                                              unsigned int* __restrict__ erec) {
    __shared__ int hist[256];
    __shared__ int scn[256];
    __shared__ int cur[256];
    const int b = blockIdx.x;
    const int node0 = b << 8;
    const int t = threadIdx.x;
    hist[t] = 0;
    __syncthreads();
    const int cnt = btail[b];
    const uint2* src = binned + (size_t)b * BCAP;
    for (int s = t; s < cnt; s += 256)
        atomicAdd(&hist[src[s].y & 255], 1);
    __syncthreads();
    int h = hist[t];
    scn[t] = h;
    __syncthreads();
    for (int off = 1; off < 256; off <<= 1) {
        int add = (t >= off) ? scn[t - off] : 0;
        __syncthreads();
        scn[t] += add;
        __syncthreads();
    }
    int excl = bbase[b] + scn[t] - h;
    int n = node0 + t;
    if (n < N_NODES) starts[n] = excl;
    if (b == 0 && t == 0) starts[N_NODES] = N_EDGES;
    cur[t] = excl;
    __syncthreads();
    for (int s = t; s < cnt; s += 256) {
        uint2 p = src[s];
        int pp = atomicAdd(&cur[p.y & 255], 1);
        erec[pp] = p.x;
    }
}

// W2s[l][k][h] = sum_{m<3} rad_w2[l][k][h*3+m]; Wsp[l][k][h] = (self_w @ proj_top)[k][h]
__global__ void k_prep(const float* __restrict__ rad_w2, const float* __restrict__ self_w,
                       const float* __restrict__ proj_w,
                       float* __restrict__ W2s, float* __restrict__ Wsp) {
    int i = blockIdx.x * blockDim.x + threadIdx.x;          // L*H*H
    if (i >= NLAYER * HDIM * HDIM) return;
    int l = i / (HDIM * HDIM); int rem = i % (HDIM * HDIM);
    int k = rem / HDIM; int h = rem % HDIM;
    const float* w = rad_w2 + ((size_t)l * HDIM + k) * (HDIM * 3) + h * 3;
    W2s[i] = w[0] + w[1] + w[2];
    const float* sw = self_w + ((size_t)l * HDIM + k) * HDIM;
    const float* pw = proj_w + (size_t)l * 2 * HDIM * HDIM;
    float acc = 0.f;
    for (int m = 0; m < HDIM; ++m) acc += sw[m] * pw[m * HDIM + h];
    Wsp[i] = acc;
}

// bf16 transposed weights for MFMA B-operands: layout [n][k] contiguous in k
__global__ void k_wtr(const float* __restrict__ Wsp, const float* __restrict__ proj_w,
                      const float* __restrict__ mlp_w1, const float* __restrict__ mlp_w2,
                      unsigned short* __restrict__ WspT, unsigned short* __restrict__ PbT,
                      unsigned short* __restrict__ W1T, unsigned short* __restrict__ W2T) {
    int i = blockIdx.x * blockDim.x + threadIdx.x;          // L * 24576
    if (i >= NLAYER * 24576) return;
    int l = i / 24576, off = i % 24576;
    if (off < 4096) {
        int n = off >> 6, k = off & 63;
        WspT[(size_t)l * 4096 + off] = (unsigned short)f2bf(Wsp[(size_t)l * 4096 + k * 64 + n]);
    } else if (off < 8192) {
        int o = off - 4096; int n = o >> 6, k = o & 63;
        PbT[(size_t)l * 4096 + o] =
            (unsigned short)f2bf(proj_w[(size_t)l * 8192 + (64 + k) * 64 + n]);
    } else if (off < 16384) {
        int o = off - 8192; int n = o >> 6, k = o & 63;
        W1T[(size_t)l * 8192 + o] = (unsigned short)f2bf(mlp_w1[(size_t)l * 8192 + k * 128 + n]);
    } else {
        int o = off - 16384; int n = o >> 7, k = o & 127;
        W2T[(size_t)l * 8192 + o] = (unsigned short)f2bf(mlp_w2[(size_t)l * 8192 + k * 64 + n]);
    }
}

// bf16 transposed readout weights: Ro1T[64][64], Ro2T[32][64]
__global__ void k_rotr(const float* __restrict__ ro_w1, const float* __restrict__ ro_w2,
                       unsigned short* __restrict__ Ro1T, unsigned short* __restrict__ Ro2T) {
    int i = blockIdx.x * blockDim.x + threadIdx.x;          // 6144
    if (i >= 6144) return;
    if (i < 4096) {
        int n = i >> 6, k = i & 63;
        Ro1T[i] = (unsigned short)f2bf(ro_w1[k * 64 + n]);
    } else {
        int o = i - 4096; int n = o >> 6, k = o & 63;       // n in 0..31
        Ro2T[o] = (unsigned short)f2bf(ro_w2[k * 32 + n]);
    }
}

// b2s[l][h] = sum_m rad_b2[l][h*3+m];  bsp[l][h] = self_b@proj_top + proj_b
__global__ void k_bias(const float* __restrict__ rad_b2, const float* __restrict__ self_b,
                       const float* __restrict__ proj_w, const float* __restrict__ proj_b,
                       float* __restrict__ b2s, float* __restrict__ bsp) {
    int i = blockIdx.x * blockDim.x + threadIdx.x;          // L*H
    if (i >= NLAYER * HDIM) return;
    int l = i / HDIM, h = i % HDIM;
    const float* rb2 = rad_b2 + l * HDIM * 3 + h * 3;
    b2s[i] = rb2[0] + rb2[1] + rb2[2];
    float acc = proj_b[l * HDIM + h];
    const float* pw = proj_w + (size_t)l * 2 * HDIM * HDIM;
    const float* sb = self_b + l * HDIM;
    for (int m = 0; m < HDIM; ++m) acc += sb[m] * pw[m * HDIM + h];
    bsp[i] = acc;
}

// radial LUT
__global__ void k_lut(const float* __restrict__ widths, const float* __restrict__ rad_w1,
                      const float* __restrict__ rad_b1, const float* __restrict__ W2s,
                      const float* __restrict__ b2s, float* __restrict__ lut) {
    int bid = blockIdx.x;                 // l*TLUT + t
    int l = bid / TLUT, t = bid % TLUT;
    int h = threadIdx.x;                  // 64 threads
    __shared__ float h1s[HDIM];
    float len = (float)t * (CUT_R / (float)(TLUT - 1));
    float cut = 0.0f;
    if (len < CUT_R) cut = 0.5f * (cosf(len * (PI_F / CUT_R)) + 1.0f);
    float acc = rad_b1[l * HDIM + h];
    for (int b = 0; b < NBASIS; ++b) {
        float wb = fmaxf(widths[b], 0.1f);
        float center = (float)b * (CUT_R / (float)(NBASIS - 1));
        float d = (len - center) / wb;
        float rbf = __expf(-0.5f * d * d) * cut;
        acc += rbf * rad_w1[(l * NBASIS + b) * HDIM + h];
    }
    h1s[h] = siluf(acc);
    __syncthreads();
    float o = b2s[l * HDIM + h];
    const float* w2 = W2s + (size_t)l * HDIM * HDIM;
    for (int k = 0; k < HDIM; ++k) o += h1s[k] * w2[k * HDIM + h];
    lut[(size_t)bid * HDIM + h] = o;
}

// lutQb[(l*TLUT+t)*16+j] = uint4; comp c packs bf16(lut[t][4j+c]) | bf16(lut[t+1][4j+c])<<16
__global__ void k_lutq(const float* __restrict__ lut, uint4* __restrict__ lutQb) {
    int i = blockIdx.x * blockDim.x + threadIdx.x;          // L*TLUT*16
    if (i >= NLAYER * TLUT * 16) return;
    int j = i & 15;
    int lt = i >> 4;
    int l = lt / TLUT, t = lt % TLUT;
    int t1 = (t < TLUT - 1) ? t + 1 : t;
    const float* r0 = lut + (size_t)(l * TLUT + t)  * HDIM + 4 * j;
    const float* r1 = lut + (size_t)(l * TLUT + t1) * HDIM + 4 * j;
    uint4 o;
    o.x = f2bf(r0[0]) | (f2bf(r1[0]) << 16);
    o.y = f2bf(r0[1]) | (f2bf(r1[1]) << 16);
    o.z = f2bf(r0[2]) | (f2bf(r1[2]) << 16);
    o.w = f2bf(r0[3]) | (f2bf(r1[3]) << 16);
    lutQb[i] = o;
}

// ---------------- per-layer kernels ----------------

// one wave per node, 8 edge slots x 8 lanes (8 channels each via uint4 loads).
__global__ __launch_bounds__(256) void k_agg(const uint4* __restrict__ featsbf4,
                                             const uint4* __restrict__ lutQb_l,
                                             const int* __restrict__ starts,
                                             const unsigned int* __restrict__ erec,
                                             uint4* __restrict__ aggbf4) {
    int wid  = (blockIdx.x * blockDim.x + threadIdx.x) >> 6;
    int lane = threadIdx.x & 63;
    int slot = lane >> 3;     // 0..7
    int j    = lane & 7;      // channel octet
    if (wid >= N_NODES) return;
    int e0 = starts[wid], e1 = starts[wid + 1];
    float a0 = 0, a1 = 0, a2 = 0, a3 = 0, a4 = 0, a5 = 0, a6 = 0, a7 = 0;
    #pragma unroll 2
    for (int e = e0 + slot; e < e1; e += 8) {
        unsigned int rec = erec[e];
        int c    = rec >> 16;
        int tfix = rec & 0xffff;
        int i0   = tfix >> 7;
        float f  = (float)(tfix & 127) * (1.0f / 128.0f);
        uint4 q0 = lutQb_l[i0 * 16 + 2 * j];
        uint4 q1 = lutQb_l[i0 * 16 + 2 * j + 1];
        uint4 fb = featsbf4[(size_t)c * 8 + j];
        a0 += bf_lo(fb.x) * lrp(q0.x, f);
        a1 += bf_hi(fb.x) * lrp(q0.y, f);
        a2 += bf_lo(fb.y) * lrp(q0.z, f);
        a3 += bf_hi(fb.y) * lrp(q0.w, f);
        a4 += bf_lo(fb.z) * lrp(q1.x, f);
        a5 += bf_hi(fb.z) * lrp(q1.y, f);
        a6 += bf_lo(fb.w) * lrp(q1.z, f);
        a7 += bf_hi(fb.w) * lrp(q1.w, f);
    }
    #pragma unroll
    for (int off = 8; off < 64; off <<= 1) {
        a0 += __shfl_xor(a0, off, 64);  a1 += __shfl_xor(a1, off, 64);
        a2 += __shfl_xor(a2, off, 64);  a3 += __shfl_xor(a3, off, 64);
        a4 += __shfl_xor(a4, off, 64);  a5 += __shfl_xor(a5, off, 64);
        a6 += __shfl_xor(a6, off, 64);  a7 += __shfl_xor(a7, off, 64);
    }
    if (slot == 0) {
        uint4 o;
        o.x = f2bf(a0) | (f2bf(a1) << 16);
        o.y = f2bf(a2) | (f2bf(a3) << 16);
        o.z = f2bf(a4) | (f2bf(a5) << 16);
        o.w = f2bf(a6) | (f2bf(a7) << 16);
        aggbf4[(size_t)wid * 8 + j] = o;
    }
}

// k_node v3 (MFMA): 64 nodes/block, 4 waves; wave w owns node rows [16w,16w+16).
constexpr int BP = 72;                     // bf16 LDS row pitch
__global__ __launch_bounds__(256) void k_node(float* __restrict__ feats,
        unsigned short* __restrict__ featsbf,
        const unsigned short* __restrict__ aggbf,
        const unsigned short* __restrict__ WspT_l, const unsigned short* __restrict__ PbT_l,
        const unsigned short* __restrict__ W1T_l, const unsigned short* __restrict__ W2T_l,
        const float* __restrict__ bsp_l,
        const float* __restrict__ mlp_b1_l, const float* __restrict__ mlp_b2_l,
        const float* __restrict__ ln_g_l, const float* __restrict__ ln_b_l) {
    __shared__ unsigned short P[64 * BP];   // x -> conv
    __shared__ unsigned short Q[64 * BP];   // a -> m1_lo
    __shared__ unsigned short S[64 * BP];   // m1_hi
    const int tid  = threadIdx.x;
    const int lane = tid & 63;
    const int wib  = tid >> 6;
    const int mt   = __builtin_amdgcn_readfirstlane(wib);
    const int nb0  = blockIdx.x * 64;
    const int colL = lane & 15;
    const int kgrp = lane >> 4;

    #pragma unroll 4
    for (int i = 0; i < 16; ++i) {
        int r  = wib + i * 4;
        int nd = nb0 + r; nd = (nd < N_NODES) ? nd : (N_NODES - 1);
        P[r * BP + lane] = featsbf[(size_t)nd * 64 + lane];
        Q[r * BP + lane] = aggbf[(size_t)nd * 64 + lane];
    }
    __syncthreads();

    // ---- conv = x@Wsp + a@Pb + bsp ----
    f32x4 acc[4];
    #pragma unroll
    for (int nt = 0; nt < 4; ++nt) {
        float b = bsp_l[nt * 16 + colL];
        acc[nt][0] = b; acc[nt][1] = b; acc[nt][2] = b; acc[nt][3] = b;
    }
    #pragma unroll
    for (int kb = 0; kb < 2; ++kb) {
        short8 ax = *(const short8*)&P[(mt * 16 + colL) * BP + kb * 32 + kgrp * 8];
        short8 aa = *(const short8*)&Q[(mt * 16 + colL) * BP + kb * 32 + kgrp * 8];
        #pragma unroll
        for (int nt = 0; nt < 4; ++nt) {
            short8 bw = *(const short8*)&WspT_l[(nt * 16 + colL) * 64 + kb * 32 + kgrp * 8];
            acc[nt] = MFMA16(ax, bw, acc[nt], 0, 0, 0);
            short8 bp = *(const short8*)&PbT_l[(nt * 16 + colL) * 64 + kb * 32 + kgrp * 8];
            acc[nt] = MFMA16(aa, bp, acc[nt], 0, 0, 0);
        }
    }
    __syncthreads();
    #pragma unroll
    for (int nt = 0; nt < 4; ++nt)
        #pragma unroll
        for (int j = 0; j < 4; ++j)
            P[(mt * 16 + kgrp * 4 + j) * BP + nt * 16 + colL] = (unsigned short)f2bf(acc[nt][j]);
    __syncthreads();

    // ---- m1 = silu(conv@W1 + b1), 128 wide ----
    {
        f32x4 m[8];
        #pragma unroll
        for (int nt = 0; nt < 8; ++nt) {
            float b = mlp_b1_l[nt * 16 + colL];
            m[nt][0] = b; m[nt][1] = b; m[nt][2] = b; m[nt][3] = b;
        }
        #pragma unroll
        for (int kb = 0; kb < 2; ++kb) {
            short8 ac = *(const short8*)&P[(mt * 16 + colL) * BP + kb * 32 + kgrp * 8];
            #pragma unroll
            for (int nt = 0; nt < 8; ++nt) {
                short8 bw = *(const short8*)&W1T_l[(nt * 16 + colL) * 64 + kb * 32 + kgrp * 8];
                m[nt] = MFMA16(ac, bw, m[nt], 0, 0, 0);
            }
        }
        __syncthreads();
        #pragma unroll
        for (int nt = 0; nt < 4; ++nt)
            #pragma unroll
            for (int j = 0; j < 4; ++j)
                Q[(mt * 16 + kgrp * 4 + j) * BP + nt * 16 + colL] =
                    (unsigned short)f2bf(siluf(m[nt][j]));
        #pragma unroll
        for (int nt = 4; nt < 8; ++nt)
            #pragma unroll
            for (int j = 0; j < 4; ++j)
                S[(mt * 16 + kgrp * 4 + j) * BP + (nt - 4) * 16 + colL] =
                    (unsigned short)f2bf(siluf(m[nt][j]));
    }
    __syncthreads();

    // ---- upd = m1@W2 + b2 ----
    f32x4 u[4];
    #pragma unroll
    for (int nt = 0; nt < 4; ++nt) {
        float b = mlp_b2_l[nt * 16 + colL];
        u[nt][0] = b; u[nt][1] = b; u[nt][2] = b; u[nt][3] = b;
    }
    #pragma unroll
    for (int kb = 0; kb < 4; ++kb) {
        short8 am = (kb < 2)
            ? *(const short8*)&Q[(mt * 16 + colL) * BP + kb * 32 + kgrp * 8]
            : *(const short8*)&S[(mt * 16 + colL) * BP + (kb - 2) * 32 + kgrp * 8];
        #pragma unroll
        for (int nt = 0; nt < 4; ++nt) {
            short8 bw = *(const short8*)&W2T_l[(nt * 16 + colL) * 128 + kb * 32 + kgrp * 8];
            u[nt] = MFMA16(am, bw, u[nt], 0, 0, 0);
        }
    }

    // ---- residual + LayerNorm ----
    float y[4][4];
    float s1[4] = {0, 0, 0, 0}, s2[4] = {0, 0, 0, 0};
    #pragma unroll
    for (int j = 0; j < 4; ++j) {
        int node = nb0 + mt * 16 + kgrp * 4 + j;
        int nds  = (node < N_NODES) ? node : (N_NODES - 1);
        #pragma unroll
        for (int nt = 0; nt < 4; ++nt) {
            float v = feats[(size_t)nds * 64 + nt * 16 + colL] + u[nt][j];
            y[nt][j] = v;
            s1[j] += v; s2[j] += v * v;
        }
    }
    #pragma unroll
    for (int off = 1; off < 16; off <<= 1) {
        #pragma unroll
        for (int j = 0; j < 4; ++j) {
            s1[j] += __shfl_xor(s1[j], off, 64);
            s2[j] += __shfl_xor(s2[j], off, 64);
        }
    }
    float gv[4], bv[4];
    #pragma unroll
    for (int nt = 0; nt < 4; ++nt) {
        gv[nt] = ln_g_l[nt * 16 + colL];
        bv[nt] = ln_b_l[nt * 16 + colL];
    }
    #pragma unroll
    for (int j = 0; j < 4; ++j) {
        int node = nb0 + mt * 16 + kgrp * 4 + j;
        if (node >= N_NODES) continue;
        float mu  = s1[j] * (1.0f / 64.0f);
        float var = s2[j] * (1.0f / 64.0f) - mu * mu;
        float rr  = rsqrtf(var + 1e-5f);
        #pragma unroll
        for (int nt = 0; nt < 4; ++nt) {
            float o = (y[nt][j] - mu) * rr * gv[nt] + bv[nt];
            feats[(size_t)node * 64 + nt * 16 + colL]   = o;
            featsbf[(size_t)node * 64 + nt * 16 + colL] = (unsigned short)f2bf(o);
        }
    }
}

// ---------------- readout (MFMA, k_node template) ----------------

__global__ __launch_bounds__(256) void k_readout(const unsigned short* __restrict__ featsbf,
        const int* __restrict__ an,
        const unsigned short* __restrict__ Ro1T, const unsigned short* __restrict__ Ro2T,
        const float* __restrict__ ro_b1, const float* __restrict__ ro_b2,
        const float* __restrict__ ro_w3, const float* __restrict__ ro_b3,
        const float* __restrict__ atomic_e, float* __restrict__ blockpart) {
    __shared__ unsigned short P[64 * BP];   // feats
    __shared__ unsigned short Q[64 * BP];   // h1
    __shared__ float sred[256];
    const int tid  = threadIdx.x;
    const int lane = tid & 63;
    const int wib  = tid >> 6;
    const int mt   = __builtin_amdgcn_readfirstlane(wib);
    const int nb0  = blockIdx.x * 64;
    const int colL = lane & 15;
    const int kgrp = lane >> 4;

    #pragma unroll 4
    for (int i = 0; i < 16; ++i) {
        int r  = wib + i * 4;
        int nd = nb0 + r; nd = (nd < N_NODES) ? nd : (N_NODES - 1);
        P[r * BP + lane] = featsbf[(size_t)nd * 64 + lane];
    }
    __syncthreads();

    // ---- h1 = silu(x @ Ro1 + b1) ----
    {
        f32x4 m[4];
        #pragma unroll
        for (int nt = 0; nt < 4; ++nt) {
            float b = ro_b1[nt * 16 + colL];
            m[nt][0] = b; m[nt][1] = b; m[nt][2] = b; m[nt][3] = b;
        }
        #pragma unroll
        for (int kb = 0; kb < 2; ++kb) {
            short8 ax = *(const short8*)&P[(mt * 16 + colL) * BP + kb * 32 + kgrp * 8];
            #pragma unroll
            for (int nt = 0; nt < 4; ++nt) {
                short8 bw = *(const short8*)&Ro1T[(nt * 16 + colL) * 64 + kb * 32 + kgrp * 8];
                m[nt] = MFMA16(ax, bw, m[nt], 0, 0, 0);
            }
        }
        __syncthreads();
        #pragma unroll
        for (int nt = 0; nt < 4; ++nt)
            #pragma unroll
            for (int j = 0; j < 4; ++j)
                Q[(mt * 16 + kgrp * 4 + j) * BP + nt * 16 + colL] =
                    (unsigned short)f2bf(siluf(m[nt][j]));
    }
    __syncthreads();

    // ---- h2 = silu(h1 @ Ro2 + b2), 32 wide; e = h2 @ ro_w3 ----
    f32x4 u[2];
    #pragma unroll
    for (int nt = 0; nt < 2; ++nt) {
        float b = ro_b2[nt * 16 + colL];
        u[nt][0] = b; u[nt][1] = b; u[nt][2] = b; u[nt][3] = b;
    }
    #pragma unroll
    for (int kb = 0; kb < 2; ++kb) {
        short8 am = *(const short8*)&Q[(mt * 16 + colL) * BP + kb * 32 + kgrp * 8];
        #pragma unroll
        for (int nt = 0; nt < 2; ++nt) {
            short8 bw = *(const short8*)&Ro2T[(nt * 16 + colL) * 64 + kb * 32 + kgrp * 8];
            u[nt] = MFMA16(am, bw, u[nt], 0, 0, 0);
        }
    }
    float w3[2];
    #pragma unroll
    for (int nt = 0; nt < 2; ++nt) w3[nt] = ro_w3[nt * 16 + colL];
    float part = 0.0f;
    #pragma unroll
    for (int j = 0; j < 4; ++j) {
        float c = siluf(u[0][j]) * w3[0] + siluf(u[1][j]) * w3[1];
        // reduce over the 16 channels (colL) within each 16-lane group
        #pragma unroll
        for (int off = 1; off < 16; off <<= 1) c += __shfl_xor(c, off, 64);
        int node = nb0 + mt * 16 + kgrp * 4 + j;
        if (colL == 0 && node < N_NODES)
            part += c + ro_b3[0] + atomic_e[an[node]];
    }
    sred[tid] = part;
    __syncthreads();
    for (int off = 128; off > 0; off >>= 1) {
        if (tid < off) sred[tid] += sred[tid + off];
        __syncthreads();
    }
    if (tid == 0) blockpart[blockIdx.x] = sred[0];
}

__global__ void k_final(const float* __restrict__ blockpart, int nb, float* __restrict__ out) {
    __shared__ float s[256];
    float acc = 0.f;
    for (int i = threadIdx.x; i < nb; i += 256) acc += blockpart[i];
    s[threadIdx.x] = acc; __syncthreads();
    for (int off = 128; off > 0; off >>= 1) {
        if (threadIdx.x < off) s[threadIdx.x] += s[threadIdx.x + off];
        __syncthreads();
    }
    if (threadIdx.x == 0) out[0] = s[0];
}

// ---------------- launch ----------------

extern "C" void kernel_launch(void* const* d_in, const int* in_sizes, int n_in,
                              void* d_out, int out_size, void* d_ws, size_t ws_size,
                              hipStream_t stream) {
    const int*   an       = (const int*)  d_in[0];
    const float* pos      = (const float*)d_in[1];
    const int*   edge     = (const int*)  d_in[2];
    const float* widths   = (const float*)d_in[3];
    const float* embed    = (const float*)d_in[4];
    const float* rad_w1   = (const float*)d_in[5];
    const float* rad_b1   = (const float*)d_in[6];
    const float* rad_w2   = (const float*)d_in[7];
    const float* rad_b2   = (const float*)d_in[8];
    const float* self_w   = (const float*)d_in[9];
    const float* self_b   = (const float*)d_in[10];
    const float* proj_w   = (const float*)d_in[11];
    const float* proj_b   = (const float*)d_in[12];
    const float* mlp_w1   = (const float*)d_in[13];
    const float* mlp_b1   = (const float*)d_in[14];
    const float* mlp_w2   = (const float*)d_in[15];
    const float* mlp_b2   = (const float*)d_in[16];
    const float* ln_g     = (const float*)d_in[17];
    const float* ln_b     = (const float*)d_in[18];
    const float* ro_w1    = (const float*)d_in[19];
    const float* ro_b1    = (const float*)d_in[20];
    const float* ro_w2    = (const float*)d_in[21];
    const float* ro_b2    = (const float*)d_in[22];
    const float* ro_w3    = (const float*)d_in[23];
    const float* ro_b3    = (const float*)d_in[24];
    const float* atomic_e = (const float*)d_in[25];

    char* w = (char*)d_ws;
    auto alloc = [&](size_t bytes) { char* p = w; w += (bytes + 255) & ~(size_t)255; return p; };
    float* feats     = (float*)alloc(sizeof(float) * N_NODES * HDIM);
    unsigned short* featsbf = (unsigned short*)alloc(sizeof(unsigned short) * N_NODES * HDIM);
    unsigned short* aggbf   = (unsigned short*)alloc(sizeof(unsigned short) * N_NODES * HDIM);
    float* lut       = (float*)alloc(sizeof(float) * NLAYER * TLUT * HDIM);
    uint4* lutQb     = (uint4*)alloc(sizeof(uint4) * NLAYER * TLUT * 16);
    float* W2s       = (float*)alloc(sizeof(float) * NLAYER * HDIM * HDIM);
    float* b2s       = (float*)alloc(sizeof(float) * NLAYER * HDIM);
    float* Wsp       = (float*)alloc(sizeof(float) * NLAYER * HDIM * HDIM);
    float* bsp       = (float*)alloc(sizeof(float) * NLAYER * HDIM);
    unsigned short* WspT = (unsigned short*)alloc(sizeof(unsigned short) * NLAYER * 4096);
    unsigned short* PbT  = (unsigned short*)alloc(sizeof(unsigned short) * NLAYER * 4096);
    unsigned short* W1T  = (unsigned short*)alloc(sizeof(unsigned short) * NLAYER * 8192);
    unsigned short* W2T  = (unsigned short*)alloc(sizeof(unsigned short) * NLAYER * 8192);
    unsigned short* Ro1T = (unsigned short*)alloc(sizeof(unsigned short) * 4096);
    unsigned short* Ro2T = (unsigned short*)alloc(sizeof(unsigned short) * 2048);
    unsigned int* erec = (unsigned int*)alloc(sizeof(unsigned int) * N_EDGES);
    uint2* binned    = (uint2*)alloc(sizeof(uint2) * (size_t)NBKT * BCAP);
    int*   btail     = (int*)  alloc(sizeof(int) * 256);
    int*   bbase     = (int*)  alloc(sizeof(int) * 256);
    int*   starts    = (int*)  alloc(sizeof(int) * (N_NODES + 1));
    float* blockpart = (float*)alloc(sizeof(float) * 1024);
    (void)ws_size; (void)in_sizes; (void)n_in; (void)out_size;

    const int* erow = edge;
    const int* ecol = edge + N_EDGES;

    hipMemsetAsync(btail, 0, sizeof(int) * 256, stream);
    k_embed<<<12500, 256, 0, stream>>>(an, embed, feats, featsbf);
    k_binA<<<(N_EDGES + TILE - 1) / TILE, 256, 0, stream>>>(erow, ecol, pos, btail, binned);
    k_scanB<<<1, 256, 0, stream>>>(btail, bbase);
    k_binB<<<NBKT, 256, 0, stream>>>(binned, btail, bbase, starts, erec);
    k_prep<<<80, 256, 0, stream>>>(rad_w2, self_w, proj_w, W2s, Wsp);
    k_wtr<<<(NLAYER * 24576 + 255) / 256, 256, 0, stream>>>(Wsp, proj_w, mlp_w1, mlp_w2,
                                                            WspT, PbT, W1T, W2T);
    k_rotr<<<24, 256, 0, stream>>>(ro_w1, ro_w2, Ro1T, Ro2T);
    k_bias<<<5, 64, 0, stream>>>(rad_b2, self_b, proj_w, proj_b, b2s, bsp);
    k_lut<<<NLAYER * TLUT, 64, 0, stream>>>(widths, rad_w1, rad_b1, W2s, b2s, lut);
    k_lutq<<<(NLAYER * TLUT * 16 + 255) / 256, 256, 0, stream>>>(lut, lutQb);

    for (int l = 0; l < NLAYER; ++l) {
        k_agg<<<12500, 256, 0, stream>>>((const uint4*)featsbf,
                                         lutQb + (size_t)l * TLUT * 16,
                                         starts, erec, (uint4*)aggbf);
        k_node<<<782, 256, 0, stream>>>(feats, featsbf, aggbf,
            WspT + (size_t)l * 4096, PbT + (size_t)l * 4096,
            W1T + (size_t)l * 8192, W2T + (size_t)l * 8192,
            bsp + l * HDIM, mlp_b1 + l * 2 * HDIM, mlp_b2 + l * HDIM,
            ln_g + l * HDIM, ln_b + l * HDIM);
    }

    k_readout<<<782, 256, 0, stream>>>(featsbf, an, Ro1T, Ro2T, ro_b1, ro_b2,
                                       ro_w3, ro_b3, atomic_e, blockpart);
    k_final<<<1, 256, 0, stream>>>(blockpart, 782, (float*)d_out);
}

// Round 16
// 413.588 us; speedup vs baseline: 6.8599x; 1.0721x over previous
//
#include <hip/hip_runtime.h>
#include <math.h>

// Problem constants (from reference)
constexpr int N_NODES = 50000;
constexpr int N_EDGES = 1600000;
constexpr int HDIM    = 64;
constexpr int NLAYER  = 5;
constexpr int NBASIS  = 8;
constexpr int TLUT    = 512;           // radial LUT entries per layer
constexpr float CUT_R = 5.0f;
constexpr float PI_F  = 3.14159265358979f;

// binned scatter: buckets of 256 nodes (r >> 8)
constexpr int NBKT = 196;
constexpr int BCAP = 9216;             // mean 8192 + ~11 sigma
constexpr int TILE = 1024;             // smaller tile -> 23KB LDS -> 6 blocks/CU

typedef __attribute__((ext_vector_type(8))) short short8;   // 8 bf16 (4 VGPRs)
typedef __attribute__((ext_vector_type(4))) float f32x4;    // MFMA acc
#define MFMA16 __builtin_amdgcn_mfma_f32_16x16x32_bf16

__device__ __forceinline__ float waveRedSum(float v) {
    for (int off = 32; off > 0; off >>= 1) v += __shfl_xor(v, off, 64);
    return v;
}
__device__ __forceinline__ float siluf(float x) { return x / (1.0f + __expf(-x)); }

// round-to-nearest-even f32 -> bf16 bits
__device__ __forceinline__ unsigned int f2bf(float x) {
    unsigned int b = __float_as_uint(x);
    return (b + 0x7fffu + ((b >> 16) & 1u)) >> 16;
}
__device__ __forceinline__ float bf_lo(unsigned int u) { return __uint_as_float(u << 16); }
__device__ __forceinline__ float bf_hi(unsigned int u) { return __uint_as_float(u & 0xffff0000u); }

// ---------------- setup kernels ----------------

__global__ void k_embed(const int* __restrict__ an, const float* __restrict__ embed,
                        float* __restrict__ feats, unsigned short* __restrict__ featsbf) {
    int i = blockIdx.x * blockDim.x + threadIdx.x;           // N*H threads
    if (i >= N_NODES * HDIM) return;
    int node = i >> 6, h = i & 63;
    float v = embed[an[node] * HDIM + h];
    feats[i] = v;
    featsbf[i] = (unsigned short)f2bf(v);
}

// pass A: block-sort TILE-edge tiles by node bucket (r>>8), append runs to binned[]
// rec packs (col<<16) | nearest-LUT-index
__global__ __launch_bounds__(256) void k_binA(const int* __restrict__ row,
                                              const int* __restrict__ col,
                                              const float* __restrict__ pos,
                                              int* __restrict__ btail,
                                              uint2* __restrict__ binned) {
    __shared__ uint2 ent[TILE];          // 8 KB: payload {rec, row}
    __shared__ short bb[TILE];           // 2 KB: bucket id
    __shared__ uint2 sorted[TILE];       // 8 KB
    __shared__ int cnt[256], cnt2[256], base[256], gbase[256], scn[256];
    const int tid = threadIdx.x;
    const int t0  = blockIdx.x * TILE;
    const int nv  = min(TILE, N_EDGES - t0);

    cnt[tid] = 0;
    __syncthreads();

    #pragma unroll
    for (int i = 0; i < TILE / 256; ++i) {
        int idx = i * 256 + tid;
        if (idx < nv) {
            int e = t0 + idx;
            int r = row[e], c = col[e];
            float dx = pos[c * 3 + 0] - pos[r * 3 + 0];
            float dy = pos[c * 3 + 1] - pos[r * 3 + 1];
            float dz = pos[c * 3 + 2] - pos[r * 3 + 2];
            float len = sqrtf(dx * dx + dy * dy + dz * dz);
            float t = len * ((float)(TLUT - 1) / CUT_R);
            t = fminf(t, (float)(TLUT - 1));
            unsigned int nn = (unsigned int)(t + 0.5f);     // nearest index
            if (nn > TLUT - 1) nn = TLUT - 1;
            uint2 p;
            p.x = ((unsigned int)c << 16) | nn;
            p.y = (unsigned int)r;
            ent[idx] = p;
            int b = r >> 8;
            bb[idx] = (short)b;
            atomicAdd(&cnt[b], 1);
        }
    }
    __syncthreads();
    int cv = cnt[tid];
    scn[tid] = cv;
    __syncthreads();
    for (int off = 1; off < 256; off <<= 1) {
        int add = (tid >= off) ? scn[tid - off] : 0;
        __syncthreads();
        scn[tid] += add;
        __syncthreads();
    }
    base[tid] = scn[tid] - cv;
    if (tid < NBKT && cv > 0) gbase[tid] = atomicAdd(&btail[tid], cv);
    cnt2[tid] = base[tid];
    __syncthreads();
    #pragma unroll
    for (int i = 0; i < TILE / 256; ++i) {
        int idx = i * 256 + tid;
        if (idx < nv) {
            int b = bb[idx];
            int p = atomicAdd(&cnt2[b], 1);
            sorted[p] = ent[idx];
        }
    }
    __syncthreads();
    for (int s = tid; s < nv; s += 256) {
        uint2 p = sorted[s];
        int b = (int)(p.y >> 8);
        binned[(size_t)b * BCAP + gbase[b] + (s - base[b])] = p;
    }
}

// exclusive scan of 196 bucket totals (1 block, 256 threads)
__global__ void k_scanB(const int* __restrict__ btail, int* __restrict__ bbase) {
    __shared__ int s[256];
    int t = threadIdx.x;
    int v = (t < NBKT) ? btail[t] : 0;
    s[t] = v; __syncthreads();
    for (int off = 1; off < 256; off <<= 1) {
        int add = (t >= off) ? s[t - off] : 0;
        __syncthreads();
        s[t] += add;
        __syncthreads();
    }
    if (t < NBKT) bbase[t] = s[t] - v;
}

// pass B: one block per 256-node bucket. LDS histogram -> scan -> starts ->
// scatter erec via LDS cursors. No global atomics.
__global__ __launch_bounds__(256) void k_binB(const uint2* __restrict__ binned,
                                              const int* __restrict__ btail,
                                              const int* __restrict__ bbase,
                                              int* __restrict__ starts,
                                              unsigned int* __restrict__ erec) {
    __shared__ int hist[256];
    __shared__ int scn[256];
    __shared__ int cur[256];
    const int b = blockIdx.x;
    const int node0 = b << 8;
    const int t = threadIdx.x;
    hist[t] = 0;
    __syncthreads();
    const int cnt = btail[b];
    const uint2* src = binned + (size_t)b * BCAP;
    for (int s = t; s < cnt; s += 256)
        atomicAdd(&hist[src[s].y & 255], 1);
    __syncthreads();
    int h = hist[t];
    scn[t] = h;
    __syncthreads();
    for (int off = 1; off < 256; off <<= 1) {
        int add = (t >= off) ? scn[t - off] : 0;
        __syncthreads();
        scn[t] += add;
        __syncthreads();
    }
    int excl = bbase[b] + scn[t] - h;
    int n = node0 + t;
    if (n < N_NODES) starts[n] = excl;
    if (b == 0 && t == 0) starts[N_NODES] = N_EDGES;
    cur[t] = excl;
    __syncthreads();
    for (int s = t; s < cnt; s += 256) {
        uint2 p = src[s];
        int pp = atomicAdd(&cur[p.y & 255], 1);
        erec[pp] = p.x;
    }
}

// W2s[l][k][h] = sum_{m<3} rad_w2[l][k][h*3+m]; Wsp[l][k][h] = (self_w @ proj_top)[k][h]
__global__ void k_prep(const float* __restrict__ rad_w2, const float* __restrict__ self_w,
                       const float* __restrict__ proj_w,
                       float* __restrict__ W2s, float* __restrict__ Wsp) {
    int i = blockIdx.x * blockDim.x + threadIdx.x;          // L*H*H
    if (i >= NLAYER * HDIM * HDIM) return;
    int l = i / (HDIM * HDIM); int rem = i % (HDIM * HDIM);
    int k = rem / HDIM; int h = rem % HDIM;
    const float* w = rad_w2 + ((size_t)l * HDIM + k) * (HDIM * 3) + h * 3;
    W2s[i] = w[0] + w[1] + w[2];
    const float* sw = self_w + ((size_t)l * HDIM + k) * HDIM;
    const float* pw = proj_w + (size_t)l * 2 * HDIM * HDIM;
    float acc = 0.f;
    for (int m = 0; m < HDIM; ++m) acc += sw[m] * pw[m * HDIM + h];
    Wsp[i] = acc;
}

// bf16 transposed weights for MFMA B-operands: layout [n][k] contiguous in k
__global__ void k_wtr(const float* __restrict__ Wsp, const float* __restrict__ proj_w,
                      const float* __restrict__ mlp_w1, const float* __restrict__ mlp_w2,
                      unsigned short* __restrict__ WspT, unsigned short* __restrict__ PbT,
                      unsigned short* __restrict__ W1T, unsigned short* __restrict__ W2T) {
    int i = blockIdx.x * blockDim.x + threadIdx.x;          // L * 24576
    if (i >= NLAYER * 24576) return;
    int l = i / 24576, off = i % 24576;
    if (off < 4096) {
        int n = off >> 6, k = off & 63;
        WspT[(size_t)l * 4096 + off] = (unsigned short)f2bf(Wsp[(size_t)l * 4096 + k * 64 + n]);
    } else if (off < 8192) {
        int o = off - 4096; int n = o >> 6, k = o & 63;
        PbT[(size_t)l * 4096 + o] =
            (unsigned short)f2bf(proj_w[(size_t)l * 8192 + (64 + k) * 64 + n]);
    } else if (off < 16384) {
        int o = off - 8192; int n = o >> 6, k = o & 63;
        W1T[(size_t)l * 8192 + o] = (unsigned short)f2bf(mlp_w1[(size_t)l * 8192 + k * 128 + n]);
    } else {
        int o = off - 16384; int n = o >> 7, k = o & 127;
        W2T[(size_t)l * 8192 + o] = (unsigned short)f2bf(mlp_w2[(size_t)l * 8192 + k * 64 + n]);
    }
}

// bf16 transposed readout weights: Ro1T[64][64], Ro2T[32][64]
__global__ void k_rotr(const float* __restrict__ ro_w1, const float* __restrict__ ro_w2,
                       unsigned short* __restrict__ Ro1T, unsigned short* __restrict__ Ro2T) {
    int i = blockIdx.x * blockDim.x + threadIdx.x;          // 6144
    if (i >= 6144) return;
    if (i < 4096) {
        int n = i >> 6, k = i & 63;
        Ro1T[i] = (unsigned short)f2bf(ro_w1[k * 64 + n]);
    } else {
        int o = i - 4096; int n = o >> 6, k = o & 63;       // n in 0..31
        Ro2T[o] = (unsigned short)f2bf(ro_w2[k * 32 + n]);
    }
}

// b2s[l][h] = sum_m rad_b2[l][h*3+m];  bsp[l][h] = self_b@proj_top + proj_b
__global__ void k_bias(const float* __restrict__ rad_b2, const float* __restrict__ self_b,
                       const float* __restrict__ proj_w, const float* __restrict__ proj_b,
                       float* __restrict__ b2s, float* __restrict__ bsp) {
    int i = blockIdx.x * blockDim.x + threadIdx.x;          // L*H
    if (i >= NLAYER * HDIM) return;
    int l = i / HDIM, h = i % HDIM;
    const float* rb2 = rad_b2 + l * HDIM * 3 + h * 3;
    b2s[i] = rb2[0] + rb2[1] + rb2[2];
    float acc = proj_b[l * HDIM + h];
    const float* pw = proj_w + (size_t)l * 2 * HDIM * HDIM;
    const float* sb = self_b + l * HDIM;
    for (int m = 0; m < HDIM; ++m) acc += sb[m] * pw[m * HDIM + h];
    bsp[i] = acc;
}

// radial LUT
__global__ void k_lut(const float* __restrict__ widths, const float* __restrict__ rad_w1,
                      const float* __restrict__ rad_b1, const float* __restrict__ W2s,
                      const float* __restrict__ b2s, float* __restrict__ lut) {
    int bid = blockIdx.x;                 // l*TLUT + t
    int l = bid / TLUT, t = bid % TLUT;
    int h = threadIdx.x;                  // 64 threads
    __shared__ float h1s[HDIM];
    float len = (float)t * (CUT_R / (float)(TLUT - 1));
    float cut = 0.0f;
    if (len < CUT_R) cut = 0.5f * (cosf(len * (PI_F / CUT_R)) + 1.0f);
    float acc = rad_b1[l * HDIM + h];
    for (int b = 0; b < NBASIS; ++b) {
        float wb = fmaxf(widths[b], 0.1f);
        float center = (float)b * (CUT_R / (float)(NBASIS - 1));
        float d = (len - center) / wb;
        float rbf = __expf(-0.5f * d * d) * cut;
        acc += rbf * rad_w1[(l * NBASIS + b) * HDIM + h];
    }
    h1s[h] = siluf(acc);
    __syncthreads();
    float o = b2s[l * HDIM + h];
    const float* w2 = W2s + (size_t)l * HDIM * HDIM;
    for (int k = 0; k < HDIM; ++k) o += h1s[k] * w2[k * HDIM + h];
    lut[(size_t)bid * HDIM + h] = o;
}

// bf16 LUT rows for nearest-neighbor lookup: lutB[l][t][64]
__global__ void k_lutb(const float* __restrict__ lut, unsigned short* __restrict__ lutB) {
    int i = blockIdx.x * blockDim.x + threadIdx.x;          // L*TLUT*64
    if (i >= NLAYER * TLUT * HDIM) return;
    lutB[i] = (unsigned short)f2bf(lut[i]);
}

// ---------------- per-layer kernels ----------------

// one wave per node, 8 edge slots x 8 lanes (8 channels each via uint4 loads).
// Nearest-neighbor LUT: one bf16 row read per edge (2 lines vs 4 for interp).
__global__ __launch_bounds__(256) void k_agg(const uint4* __restrict__ featsbf4,
                                             const uint4* __restrict__ lutB4_l,
                                             const int* __restrict__ starts,
                                             const unsigned int* __restrict__ erec,
                                             uint4* __restrict__ aggbf4) {
    int wid  = (blockIdx.x * blockDim.x + threadIdx.x) >> 6;
    int lane = threadIdx.x & 63;
    int slot = lane >> 3;     // 0..7
    int j    = lane & 7;      // channel octet
    if (wid >= N_NODES) return;
    int e0 = starts[wid], e1 = starts[wid + 1];
    float a0 = 0, a1 = 0, a2 = 0, a3 = 0, a4 = 0, a5 = 0, a6 = 0, a7 = 0;
    #pragma unroll 2
    for (int e = e0 + slot; e < e1; e += 8) {
        unsigned int rec = erec[e];
        int c  = rec >> 16;
        int i0 = rec & 0xffff;
        uint4 qw = lutB4_l[i0 * 8 + j];
        uint4 fb = featsbf4[(size_t)c * 8 + j];
        a0 += bf_lo(fb.x) * bf_lo(qw.x);
        a1 += bf_hi(fb.x) * bf_hi(qw.x);
        a2 += bf_lo(fb.y) * bf_lo(qw.y);
        a3 += bf_hi(fb.y) * bf_hi(qw.y);
        a4 += bf_lo(fb.z) * bf_lo(qw.z);
        a5 += bf_hi(fb.z) * bf_hi(qw.z);
        a6 += bf_lo(fb.w) * bf_lo(qw.w);
        a7 += bf_hi(fb.w) * bf_hi(qw.w);
    }
    #pragma unroll
    for (int off = 8; off < 64; off <<= 1) {
        a0 += __shfl_xor(a0, off, 64);  a1 += __shfl_xor(a1, off, 64);
        a2 += __shfl_xor(a2, off, 64);  a3 += __shfl_xor(a3, off, 64);
        a4 += __shfl_xor(a4, off, 64);  a5 += __shfl_xor(a5, off, 64);
        a6 += __shfl_xor(a6, off, 64);  a7 += __shfl_xor(a7, off, 64);
    }
    if (slot == 0) {
        uint4 o;
        o.x = f2bf(a0) | (f2bf(a1) << 16);
        o.y = f2bf(a2) | (f2bf(a3) << 16);
        o.z = f2bf(a4) | (f2bf(a5) << 16);
        o.w = f2bf(a6) | (f2bf(a7) << 16);
        aggbf4[(size_t)wid * 8 + j] = o;
    }
}

// k_node v3 (MFMA): 64 nodes/block, 4 waves; wave w owns node rows [16w,16w+16).
constexpr int BP = 72;                     // bf16 LDS row pitch
__global__ __launch_bounds__(256) void k_node(float* __restrict__ feats,
        unsigned short* __restrict__ featsbf,
        const unsigned short* __restrict__ aggbf,
        const unsigned short* __restrict__ WspT_l, const unsigned short* __restrict__ PbT_l,
        const unsigned short* __restrict__ W1T_l, const unsigned short* __restrict__ W2T_l,
        const float* __restrict__ bsp_l,
        const float* __restrict__ mlp_b1_l, const float* __restrict__ mlp_b2_l,
        const float* __restrict__ ln_g_l, const float* __restrict__ ln_b_l) {
    __shared__ unsigned short P[64 * BP];   // x -> conv
    __shared__ unsigned short Q[64 * BP];   // a -> m1_lo
    __shared__ unsigned short S[64 * BP];   // m1_hi
    const int tid  = threadIdx.x;
    const int lane = tid & 63;
    const int wib  = tid >> 6;
    const int mt   = __builtin_amdgcn_readfirstlane(wib);
    const int nb0  = blockIdx.x * 64;
    const int colL = lane & 15;
    const int kgrp = lane >> 4;

    #pragma unroll 4
    for (int i = 0; i < 16; ++i) {
        int r  = wib + i * 4;
        int nd = nb0 + r; nd = (nd < N_NODES) ? nd : (N_NODES - 1);
        P[r * BP + lane] = featsbf[(size_t)nd * 64 + lane];
        Q[r * BP + lane] = aggbf[(size_t)nd * 64 + lane];
    }
    __syncthreads();

    // ---- conv = x@Wsp + a@Pb + bsp ----
    f32x4 acc[4];
    #pragma unroll
    for (int nt = 0; nt < 4; ++nt) {
        float b = bsp_l[nt * 16 + colL];
        acc[nt][0] = b; acc[nt][1] = b; acc[nt][2] = b; acc[nt][3] = b;
    }
    #pragma unroll
    for (int kb = 0; kb < 2; ++kb) {
        short8 ax = *(const short8*)&P[(mt * 16 + colL) * BP + kb * 32 + kgrp * 8];
        short8 aa = *(const short8*)&Q[(mt * 16 + colL) * BP + kb * 32 + kgrp * 8];
        #pragma unroll
        for (int nt = 0; nt < 4; ++nt) {
            short8 bw = *(const short8*)&WspT_l[(nt * 16 + colL) * 64 + kb * 32 + kgrp * 8];
            acc[nt] = MFMA16(ax, bw, acc[nt], 0, 0, 0);
            short8 bp = *(const short8*)&PbT_l[(nt * 16 + colL) * 64 + kb * 32 + kgrp * 8];
            acc[nt] = MFMA16(aa, bp, acc[nt], 0, 0, 0);
        }
    }
    __syncthreads();
    #pragma unroll
    for (int nt = 0; nt < 4; ++nt)
        #pragma unroll
        for (int j = 0; j < 4; ++j)
            P[(mt * 16 + kgrp * 4 + j) * BP + nt * 16 + colL] = (unsigned short)f2bf(acc[nt][j]);
    __syncthreads();

    // ---- m1 = silu(conv@W1 + b1), 128 wide ----
    {
        f32x4 m[8];
        #pragma unroll
        for (int nt = 0; nt < 8; ++nt) {
            float b = mlp_b1_l[nt * 16 + colL];
            m[nt][0] = b; m[nt][1] = b; m[nt][2] = b; m[nt][3] = b;
        }
        #pragma unroll
        for (int kb = 0; kb < 2; ++kb) {
            short8 ac = *(const short8*)&P[(mt * 16 + colL) * BP + kb * 32 + kgrp * 8];
            #pragma unroll
            for (int nt = 0; nt < 8; ++nt) {
                short8 bw = *(const short8*)&W1T_l[(nt * 16 + colL) * 64 + kb * 32 + kgrp * 8];
                m[nt] = MFMA16(ac, bw, m[nt], 0, 0, 0);
            }
        }
        __syncthreads();
        #pragma unroll
        for (int nt = 0; nt < 4; ++nt)
            #pragma unroll
            for (int j = 0; j < 4; ++j)
                Q[(mt * 16 + kgrp * 4 + j) * BP + nt * 16 + colL] =
                    (unsigned short)f2bf(siluf(m[nt][j]));
        #pragma unroll
        for (int nt = 4; nt < 8; ++nt)
            #pragma unroll
            for (int j = 0; j < 4; ++j)
                S[(mt * 16 + kgrp * 4 + j) * BP + (nt - 4) * 16 + colL] =
                    (unsigned short)f2bf(siluf(m[nt][j]));
    }
    __syncthreads();

    // ---- upd = m1@W2 + b2 ----
    f32x4 u[4];
    #pragma unroll
    for (int nt = 0; nt < 4; ++nt) {
        float b = mlp_b2_l[nt * 16 + colL];
        u[nt][0] = b; u[nt][1] = b; u[nt][2] = b; u[nt][3] = b;
    }
    #pragma unroll
    for (int kb = 0; kb < 4; ++kb) {
        short8 am = (kb < 2)
            ? *(const short8*)&Q[(mt * 16 + colL) * BP + kb * 32 + kgrp * 8]
            : *(const short8*)&S[(mt * 16 + colL) * BP + (kb - 2) * 32 + kgrp * 8];
        #pragma unroll
        for (int nt = 0; nt < 4; ++nt) {
            short8 bw = *(const short8*)&W2T_l[(nt * 16 + colL) * 128 + kb * 32 + kgrp * 8];
            u[nt] = MFMA16(am, bw, u[nt], 0, 0, 0);
        }
    }

    // ---- residual + LayerNorm ----
    float y[4][4];
    float s1[4] = {0, 0, 0, 0}, s2[4] = {0, 0, 0, 0};
    #pragma unroll
    for (int j = 0; j < 4; ++j) {
        int node = nb0 + mt * 16 + kgrp * 4 + j;
        int nds  = (node < N_NODES) ? node : (N_NODES - 1);
        #pragma unroll
        for (int nt = 0; nt < 4; ++nt) {
            float v = feats[(size_t)nds * 64 + nt * 16 + colL] + u[nt][j];
            y[nt][j] = v;
            s1[j] += v; s2[j] += v * v;
        }
    }
    #pragma unroll
    for (int off = 1; off < 16; off <<= 1) {
        #pragma unroll
        for (int j = 0; j < 4; ++j) {
            s1[j] += __shfl_xor(s1[j], off, 64);
            s2[j] += __shfl_xor(s2[j], off, 64);
        }
    }
    float gv[4], bv[4];
    #pragma unroll
    for (int nt = 0; nt < 4; ++nt) {
        gv[nt] = ln_g_l[nt * 16 + colL];
        bv[nt] = ln_b_l[nt * 16 + colL];
    }
    #pragma unroll
    for (int j = 0; j < 4; ++j) {
        int node = nb0 + mt * 16 + kgrp * 4 + j;
        if (node >= N_NODES) continue;
        float mu  = s1[j] * (1.0f / 64.0f);
        float var = s2[j] * (1.0f / 64.0f) - mu * mu;
        float rr  = rsqrtf(var + 1e-5f);
        #pragma unroll
        for (int nt = 0; nt < 4; ++nt) {
            float o = (y[nt][j] - mu) * rr * gv[nt] + bv[nt];
            feats[(size_t)node * 64 + nt * 16 + colL]   = o;
            featsbf[(size_t)node * 64 + nt * 16 + colL] = (unsigned short)f2bf(o);
        }
    }
}

// ---------------- readout (MFMA, k_node template) ----------------

__global__ __launch_bounds__(256) void k_readout(const unsigned short* __restrict__ featsbf,
        const int* __restrict__ an,
        const unsigned short* __restrict__ Ro1T, const unsigned short* __restrict__ Ro2T,
        const float* __restrict__ ro_b1, const float* __restrict__ ro_b2,
        const float* __restrict__ ro_w3, const float* __restrict__ ro_b3,
        const float* __restrict__ atomic_e, float* __restrict__ blockpart) {
    __shared__ unsigned short P[64 * BP];   // feats
    __shared__ unsigned short Q[64 * BP];   // h1
    __shared__ float sred[256];
    const int tid  = threadIdx.x;
    const int lane = tid & 63;
    const int wib  = tid >> 6;
    const int mt   = __builtin_amdgcn_readfirstlane(wib);
    const int nb0  = blockIdx.x * 64;
    const int colL = lane & 15;
    const int kgrp = lane >> 4;

    #pragma unroll 4
    for (int i = 0; i < 16; ++i) {
        int r  = wib + i * 4;
        int nd = nb0 + r; nd = (nd < N_NODES) ? nd : (N_NODES - 1);
        P[r * BP + lane] = featsbf[(size_t)nd * 64 + lane];
    }
    __syncthreads();

    // ---- h1 = silu(x @ Ro1 + b1) ----
    {
        f32x4 m[4];
        #pragma unroll
        for (int nt = 0; nt < 4; ++nt) {
            float b = ro_b1[nt * 16 + colL];
            m[nt][0] = b; m[nt][1] = b; m[nt][2] = b; m[nt][3] = b;
        }
        #pragma unroll
        for (int kb = 0; kb < 2; ++kb) {
            short8 ax = *(const short8*)&P[(mt * 16 + colL) * BP + kb * 32 + kgrp * 8];
            #pragma unroll
            for (int nt = 0; nt < 4; ++nt) {
                short8 bw = *(const short8*)&Ro1T[(nt * 16 + colL) * 64 + kb * 32 + kgrp * 8];
                m[nt] = MFMA16(ax, bw, m[nt], 0, 0, 0);
            }
        }
        __syncthreads();
        #pragma unroll
        for (int nt = 0; nt < 4; ++nt)
            #pragma unroll
            for (int j = 0; j < 4; ++j)
                Q[(mt * 16 + kgrp * 4 + j) * BP + nt * 16 + colL] =
                    (unsigned short)f2bf(siluf(m[nt][j]));
    }
    __syncthreads();

    // ---- h2 = silu(h1 @ Ro2 + b2), 32 wide; e = h2 @ ro_w3 ----
    f32x4 u[2];
    #pragma unroll
    for (int nt = 0; nt < 2; ++nt) {
        float b = ro_b2[nt * 16 + colL];
        u[nt][0] = b; u[nt][1] = b; u[nt][2] = b; u[nt][3] = b;
    }
    #pragma unroll
    for (int kb = 0; kb < 2; ++kb) {
        short8 am = *(const short8*)&Q[(mt * 16 + colL) * BP + kb * 32 + kgrp * 8];
        #pragma unroll
        for (int nt = 0; nt < 2; ++nt) {
            short8 bw = *(const short8*)&Ro2T[(nt * 16 + colL) * 64 + kb * 32 + kgrp * 8];
            u[nt] = MFMA16(am, bw, u[nt], 0, 0, 0);
        }
    }
    float w3[2];
    #pragma unroll
    for (int nt = 0; nt < 2; ++nt) w3[nt] = ro_w3[nt * 16 + colL];
    float part = 0.0f;
    #pragma unroll
    for (int j = 0; j < 4; ++j) {
        float c = siluf(u[0][j]) * w3[0] + siluf(u[1][j]) * w3[1];
        #pragma unroll
        for (int off = 1; off < 16; off <<= 1) c += __shfl_xor(c, off, 64);
        int node = nb0 + mt * 16 + kgrp * 4 + j;
        if (colL == 0 && node < N_NODES)
            part += c + ro_b3[0] + atomic_e[an[node]];
    }
    sred[tid] = part;
    __syncthreads();
    for (int off = 128; off > 0; off >>= 1) {
        if (tid < off) sred[tid] += sred[tid + off];
        __syncthreads();
    }
    if (tid == 0) blockpart[blockIdx.x] = sred[0];
}

__global__ void k_final(const float* __restrict__ blockpart, int nb, float* __restrict__ out) {
    __shared__ float s[256];
    float acc = 0.f;
    for (int i = threadIdx.x; i < nb; i += 256) acc += blockpart[i];
    s[threadIdx.x] = acc; __syncthreads();
    for (int off = 128; off > 0; off >>= 1) {
        if (threadIdx.x < off) s[threadIdx.x] += s[threadIdx.x + off];
        __syncthreads();
    }
    if (threadIdx.x == 0) out[0] = s[0];
}

// ---------------- launch ----------------

extern "C" void kernel_launch(void* const* d_in, const int* in_sizes, int n_in,
                              void* d_out, int out_size, void* d_ws, size_t ws_size,
                              hipStream_t stream) {
    const int*   an       = (const int*)  d_in[0];
    const float* pos      = (const float*)d_in[1];
    const int*   edge     = (const int*)  d_in[2];
    const float* widths   = (const float*)d_in[3];
    const float* embed    = (const float*)d_in[4];
    const float* rad_w1   = (const float*)d_in[5];
    const float* rad_b1   = (const float*)d_in[6];
    const float* rad_w2   = (const float*)d_in[7];
    const float* rad_b2   = (const float*)d_in[8];
    const float* self_w   = (const float*)d_in[9];
    const float* self_b   = (const float*)d_in[10];
    const float* proj_w   = (const float*)d_in[11];
    const float* proj_b   = (const float*)d_in[12];
    const float* mlp_w1   = (const float*)d_in[13];
    const float* mlp_b1   = (const float*)d_in[14];
    const float* mlp_w2   = (const float*)d_in[15];
    const float* mlp_b2   = (const float*)d_in[16];
    const float* ln_g     = (const float*)d_in[17];
    const float* ln_b     = (const float*)d_in[18];
    const float* ro_w1    = (const float*)d_in[19];
    const float* ro_b1    = (const float*)d_in[20];
    const float* ro_w2    = (const float*)d_in[21];
    const float* ro_b2    = (const float*)d_in[22];
    const float* ro_w3    = (const float*)d_in[23];
    const float* ro_b3    = (const float*)d_in[24];
    const float* atomic_e = (const float*)d_in[25];

    char* w = (char*)d_ws;
    auto alloc = [&](size_t bytes) { char* p = w; w += (bytes + 255) & ~(size_t)255; return p; };
    float* feats     = (float*)alloc(sizeof(float) * N_NODES * HDIM);
    unsigned short* featsbf = (unsigned short*)alloc(sizeof(unsigned short) * N_NODES * HDIM);
    unsigned short* aggbf   = (unsigned short*)alloc(sizeof(unsigned short) * N_NODES * HDIM);
    float* lut       = (float*)alloc(sizeof(float) * NLAYER * TLUT * HDIM);
    unsigned short* lutB = (unsigned short*)alloc(sizeof(unsigned short) * NLAYER * TLUT * HDIM);
    float* W2s       = (float*)alloc(sizeof(float) * NLAYER * HDIM * HDIM);
    float* b2s       = (float*)alloc(sizeof(float) * NLAYER * HDIM);
    float* Wsp       = (float*)alloc(sizeof(float) * NLAYER * HDIM * HDIM);
    float* bsp       = (float*)alloc(sizeof(float) * NLAYER * HDIM);
    unsigned short* WspT = (unsigned short*)alloc(sizeof(unsigned short) * NLAYER * 4096);
    unsigned short* PbT  = (unsigned short*)alloc(sizeof(unsigned short) * NLAYER * 4096);
    unsigned short* W1T  = (unsigned short*)alloc(sizeof(unsigned short) * NLAYER * 8192);
    unsigned short* W2T  = (unsigned short*)alloc(sizeof(unsigned short) * NLAYER * 8192);
    unsigned short* Ro1T = (unsigned short*)alloc(sizeof(unsigned short) * 4096);
    unsigned short* Ro2T = (unsigned short*)alloc(sizeof(unsigned short) * 2048);
    unsigned int* erec = (unsigned int*)alloc(sizeof(unsigned int) * N_EDGES);
    uint2* binned    = (uint2*)alloc(sizeof(uint2) * (size_t)NBKT * BCAP);
    int*   btail     = (int*)  alloc(sizeof(int) * 256);
    int*   bbase     = (int*)  alloc(sizeof(int) * 256);
    int*   starts    = (int*)  alloc(sizeof(int) * (N_NODES + 1));
    float* blockpart = (float*)alloc(sizeof(float) * 1024);
    (void)ws_size; (void)in_sizes; (void)n_in; (void)out_size;

    const int* erow = edge;
    const int* ecol = edge + N_EDGES;

    hipMemsetAsync(btail, 0, sizeof(int) * 256, stream);
    k_embed<<<12500, 256, 0, stream>>>(an, embed, feats, featsbf);
    k_binA<<<(N_EDGES + TILE - 1) / TILE, 256, 0, stream>>>(erow, ecol, pos, btail, binned);
    k_scanB<<<1, 256, 0, stream>>>(btail, bbase);
    k_binB<<<NBKT, 256, 0, stream>>>(binned, btail, bbase, starts, erec);
    k_prep<<<80, 256, 0, stream>>>(rad_w2, self_w, proj_w, W2s, Wsp);
    k_wtr<<<(NLAYER * 24576 + 255) / 256, 256, 0, stream>>>(Wsp, proj_w, mlp_w1, mlp_w2,
                                                            WspT, PbT, W1T, W2T);
    k_rotr<<<24, 256, 0, stream>>>(ro_w1, ro_w2, Ro1T, Ro2T);
    k_bias<<<5, 64, 0, stream>>>(rad_b2, self_b, proj_w, proj_b, b2s, bsp);
    k_lut<<<NLAYER * TLUT, 64, 0, stream>>>(widths, rad_w1, rad_b1, W2s, b2s, lut);
    k_lutb<<<(NLAYER * TLUT * HDIM + 255) / 256, 256, 0, stream>>>(lut, lutB);

    for (int l = 0; l < NLAYER; ++l) {
        k_agg<<<12500, 256, 0, stream>>>((const uint4*)featsbf,
                                         (const uint4*)(lutB + (size_t)l * TLUT * HDIM),
                                         starts, erec, (uint4*)aggbf);
        k_node<<<782, 256, 0, stream>>>(feats, featsbf, aggbf,
            WspT + (size_t)l * 4096, PbT + (size_t)l * 4096,
            W1T + (size_t)l * 8192, W2T + (size_t)l * 8192,
            bsp + l * HDIM, mlp_b1 + l * 2 * HDIM, mlp_b2 + l * HDIM,
            ln_g + l * HDIM, ln_b + l * HDIM);
    }

    k_readout<<<782, 256, 0, stream>>>(featsbf, an, Ro1T, Ro2T, ro_b1, ro_b2,
                                       ro_w3, ro_b3, atomic_e, blockpart);
    k_final<<<1, 256, 0, stream>>>(blockpart, 782, (float*)d_out);
}